// Round 3
// baseline (1038.897 us; speedup 1.0000x reference)
//
// Hyperbolic (Poincare ball) transformer block — MI355X round 8.
// Round-7 post-mortem: butterfly-reduction VOLUME (not chain count) was the
// epilogue cost; waveRed<16> regressed attnout. This round moves the row
// reductions into the GEMM epilogue itself:
//  * k_gemm_bf16 optionally accumulates per-row {sum c^2, sum c*bias, sum c}
//    via 4 shfl steps + atomicAdd into a small L2-resident array (nacc).
//  * epi_qkv: PURE elementwise (no waveRed at all).
//  * epi_attnout: 2 tiny chains (waveRed<4> + waveRed<2>); sum(x^2),sum(x)
//    stored by stage1; bias-only sums from one-wave k_bsums kernel.
//  * epi_ffn1: single waveRed<2>. epi_final: reuses attnout's stored
//    residual norm (sum q^2 = resn^2).
//  * Atomic buffers zeroed by the previous consumer (wave-owned rows; no
//    memsets, no races).
//  * FFN: CH=8192 (h2 relocated to R_a frees contiguous 96MB for m1/hid/
//    partials), split-K 4->2: partial traffic 512MB->256MB, 16 launches.
// GEMM inner loop and MFMA attention unchanged.
#include <hip/hip_runtime.h>
#include <math.h>

#define S_DIM 128
#define B_DIM 256
#define E_DIM 512
#define F_DIM 2048
#define N_ROWS (S_DIM * B_DIM) /* 32768 */
#define CH 8192                /* FFN row chunk */
#define MAXN 0.99999f          /* 1 - 1e-5 */

typedef __bf16 bf16x8 __attribute__((ext_vector_type(8)));
typedef float f32x4 __attribute__((ext_vector_type(4)));

// ---- fast-math helpers (1-instr HW transcendentals) -----------------------
__device__ __forceinline__ float frcp(float x) { return __builtin_amdgcn_rcpf(x); }
__device__ __forceinline__ float frsq(float x) { return __builtin_amdgcn_rsqf(x); }
__device__ __forceinline__ float fexp2(float x) { return __builtin_amdgcn_exp2f(x); }
__device__ __forceinline__ float flog2(float x) { return __builtin_amdgcn_logf(x); }
__device__ __forceinline__ float fatanh(float x) {
  return 0.34657359f * flog2((1.f + x) * frcp(1.f - x));
}
__device__ __forceinline__ float ftanh(float x) {
  float t = fexp2(x * -2.88539008f);
  return (1.f - t) * frcp(1.f + t);
}

__device__ __forceinline__ ushort f2bf(float f) {
  __bf16 h = (__bf16)f;
  return __builtin_bit_cast(ushort, h);
}
__device__ __forceinline__ uint pack2(float a, float b) {
  return (uint)f2bf(a) | ((uint)f2bf(b) << 16);
}

__device__ __forceinline__ void gld16(const ushort* g, ushort* l) {
  __builtin_amdgcn_global_load_lds(
      (const __attribute__((address_space(1))) void*)g,
      (__attribute__((address_space(3))) void*)l, 16, 0, 0);
}

// ---- wave-wide butterfly reduction of K values (all lanes get results) ----
template <int K>
__device__ __forceinline__ void waveRed(float (&v)[K]) {
#pragma unroll
  for (int o = 1; o < 64; o <<= 1) {
#pragma unroll
    for (int i = 0; i < K; ++i) v[i] += __shfl_xor(v[i], o);
  }
}

// ---------------- fp32 -> bf16 convert (weights) ---------------------------
__global__ __launch_bounds__(256) void k_f2bf(const float* __restrict__ in,
                                              ushort* __restrict__ out, int n) {
  for (int i = blockIdx.x * 256 + threadIdx.x; i < n; i += gridDim.x * 256)
    out[i] = f2bf(in[i]);
}

// ---- one-wave bias/param sums kernel --------------------------------------
// bs: [0]=Sbq2 [1]=Sbk2 [2]=Sbv2 [3]=Sbo2 [4]=Sbo [5]=Sb1_2 [6]=Sb2_2
//     [7]=Sg1_2 [8]=Sg1lb1 [9]=Slb1_2
__global__ void k_bsums(const float* __restrict__ bq, const float* __restrict__ bk,
                        const float* __restrict__ bv, const float* __restrict__ bo,
                        const float* __restrict__ b1, const float* __restrict__ b2,
                        const float* __restrict__ g1, const float* __restrict__ lb1,
                        float* __restrict__ bs) {
  int lane = threadIdx.x;
  float p[10];
#pragma unroll
  for (int i = 0; i < 10; ++i) p[i] = 0.f;
  for (int i = lane; i < E_DIM; i += 64) {
    float a = bq[i]; p[0] += a * a;
    a = bk[i]; p[1] += a * a;
    a = bv[i]; p[2] += a * a;
    float o = bo[i]; p[3] += o * o; p[4] += o;
    float c = b2[i]; p[6] += c * c;
    float g = g1[i], l = lb1[i];
    p[7] += g * g; p[8] += g * l; p[9] += l * l;
  }
  for (int i = lane; i < F_DIM; i += 64) { float a = b1[i]; p[5] += a * a; }
  waveRed<10>(p);
  if (lane == 0) {
    bs[0] = p[0]; bs[1] = p[1]; bs[2] = p[2]; bs[3] = p[3]; bs[4] = p[4];
    bs[5] = p[5]; bs[6] = p[6]; bs[7] = p[7]; bs[8] = p[8]; bs[9] = p[9];
  }
}

// ---- stage 1: h1 = expmap0(LN(logmap0(x))) -> bf16. 2 rows/wave. ----------
// Also stores raw sum(x^2), sum(x) per row and zeroes the nacc atomics.
__global__ __launch_bounds__(256) void k_stage1(
    const float* __restrict__ x, const float* __restrict__ g,
    const float* __restrict__ bb, const float* __restrict__ bs,
    ushort* __restrict__ h, float* __restrict__ hn,
    float* __restrict__ sx2a, float* __restrict__ sx1a,
    float* __restrict__ nacc) {
  int wv = threadIdx.x >> 6, lane = threadIdx.x & 63;
  int row = blockIdx.x * 8 + wv * 2;
  size_t base = (size_t)row * E_DIM + lane * 8;
  float v[2][8], gv[8], bv[8];
  *(float4*)&v[0][0] = *(const float4*)(x + base);
  *(float4*)&v[0][4] = *(const float4*)(x + base + 4);
  *(float4*)&v[1][0] = *(const float4*)(x + base + E_DIM);
  *(float4*)&v[1][4] = *(const float4*)(x + base + E_DIM + 4);
  *(float4*)&gv[0] = *(const float4*)(g + lane * 8);
  *(float4*)&gv[4] = *(const float4*)(g + lane * 8 + 4);
  *(float4*)&bv[0] = *(const float4*)(bb + lane * 8);
  *(float4*)&bv[4] = *(const float4*)(bb + lane * 8 + 4);
  // per-row: v^2, v, g^2 v^2, g^2 v, g v b
  float s[10];
#pragma unroll
  for (int i = 0; i < 10; ++i) s[i] = 0.f;
#pragma unroll
  for (int i = 0; i < 8; ++i) {
    float gg = gv[i] * gv[i], gb = gv[i] * bv[i];
#pragma unroll
    for (int r2 = 0; r2 < 2; ++r2) {
      float vv = v[r2][i];
      s[r2 * 5 + 0] += vv * vv;
      s[r2 * 5 + 1] += vv;
      s[r2 * 5 + 2] += vv * vv * gg;
      s[r2 * 5 + 3] += vv * gg;
      s[r2 * 5 + 4] += vv * gb;
    }
  }
  waveRed<10>(s);
  float Sg2 = bs[7], Sgb = bs[8], Sb2 = bs[9];
#pragma unroll
  for (int r2 = 0; r2 < 2; ++r2) {
    float T0 = s[r2 * 5 + 0], T1 = s[r2 * 5 + 1], T2 = s[r2 * 5 + 2];
    float T3 = s[r2 * 5 + 3], T4 = s[r2 * 5 + 4];
    float se = T0 + 1e-30f;
    float rn = frsq(se);
    float n = se * rn;
    float a = fatanh(fminf(n, MAXN)) * rn;
    float mu = a * T1 * (1.f / 512.f);
    float var = fmaxf(a * a * T0 * (1.f / 512.f) - mu * mu, 0.f);
    float rstd = frsq(var + 1e-5f);
    float A = a * rstd, B = -mu * rstd;
    float se2 = fmaxf(A * A * T2 + 2.f * A * B * T3 + 2.f * A * T4 +
                          B * B * Sg2 + 2.f * B * Sgb + Sb2, 0.f) + 1e-30f;
    float rn2 = frsq(se2);
    float n2 = se2 * rn2;
    float th = ftanh(n2);
    float f = th * rn2;
    float e[8];
#pragma unroll
    for (int i = 0; i < 8; ++i) e[i] = (A * v[r2][i] + B) * gv[i] + bv[i];
    uint4 o = {pack2(e[0] * f, e[1] * f), pack2(e[2] * f, e[3] * f),
               pack2(e[4] * f, e[5] * f), pack2(e[6] * f, e[7] * f)};
    *reinterpret_cast<uint4*>(h + base + r2 * E_DIM) = o;
    if (lane == 0) {
      hn[row + r2] = th;
      sx2a[row + r2] = T0;
      sx1a[row + r2] = T1;
    }
  }
  if (lane == 0) {
    nacc[row] = 0.f; nacc[row + 1] = 0.f;
    nacc[N_ROWS + row] = 0.f; nacc[N_ROWS + row + 1] = 0.f;
    nacc[2 * N_ROWS + row] = 0.f; nacc[2 * N_ROWS + row + 1] = 0.f;
  }
}

// -------- bf16 MFMA GEMM: C[n][m] = sum_k A[n][k]*B[m][k], C fp32 ----------
// Optional per-row norm accumulation: nacc[3][nR] += {c^2, c*bias, c}.
__global__ __launch_bounds__(256) void k_gemm_bf16(
    const ushort* __restrict__ A, const ushort* __restrict__ B,
    float* __restrict__ C, int K, int M, int kseg,
    unsigned long long partStride, const float* __restrict__ bias,
    float* __restrict__ nacc, int nR) {
  __shared__ __align__(16) ushort As[128 * 32];
  __shared__ __align__(16) ushort Bs[128 * 32];
  int tid = threadIdx.x;
  int w = tid >> 6, lane = tid & 63;
  int wm = w >> 1, wn = w & 1;
  size_t row0 = (size_t)blockIdx.y * 128;
  size_t col0 = (size_t)blockIdx.x * 128;
  int k0 = blockIdx.z * kseg;

  const ushort* gA =
      A + (row0 + w * 32 + (lane >> 2)) * (size_t)K + (lane & 3) * 8 + k0;
  const ushort* gB =
      B + (col0 + w * 32 + (lane >> 2)) * (size_t)K + (lane & 3) * 8 + k0;
  ushort* lA = As + (w * 32) * 32;
  ushort* lB = Bs + (w * 32) * 32;
  const int rowK16 = 16 * K;

  int fro = (lane & 15) * 32 + (lane >> 4) * 8;
  const ushort* raA = As + (wm * 64) * 32 + fro;
  const ushort* raB = Bs + (wn * 64) * 32 + fro;

  f32x4 zero = {0.f, 0.f, 0.f, 0.f};
  f32x4 acc[4][4];
#pragma unroll
  for (int i = 0; i < 4; ++i)
#pragma unroll
    for (int j = 0; j < 4; ++j) acc[i][j] = zero;

  for (int kt = 0; kt < kseg; kt += 32) {
    __syncthreads();
    gld16(gA + kt, lA);
    gld16(gA + kt + rowK16, lA + 16 * 32);
    gld16(gB + kt, lB);
    gld16(gB + kt + rowK16, lB + 16 * 32);
    __syncthreads();
    bf16x8 af[4], bfv[4];
#pragma unroll
    for (int t = 0; t < 4; ++t) {
      af[t] = *reinterpret_cast<const bf16x8*>(raA + t * 512);
      bfv[t] = *reinterpret_cast<const bf16x8*>(raB + t * 512);
    }
#pragma unroll
    for (int i = 0; i < 4; ++i)
#pragma unroll
      for (int j = 0; j < 4; ++j)
        acc[i][j] = __builtin_amdgcn_mfma_f32_16x16x32_bf16(af[i], bfv[j],
                                                            acc[i][j], 0, 0, 0);
  }
  float* Cz = C + (size_t)blockIdx.z * partStride;
  int crow = wm * 64 + (lane >> 4) * 4;
  int ccol = (int)col0 + wn * 64 + (lane & 15);
#pragma unroll
  for (int ti = 0; ti < 4; ++ti) {
    size_t r = row0 + crow + ti * 16;
#pragma unroll
    for (int tj = 0; tj < 4; ++tj) {
      int cc = ccol + tj * 16;
#pragma unroll
      for (int reg = 0; reg < 4; ++reg)
        Cz[(r + reg) * (size_t)M + cc] = acc[ti][tj][reg];
    }
  }
  if (nacc != nullptr) {
    float bvv[4];
#pragma unroll
    for (int tj = 0; tj < 4; ++tj) bvv[tj] = bias[ccol + tj * 16];
#pragma unroll
    for (int ti = 0; ti < 4; ++ti) {
#pragma unroll
      for (int reg = 0; reg < 4; ++reg) {
        float p2 = 0.f, pb = 0.f, p1 = 0.f;
#pragma unroll
        for (int tj = 0; tj < 4; ++tj) {
          float cv = acc[ti][tj][reg];
          p2 += cv * cv; pb += cv * bvv[tj]; p1 += cv;
        }
#pragma unroll
        for (int o = 1; o < 16; o <<= 1) {
          p2 += __shfl_xor(p2, o);
          pb += __shfl_xor(pb, o);
          p1 += __shfl_xor(p1, o);
        }
        if ((lane & 15) == 0) {
          int rr = (int)row0 + crow + ti * 16 + reg;
          atomicAdd(&nacc[rr], p2);
          atomicAdd(&nacc[nR + rr], pb);
          atomicAdd(&nacc[2 * nR + rr], p1);
        }
      }
    }
  }
}

// ---- QKV epilogue: PURE elementwise (row sums from GEMM atomics) ----------
__global__ __launch_bounds__(256) void k_epi_qkv(
    const float* __restrict__ mx, const float* __restrict__ xn_arr,
    const float* __restrict__ bias, float* __restrict__ nacc,
    const float* __restrict__ bs_sb2, ushort* __restrict__ qout) {
  int wv = threadIdx.x >> 6, lane = threadIdx.x & 63;
  int row = blockIdx.x * 8 + wv * 2;
  size_t base = (size_t)row * E_DIM + lane * 8;
  float m[2][8], bv[8];
  *(float4*)&m[0][0] = *(const float4*)(mx + base);
  *(float4*)&m[0][4] = *(const float4*)(mx + base + 4);
  *(float4*)&m[1][0] = *(const float4*)(mx + base + E_DIM);
  *(float4*)&m[1][4] = *(const float4*)(mx + base + E_DIM + 4);
  *(float4*)&bv[0] = *(const float4*)(bias + lane * 8);
  *(float4*)&bv[4] = *(const float4*)(bias + lane * 8 + 4);
  float S2 = *bs_sb2;
#pragma unroll
  for (int r2 = 0; r2 < 2; ++r2) {
    float S0 = nacc[row + r2];
    float S1 = nacc[N_ROWS + row + r2];
    float se = S0 + 1e-30f;
    float rmx = frsq(se);
    float mxn = se * rmx;
    float xn = xn_arr[row + r2];
    float aa = fatanh(fminf(xn, MAXN));
    float tt = ftanh(mxn * frcp(xn) * aa);
    float c = tt * rmx;
    float xy = c * S1, y2 = S2, x2 = tt * tt;
    float c1 = 1.f + 2.f * xy + y2, c2 = 1.f - x2;
    float iden = frcp(fmaxf(1.f + 2.f * xy + x2 * y2, 1e-15f));
    float cc1 = c1 * c * iden, cc2 = c2 * iden;
    float un2 = fmaxf(cc1 * cc1 * S0 + 2.f * cc1 * cc2 * S1 + cc2 * cc2 * S2, 0.f);
    float ue = un2 + 1e-30f;
    float run = frsq(ue);
    float un = ue * run;
    float ne = fminf(un, MAXN);
    float f = fatanh(ne) * run;
    float u[8];
#pragma unroll
    for (int i = 0; i < 8; ++i) u[i] = (cc1 * m[r2][i] + cc2 * bv[i]) * f;
    uint4 o = {pack2(u[0], u[1]), pack2(u[2], u[3]), pack2(u[4], u[5]),
               pack2(u[6], u[7])};
    *reinterpret_cast<uint4*>(qout + base + r2 * E_DIM) = o;
  }
  // re-zero for the next norm-accumulating GEMM (rows are wave-owned)
  if (lane == 0) {
    nacc[row] = 0.f; nacc[row + 1] = 0.f;
    nacc[N_ROWS + row] = 0.f; nacc[N_ROWS + row + 1] = 0.f;
    nacc[2 * N_ROWS + row] = 0.f; nacc[2 * N_ROWS + row + 1] = 0.f;
  }
}

// ---- attention: per (b,h) MFMA tile (unchanged) ---------------------------
__global__ __launch_bounds__(256) void k_attn(const ushort* __restrict__ q,
                                              const ushort* __restrict__ k,
                                              const ushort* __restrict__ v,
                                              float* __restrict__ o) {
  __shared__ __align__(16) ushort smem[27136];
  ushort* Qs = smem;
  ushort* Ks = smem + 9216;
  ushort* VTs = smem + 18432;
  ushort* Ps = smem;
  int bh = blockIdx.x;
  int b = bh >> 3, h = bh & 7;
  int tid = threadIdx.x;
  int w = tid >> 6, lane = tid & 63;
  const size_t BE = (size_t)B_DIM * E_DIM;
  size_t gbase = (size_t)b * E_DIM + (size_t)h * 64;

  {
    int s = tid >> 1, half = (tid & 1) * 32;
    const ushort* qr = q + gbase + (size_t)s * BE + half;
    const ushort* kr = k + gbase + (size_t)s * BE + half;
    const ushort* vr = v + gbase + (size_t)s * BE + half;
#pragma unroll
    for (int j = 0; j < 4; ++j) {
      *reinterpret_cast<uint4*>(&Qs[s * 72 + half + j * 8]) =
          *reinterpret_cast<const uint4*>(qr + j * 8);
      *reinterpret_cast<uint4*>(&Ks[s * 72 + half + j * 8]) =
          *reinterpret_cast<const uint4*>(kr + j * 8);
    }
    ushort tv[32];
#pragma unroll
    for (int j = 0; j < 4; ++j)
      *reinterpret_cast<uint4*>(&tv[j * 8]) =
          *reinterpret_cast<const uint4*>(vr + j * 8);
#pragma unroll
    for (int d = 0; d < 32; ++d) VTs[(half + d) * 136 + s] = tv[d];
  }
  __syncthreads();

  f32x4 zero = {0.f, 0.f, 0.f, 0.f};
  f32x4 sacc[2][8];
#pragma unroll
  for (int i = 0; i < 2; ++i)
#pragma unroll
    for (int j = 0; j < 8; ++j) sacc[i][j] = zero;
  {
    const ushort* qb = Qs + (w * 32 + (lane & 15)) * 72 + (lane >> 4) * 8;
    const ushort* kb = Ks + (lane & 15) * 72 + (lane >> 4) * 8;
#pragma unroll
    for (int kk = 0; kk < 2; ++kk) {
      bf16x8 a0 = *reinterpret_cast<const bf16x8*>(qb + kk * 32);
      bf16x8 a1 = *reinterpret_cast<const bf16x8*>(qb + 16 * 72 + kk * 32);
#pragma unroll
      for (int tj = 0; tj < 8; ++tj) {
        bf16x8 bf = *reinterpret_cast<const bf16x8*>(kb + tj * 16 * 72 + kk * 32);
        sacc[0][tj] = __builtin_amdgcn_mfma_f32_16x16x32_bf16(a0, bf,
                                                              sacc[0][tj], 0, 0, 0);
        sacc[1][tj] = __builtin_amdgcn_mfma_f32_16x16x32_bf16(a1, bf,
                                                              sacc[1][tj], 0, 0, 0);
      }
    }
  }

#pragma unroll
  for (int ti = 0; ti < 2; ++ti) {
#pragma unroll
    for (int r = 0; r < 4; ++r) {
      float mx = -1e30f;
#pragma unroll
      for (int tj = 0; tj < 8; ++tj) mx = fmaxf(mx, sacc[ti][tj][r]);
      mx = fmaxf(mx, __shfl_xor(mx, 1));
      mx = fmaxf(mx, __shfl_xor(mx, 2));
      mx = fmaxf(mx, __shfl_xor(mx, 4));
      mx = fmaxf(mx, __shfl_xor(mx, 8));
      float l = 0.f;
#pragma unroll
      for (int tj = 0; tj < 8; ++tj) {
        float e = fexp2((sacc[ti][tj][r] - mx) * (0.125f * 1.44269504f));
        sacc[ti][tj][r] = e;
        l += e;
      }
      l += __shfl_xor(l, 1);
      l += __shfl_xor(l, 2);
      l += __shfl_xor(l, 4);
      l += __shfl_xor(l, 8);
      float inv = frcp(l);
#pragma unroll
      for (int tj = 0; tj < 8; ++tj) sacc[ti][tj][r] *= inv;
    }
  }

  __syncthreads();
  {
    int qr0 = w * 32 + (lane >> 4) * 4;
    int kc = lane & 15;
#pragma unroll
    for (int ti = 0; ti < 2; ++ti)
#pragma unroll
      for (int tj = 0; tj < 8; ++tj)
#pragma unroll
        for (int r = 0; r < 4; ++r)
          Ps[(qr0 + ti * 16 + r) * 136 + tj * 16 + kc] =
              f2bf(sacc[ti][tj][r]);
  }
  __syncthreads();

  f32x4 oacc[2][4];
#pragma unroll
  for (int i = 0; i < 2; ++i)
#pragma unroll
    for (int j = 0; j < 4; ++j) oacc[i][j] = zero;
  {
    const ushort* pb = Ps + (w * 32 + (lane & 15)) * 136 + (lane >> 4) * 8;
    const ushort* vb = VTs + (lane & 15) * 136 + (lane >> 4) * 8;
#pragma unroll
    for (int kk = 0; kk < 4; ++kk) {
      bf16x8 a0 = *reinterpret_cast<const bf16x8*>(pb + kk * 32);
      bf16x8 a1 = *reinterpret_cast<const bf16x8*>(pb + 16 * 136 + kk * 32);
#pragma unroll
      for (int tj = 0; tj < 4; ++tj) {
        bf16x8 bv = *reinterpret_cast<const bf16x8*>(vb + tj * 16 * 136 + kk * 32);
        oacc[0][tj] = __builtin_amdgcn_mfma_f32_16x16x32_bf16(a0, bv,
                                                              oacc[0][tj], 0, 0, 0);
        oacc[1][tj] = __builtin_amdgcn_mfma_f32_16x16x32_bf16(a1, bv,
                                                              oacc[1][tj], 0, 0, 0);
      }
    }
  }

  {
    int qr0 = w * 32 + (lane >> 4) * 4;
    int dc = lane & 15;
#pragma unroll
    for (int ti = 0; ti < 2; ++ti)
#pragma unroll
      for (int tj = 0; tj < 4; ++tj)
#pragma unroll
        for (int r = 0; r < 4; ++r)
          o[(size_t)(qr0 + ti * 16 + r) * BE + gbase + tj * 16 + dc] =
              oacc[ti][tj][r];
  }
}

// ---- expmap0 rowwise, 2 rows/wave ----------------------------------------
__global__ __launch_bounds__(256) void k_expmap_rows(const float* __restrict__ in,
                                                     ushort* __restrict__ out,
                                                     float* __restrict__ nrm) {
  int wv = threadIdx.x >> 6, lane = threadIdx.x & 63;
  int row = blockIdx.x * 8 + wv * 2;
  size_t base = (size_t)row * E_DIM + lane * 8;
  float v[2][8];
  *(float4*)&v[0][0] = *(const float4*)(in + base);
  *(float4*)&v[0][4] = *(const float4*)(in + base + 4);
  *(float4*)&v[1][0] = *(const float4*)(in + base + E_DIM);
  *(float4*)&v[1][4] = *(const float4*)(in + base + E_DIM + 4);
  float s[2] = {0.f, 0.f};
#pragma unroll
  for (int i = 0; i < 8; ++i) {
    s[0] += v[0][i] * v[0][i];
    s[1] += v[1][i] * v[1][i];
  }
  waveRed<2>(s);
#pragma unroll
  for (int r2 = 0; r2 < 2; ++r2) {
    float se = s[r2] + 1e-30f;
    float rn = frsq(se);
    float n = se * rn;
    float th = ftanh(n);
    float f = th * rn;
    uint4 o = {pack2(v[r2][0] * f, v[r2][1] * f), pack2(v[r2][2] * f, v[r2][3] * f),
               pack2(v[r2][4] * f, v[r2][5] * f), pack2(v[r2][6] * f, v[r2][7] * f)};
    *reinterpret_cast<uint4*>(out + base + r2 * E_DIM) = o;
    if (lane == 0) nrm[row + r2] = th;
  }
}

// ---- attn-out epilogue, 2 rows/wave, 2 tiny chains ------------------------
__global__ __launch_bounds__(256) void k_epi_attnout(
    float* __restrict__ mo, const float* __restrict__ xn_arr,
    const float* __restrict__ nacc, const float* __restrict__ sx2a,
    const float* __restrict__ sx1a, const float* __restrict__ bs,
    const float* __restrict__ bo, const float* __restrict__ xin,
    const float* __restrict__ g2, const float* __restrict__ b2,
    ushort* __restrict__ h2, float* __restrict__ h2n,
    float* __restrict__ resn, float* __restrict__ naccF) {
  int wv = threadIdx.x >> 6, lane = threadIdx.x & 63;
  int row = blockIdx.x * 8 + wv * 2;
  size_t base = (size_t)row * E_DIM + lane * 8;
  float m[2][8], bv[8], r[2][8], gv[8], b2v[8];
  *(float4*)&m[0][0] = *(const float4*)(mo + base);
  *(float4*)&m[0][4] = *(const float4*)(mo + base + 4);
  *(float4*)&m[1][0] = *(const float4*)(mo + base + E_DIM);
  *(float4*)&m[1][4] = *(const float4*)(mo + base + E_DIM + 4);
  *(float4*)&r[0][0] = *(const float4*)(xin + base);
  *(float4*)&r[0][4] = *(const float4*)(xin + base + 4);
  *(float4*)&r[1][0] = *(const float4*)(xin + base + E_DIM);
  *(float4*)&r[1][4] = *(const float4*)(xin + base + E_DIM + 4);
  *(float4*)&bv[0] = *(const float4*)(bo + lane * 8);
  *(float4*)&bv[4] = *(const float4*)(bo + lane * 8 + 4);
  *(float4*)&gv[0] = *(const float4*)(g2 + lane * 8);
  *(float4*)&gv[4] = *(const float4*)(g2 + lane * 8 + 4);
  *(float4*)&b2v[0] = *(const float4*)(b2 + lane * 8);
  *(float4*)&b2v[4] = *(const float4*)(b2 + lane * 8 + 4);
  // chain 1: per-row {m.x, bo.x}
  float t[4];
#pragma unroll
  for (int i = 0; i < 4; ++i) t[i] = 0.f;
#pragma unroll
  for (int i = 0; i < 8; ++i) {
#pragma unroll
    for (int r2 = 0; r2 < 2; ++r2) {
      t[r2 * 2 + 0] += m[r2][i] * r[r2][i];
      t[r2 * 2 + 1] += bv[i] * r[r2][i];
    }
  }
  waveRed<4>(t);
  float Sb2 = bs[3], Sb = bs[4];
  float e[2][8];
  float s3[2] = {0.f, 0.f};
#pragma unroll
  for (int r2 = 0; r2 < 2; ++r2) {
    float Sm2 = nacc[row + r2];
    float Smb = nacc[N_ROWS + row + r2];
    float Sm1 = nacc[2 * N_ROWS + row + r2];
    float Sr2 = sx2a[row + r2];
    float Sr = sx1a[row + r2];
    float se = Sm2 + 1e-30f;
    float rmx = frsq(se);
    float mxn = se * rmx;
    float xn = xn_arr[row + r2];
    float aa = fatanh(fminf(xn, MAXN));
    float tt = ftanh(mxn * frcp(xn) * aa);
    float c = tt * rmx;
    float xy = c * Smb, y2 = Sb2, x2 = tt * tt;
    float c1 = 1.f + 2.f * xy + y2, c2 = 1.f - x2;
    float iden = frcp(fmaxf(1.f + 2.f * xy + x2 * y2, 1e-15f));
    float cc1 = c1 * c * iden, cc2 = c2 * iden;
    float un2 = fmaxf(cc1 * cc1 * Sm2 + 2.f * cc1 * cc2 * Smb + cc2 * cc2 * Sb2, 0.f);
    float ue = un2 + 1e-30f;
    float run = frsq(ue);
    float un = ue * run;
    float ps = un > MAXN ? MAXN * run : 1.f;
    float zn = fminf(un, MAXN);
    float sumz = ps * (cc1 * Sm1 + cc2 * Sb);
    float xy2 = ps * (cc1 * t[r2 * 2 + 0] + cc2 * t[r2 * 2 + 1]);
    float y22 = Sr2, x22 = zn * zn;
    float d1 = 1.f + 2.f * xy2 + y22, d2 = 1.f - x22;
    float iden2 = frcp(fmaxf(1.f + 2.f * xy2 + x22 * y22, 1e-15f));
    float wn2 = fmaxf(iden2 * iden2 *
                          (d1 * d1 * x22 + 2.f * d1 * d2 * xy2 + d2 * d2 * y22),
                      0.f);
    float we = wn2 + 1e-30f;
    float rwn = frsq(we);
    float wn = we * rwn;
    float ps2 = wn > MAXN ? MAXN * rwn : 1.f;
    float P = d1 * iden2 * ps2 * ps * cc1;
    float Q = d1 * iden2 * ps2 * ps * cc2;
    float R = d2 * iden2 * ps2;
    float w[8];
#pragma unroll
    for (int i = 0; i < 8; ++i) w[i] = P * m[r2][i] + Q * bv[i] + R * r[r2][i];
    *(float4*)(mo + base + r2 * E_DIM) = *(float4*)&w[0];
    *(float4*)(mo + base + r2 * E_DIM + 4) = *(float4*)&w[4];
    float ne = fminf(wn, MAXN);
    if (lane == 0) resn[row + r2] = ne;
    float ath = fatanh(ne);
    float lf = ath * frcp(ne);
    float sumw = ps2 * iden2 * (d1 * sumz + d2 * Sr);
    float mu = lf * sumw * (1.f / 512.f);
    float var = fmaxf(ath * ath * (1.f / 512.f) - mu * mu, 0.f);
    float rstd = frsq(var + 1e-5f);
#pragma unroll
    for (int i = 0; i < 8; ++i) {
      e[r2][i] = (lf * w[i] - mu) * rstd * gv[i] + b2v[i];
      s3[r2] += e[r2][i] * e[r2][i];
    }
  }
  waveRed<2>(s3);
#pragma unroll
  for (int r2 = 0; r2 < 2; ++r2) {
    float s3e = s3[r2] + 1e-30f;
    float rn3 = frsq(s3e);
    float n3 = s3e * rn3;
    float en = ftanh(n3);
    float f = en * rn3;
    if (en > MAXN) f *= MAXN * frcp(en);
    uint4 o = {pack2(e[r2][0] * f, e[r2][1] * f), pack2(e[r2][2] * f, e[r2][3] * f),
               pack2(e[r2][4] * f, e[r2][5] * f), pack2(e[r2][6] * f, e[r2][7] * f)};
    *reinterpret_cast<uint4*>(h2 + base + r2 * E_DIM) = o;
    if (lane == 0) h2n[row + r2] = fminf(en, MAXN);
  }
  // zero the FFN1 atomic buffer (rows 0..CH-1, wave-owned)
  if (lane == 0 && row < CH) {
    naccF[row] = 0.f; naccF[row + 1] = 0.f;
    naccF[CH + row] = 0.f; naccF[CH + row + 1] = 0.f;
    naccF[2 * CH + row] = 0.f; naccF[2 * CH + row + 1] = 0.f;
  }
}

// ---- FFN1 epilogue (2 rows/wave of F=2048), single chain ------------------
__global__ __launch_bounds__(256) void k_epi_ffn1(
    const float* __restrict__ mr_, const float* __restrict__ xn_arr,
    const float* __restrict__ bias, float* __restrict__ nacc,
    const float* __restrict__ bs5, ushort* __restrict__ hid,
    float* __restrict__ hn_out) {
  int wv = threadIdx.x >> 6, lane = threadIdx.x & 63;
  int row = blockIdx.x * 8 + wv * 2;
  const float* mr = mr_ + (size_t)row * F_DIM + lane * 32;
  const float* br = bias + lane * 32;
  float m[2][32], bv[32];
#pragma unroll
  for (int j = 0; j < 8; ++j) {
    *(float4*)&m[0][j * 4] = *(const float4*)(mr + j * 4);
    *(float4*)&m[1][j * 4] = *(const float4*)(mr + F_DIM + j * 4);
    *(float4*)&bv[j * 4] = *(const float4*)(br + j * 4);
  }
  float S2 = *bs5;
  float s2[2] = {0.f, 0.f};
#pragma unroll
  for (int r2 = 0; r2 < 2; ++r2) {
    float S0 = nacc[row + r2];
    float S1 = nacc[CH + row + r2];
    float se = S0 + 1e-30f;
    float rmx = frsq(se);
    float mxn = se * rmx;
    float xn = xn_arr[row + r2];
    float aa = fatanh(fminf(xn, MAXN));
    float tt = ftanh(mxn * frcp(xn) * aa);
    float c = tt * rmx;
    float xy = c * S1, y2 = S2, x2 = tt * tt;
    float c1 = 1.f + 2.f * xy + y2, c2 = 1.f - x2;
    float iden = frcp(fmaxf(1.f + 2.f * xy + x2 * y2, 1e-15f));
    float cc1 = c1 * c * iden, cc2 = c2 * iden;
    float un2 = fmaxf(cc1 * cc1 * S0 + 2.f * cc1 * cc2 * S1 + cc2 * cc2 * S2, 0.f);
    float ue = un2 + 1e-30f;
    float run = frsq(ue);
    float un = ue * run;
    float zn = fminf(un, MAXN);
    float lf = fatanh(zn) * run;
#pragma unroll
    for (int i = 0; i < 32; ++i) {
      m[r2][i] = fmaxf((cc1 * m[r2][i] + cc2 * bv[i]) * lf, 0.f);
      s2[r2] += m[r2][i] * m[r2][i];
    }
  }
  waveRed<2>(s2);
#pragma unroll
  for (int r2 = 0; r2 < 2; ++r2) {
    float s2e = s2[r2] + 1e-30f;
    float rrn = frsq(s2e);
    float rn = s2e * rrn;
    float en = ftanh(rn);
    float f = en * rrn;
    if (en > MAXN) f *= MAXN * frcp(en);
    ushort* hr = hid + (size_t)(row + r2) * F_DIM + lane * 32;
#pragma unroll
    for (int j = 0; j < 4; ++j) {
      uint4 o = {pack2(m[r2][j * 8 + 0] * f, m[r2][j * 8 + 1] * f),
                 pack2(m[r2][j * 8 + 2] * f, m[r2][j * 8 + 3] * f),
                 pack2(m[r2][j * 8 + 4] * f, m[r2][j * 8 + 5] * f),
                 pack2(m[r2][j * 8 + 6] * f, m[r2][j * 8 + 7] * f)};
      *reinterpret_cast<uint4*>(hr + j * 8) = o;
    }
    if (lane == 0) hn_out[row + r2] = fminf(en, MAXN);
  }
  // re-zero for next chunk's FFN1 GEMM
  if (lane == 0) {
    nacc[row] = 0.f; nacc[row + 1] = 0.f;
    nacc[CH + row] = 0.f; nacc[CH + row + 1] = 0.f;
    nacc[2 * CH + row] = 0.f; nacc[2 * CH + row + 1] = 0.f;
  }
}

// ---- final epilogue (2 rows/wave): 2-way split-K sum + man_linear(W2) +
// mob_relu + residual mobius_add + projx -> out fp32 ------------------------
__global__ __launch_bounds__(256) void k_epi_final(
    const float* __restrict__ m2, const float* __restrict__ xn_arr,
    const float* __restrict__ bias, const float* __restrict__ bs6,
    const float* __restrict__ res, const float* __restrict__ resn,
    float* __restrict__ out) {
  int wv = threadIdx.x >> 6, lane = threadIdx.x & 63;
  int row = blockIdx.x * 8 + wv * 2;
  size_t base = (size_t)row * E_DIM + lane * 8;
  const size_t P2 = (size_t)CH * E_DIM;
  float m[2][8], bv[8], q[2][8];
#pragma unroll
  for (int r2 = 0; r2 < 2; ++r2) {
    float ta[8], tb[8];
    *(float4*)&ta[0] = *(const float4*)(m2 + base + r2 * E_DIM);
    *(float4*)&ta[4] = *(const float4*)(m2 + base + r2 * E_DIM + 4);
    *(float4*)&tb[0] = *(const float4*)(m2 + P2 + base + r2 * E_DIM);
    *(float4*)&tb[4] = *(const float4*)(m2 + P2 + base + r2 * E_DIM + 4);
#pragma unroll
    for (int i = 0; i < 8; ++i) m[r2][i] = ta[i] + tb[i];
    *(float4*)&q[r2][0] = *(const float4*)(res + base + r2 * E_DIM);
    *(float4*)&q[r2][4] = *(const float4*)(res + base + r2 * E_DIM + 4);
  }
  *(float4*)&bv[0] = *(const float4*)(bias + lane * 8);
  *(float4*)&bv[4] = *(const float4*)(bias + lane * 8 + 4);
  float Sb2 = *bs6;
  float s[4];
#pragma unroll
  for (int i = 0; i < 4; ++i) s[i] = 0.f;
#pragma unroll
  for (int i = 0; i < 8; ++i) {
#pragma unroll
    for (int r2 = 0; r2 < 2; ++r2) {
      s[r2 * 2 + 0] += m[r2][i] * m[r2][i];
      s[r2 * 2 + 1] += m[r2][i] * bv[i];
    }
  }
  waveRed<4>(s);
  float r[2][8];
  float s2[4];
#pragma unroll
  for (int i = 0; i < 4; ++i) s2[i] = 0.f;
#pragma unroll
  for (int r2 = 0; r2 < 2; ++r2) {
    float S0 = s[r2 * 2 + 0], S1 = s[r2 * 2 + 1];
    float se = S0 + 1e-30f;
    float rmx = frsq(se);
    float mxn = se * rmx;
    float xn = xn_arr[row + r2];
    float aa = fatanh(fminf(xn, MAXN));
    float tt = ftanh(mxn * frcp(xn) * aa);
    float c = tt * rmx;
    float xy = c * S1, y2 = Sb2, x2 = tt * tt;
    float c1 = 1.f + 2.f * xy + y2, c2 = 1.f - x2;
    float iden = frcp(fmaxf(1.f + 2.f * xy + x2 * y2, 1e-15f));
    float cc1 = c1 * c * iden, cc2 = c2 * iden;
    float un2 = fmaxf(cc1 * cc1 * S0 + 2.f * cc1 * cc2 * S1 + cc2 * cc2 * Sb2, 0.f);
    float ue = un2 + 1e-30f;
    float run = frsq(ue);
    float un = ue * run;
    float zn = fminf(un, MAXN);
    float lf = fatanh(zn) * run;
#pragma unroll
    for (int i = 0; i < 8; ++i) {
      r[r2][i] = fmaxf((cc1 * m[r2][i] + cc2 * bv[i]) * lf, 0.f);
      s2[r2 * 2 + 0] += r[r2][i] * r[r2][i];
      s2[r2 * 2 + 1] += r[r2][i] * q[r2][i];
    }
  }
  waveRed<4>(s2);
#pragma unroll
  for (int r2 = 0; r2 < 2; ++r2) {
    float s2e = s2[r2 * 2 + 0] + 1e-30f;
    float rrn = frsq(s2e);
    float rn = s2e * rrn;
    float en = ftanh(rn);
    float f = en * rrn;
    if (en > MAXN) f *= MAXN * frcp(en);
    float hn = fminf(en, MAXN);
    float rsn = resn[row + r2];
    float xy2 = f * s2[r2 * 2 + 1], y22 = rsn * rsn, x22 = hn * hn;
    float d1 = 1.f + 2.f * xy2 + y22, d2 = 1.f - x22;
    float iden2 = frcp(fmaxf(1.f + 2.f * xy2 + x22 * y22, 1e-15f));
    float wn2 = fmaxf(iden2 * iden2 *
                          (d1 * d1 * x22 + 2.f * d1 * d2 * xy2 + d2 * d2 * y22),
                      0.f);
    float we = wn2 + 1e-30f;
    float rwn = frsq(we);
    float wn = we * rwn;
    float ps2 = wn > MAXN ? MAXN * rwn : 1.f;
    float w[8];
#pragma unroll
    for (int i = 0; i < 8; ++i)
      w[i] = (d1 * r[r2][i] * f + d2 * q[r2][i]) * iden2 * ps2;
    *(float4*)(out + base + r2 * E_DIM) = *(float4*)&w[0];
    *(float4*)(out + base + r2 * E_DIM + 4) = *(float4*)&w[4];
  }
}

extern "C" void kernel_launch(void* const* d_in, const int* in_sizes, int n_in,
                              void* d_out, int out_size, void* d_ws,
                              size_t ws_size, hipStream_t stream) {
  const float* x   = (const float*)d_in[0];
  const float* g1  = (const float*)d_in[1];
  const float* lb1 = (const float*)d_in[2];
  const float* g2  = (const float*)d_in[3];
  const float* lb2 = (const float*)d_in[4];
  const float* Wq  = (const float*)d_in[5];
  const float* bq  = (const float*)d_in[6];
  const float* Wk  = (const float*)d_in[7];
  const float* bk  = (const float*)d_in[8];
  const float* Wv  = (const float*)d_in[9];
  const float* bv  = (const float*)d_in[10];
  const float* Wo  = (const float*)d_in[11];
  const float* bo  = (const float*)d_in[12];
  const float* W1  = (const float*)d_in[13];
  const float* b1  = (const float*)d_in[14];
  const float* W2  = (const float*)d_in[15];
  const float* b2  = (const float*)d_in[16];
  float* out = (float*)d_out;
  float* ws = (float*)d_ws;

  const size_t NE = (size_t)N_ROWS * E_DIM;          // 16,777,216
  const size_t WF = (4 * (size_t)E_DIM * E_DIM +
                     2 * (size_t)F_DIM * E_DIM) / 2; // 1,572,864 floats
  float* R_b = ws;                   // NE: mx fp32 / attn-out / mo / res2
  float* R_a = ws + NE;              // NE/2: h1_bf16 -> oe_bf16 -> h2_bf16
  float* R_q = ws + NE + NE / 2;     // NE/2: q_bf16 -> m1 lower / m2 partials
  float* R_k = ws + 2 * NE;          // NE/2: k_bf16 -> m1 upper
  float* R_v = ws + 2 * NE + NE / 2; // NE/2: v_bf16 -> hid_bf16
  ushort* wqb = (ushort*)(ws + 3 * NE);
  ushort* wkb = wqb + (size_t)E_DIM * E_DIM;
  ushort* wvb = wkb + (size_t)E_DIM * E_DIM;
  ushort* wob = wvb + (size_t)E_DIM * E_DIM;
  ushort* w1b = wob + (size_t)E_DIM * E_DIM;
  ushort* w2b = w1b + (size_t)F_DIM * E_DIM;
  float* n_h1 = ws + 3 * NE + WF;    // |h1|; reused as resn by attnout
  float* n_oe = n_h1 + N_ROWS;
  float* n_h2 = n_oe + N_ROWS;
  float* n_h3 = n_h2 + N_ROWS;
  float* sx2a = n_h3 + N_ROWS;       // sum(x^2) per row
  float* sx1a = sx2a + N_ROWS;       // sum(x) per row
  float* nacc = sx1a + N_ROWS;       // 3*N_ROWS atomic row sums (E-GEMMs)
  float* naccF = nacc + 3 * (size_t)N_ROWS;  // 3*CH (FFN1 GEMM)
  float* bs = naccF + 3 * (size_t)CH;        // 16 scalar sums
  const size_t need = (3 * NE + WF + 9 * (size_t)N_ROWS + 3 * (size_t)CH + 16) *
                      sizeof(float);
  if (ws_size < need) return;

  k_bsums<<<1, 64, 0, stream>>>(bq, bk, bv, bo, b1, b2, g1, lb1, bs);
  k_f2bf<<<256, 256, 0, stream>>>(Wq, wqb, E_DIM * E_DIM);
  k_f2bf<<<256, 256, 0, stream>>>(Wk, wkb, E_DIM * E_DIM);
  k_f2bf<<<256, 256, 0, stream>>>(Wv, wvb, E_DIM * E_DIM);
  k_f2bf<<<256, 256, 0, stream>>>(Wo, wob, E_DIM * E_DIM);
  k_f2bf<<<512, 256, 0, stream>>>(W1, w1b, F_DIM * E_DIM);
  k_f2bf<<<512, 256, 0, stream>>>(W2, w2b, F_DIM * E_DIM);

  ushort* h1b = (ushort*)R_a;
  ushort* qb = (ushort*)R_q;
  ushort* kb = (ushort*)R_k;
  ushort* vb = (ushort*)R_v;

  // Phase A: stage1 (+nacc zero) + QKV projections (norm-accumulating GEMMs)
  k_stage1<<<N_ROWS / 8, 256, 0, stream>>>(x, g1, lb1, bs, h1b, n_h1,
                                           sx2a, sx1a, nacc);
  dim3 gQ(E_DIM / 128, N_ROWS / 128, 1);
  k_gemm_bf16<<<gQ, 256, 0, stream>>>(h1b, wqb, R_b, E_DIM, E_DIM, E_DIM, 0,
                                      bq, nacc, N_ROWS);
  k_epi_qkv<<<N_ROWS / 8, 256, 0, stream>>>(R_b, n_h1, bq, nacc, bs + 0, qb);
  k_gemm_bf16<<<gQ, 256, 0, stream>>>(h1b, wkb, R_b, E_DIM, E_DIM, E_DIM, 0,
                                      bk, nacc, N_ROWS);
  k_epi_qkv<<<N_ROWS / 8, 256, 0, stream>>>(R_b, n_h1, bk, nacc, bs + 1, kb);
  k_gemm_bf16<<<gQ, 256, 0, stream>>>(h1b, wvb, R_b, E_DIM, E_DIM, E_DIM, 0,
                                      bv, nacc, N_ROWS);
  k_epi_qkv<<<N_ROWS / 8, 256, 0, stream>>>(R_b, n_h1, bv, nacc, bs + 2, vb);

  // Phase B: MFMA attention -> R_b fp32; expmap0 -> oe bf16 (R_a, h1 dead)
  k_attn<<<B_DIM * 8, 256, 0, stream>>>(qb, kb, vb, R_b);
  ushort* oeb = (ushort*)R_a;
  k_expmap_rows<<<N_ROWS / 8, 256, 0, stream>>>(R_b, oeb, n_oe);

  // Phase C: Wo projection (norms) -> R_b; attnout: res2 in-place, h2 -> R_a
  ushort* h2b = (ushort*)R_a;  // oe dead once GEMM Wo has read it
  k_gemm_bf16<<<gQ, 256, 0, stream>>>(oeb, wob, R_b, E_DIM, E_DIM, E_DIM, 0,
                                      bo, nacc, N_ROWS);
  k_epi_attnout<<<N_ROWS / 8, 256, 0, stream>>>(R_b, n_oe, nacc, sx2a, sx1a,
                                                bs, bo, x, g2, lb2, h2b, n_h2,
                                                n_h1 /*resn*/, naccF);

  // Phase D: FFN chunked (CH=8192). m1 spans R_q+R_k (64MB), hid in R_v,
  // split-K2 partials reuse R_q (m1 dead). All stream-ordered.
  float* m1 = R_q;
  ushort* hidb = (ushort*)R_v;
  float* m2 = R_q;
  for (int c = 0; c < N_ROWS / CH; ++c) {
    size_t ro = (size_t)c * CH;
    k_gemm_bf16<<<dim3(F_DIM / 128, CH / 128, 1), 256, 0, stream>>>(
        h2b + ro * E_DIM, w1b, m1, E_DIM, F_DIM, E_DIM, 0, b1, naccF, CH);
    k_epi_ffn1<<<CH / 8, 256, 0, stream>>>(m1, n_h2 + ro, b1, naccF, bs + 5,
                                           hidb, n_h3 + ro);
    k_gemm_bf16<<<dim3(E_DIM / 128, CH / 128, 2), 256, 0, stream>>>(
        hidb, w2b, m2, F_DIM, E_DIM, F_DIM / 2,
        (unsigned long long)((size_t)CH * E_DIM), nullptr, nullptr, 0);
    k_epi_final<<<CH / 8, 256, 0, stream>>>(m2, n_h3 + ro, b2, bs + 6,
                                            R_b + ro * E_DIM, n_h1 + ro,
                                            out + ro * E_DIM);
  }
}

// Round 4
// 873.767 us; speedup vs baseline: 1.1890x; 1.1890x over previous
//
// Hyperbolic (Poincare ball) transformer block — MI355X round 9.
// Round-8 post-mortem: cross-block atomic row-sums poisoned the GEMMs
// (MfmaUtil 37%->9.6%, bank-conflict 0->2.1M, GEMMs 65us). Fix: make the
// row reduction BLOCK-LOCAL instead.
//  * k_qkv_fused: one block = 32 rows x all 512 cols (acc 64 VGPR, LDS
//    A 2KB + B 32KB, 4 blocks/CU). Full epi_qkv fused into the epilogue:
//    4-step shfl (16-lane col groups) -> 1KB LDS cross-wave reduce ->
//    32 threads run the scalar chain -> bf16 written directly. Removes
//    per projection: 64MB fp32 C write + 64MB epi read + epi dispatch.
//  * Wo/FFN GEMMs: plain round-7 kernel (no atomics).
//  * attnout: round-6 1-row/wave version (measured 42.6us vs r7's 45.4).
//  * FFN keeps round-8's CH=8192 + split-K2 (partial traffic 256MB).
#include <hip/hip_runtime.h>
#include <math.h>

#define S_DIM 128
#define B_DIM 256
#define E_DIM 512
#define F_DIM 2048
#define N_ROWS (S_DIM * B_DIM) /* 32768 */
#define CH 8192                /* FFN row chunk */
#define MAXN 0.99999f          /* 1 - 1e-5 */

typedef __bf16 bf16x8 __attribute__((ext_vector_type(8)));
typedef float f32x4 __attribute__((ext_vector_type(4)));

// ---- fast-math helpers (1-instr HW transcendentals) -----------------------
__device__ __forceinline__ float frcp(float x) { return __builtin_amdgcn_rcpf(x); }
__device__ __forceinline__ float frsq(float x) { return __builtin_amdgcn_rsqf(x); }
__device__ __forceinline__ float fexp2(float x) { return __builtin_amdgcn_exp2f(x); }
__device__ __forceinline__ float flog2(float x) { return __builtin_amdgcn_logf(x); }
__device__ __forceinline__ float fatanh(float x) {
  return 0.34657359f * flog2((1.f + x) * frcp(1.f - x));
}
__device__ __forceinline__ float ftanh(float x) {
  float t = fexp2(x * -2.88539008f);
  return (1.f - t) * frcp(1.f + t);
}

__device__ __forceinline__ ushort f2bf(float f) {
  __bf16 h = (__bf16)f;
  return __builtin_bit_cast(ushort, h);
}
__device__ __forceinline__ uint pack2(float a, float b) {
  return (uint)f2bf(a) | ((uint)f2bf(b) << 16);
}

__device__ __forceinline__ void gld16(const ushort* g, ushort* l) {
  __builtin_amdgcn_global_load_lds(
      (const __attribute__((address_space(1))) void*)g,
      (__attribute__((address_space(3))) void*)l, 16, 0, 0);
}

// ---- wave-wide butterfly reduction of K values (all lanes get results) ----
template <int K>
__device__ __forceinline__ void waveRed(float (&v)[K]) {
#pragma unroll
  for (int o = 1; o < 64; o <<= 1) {
#pragma unroll
    for (int i = 0; i < K; ++i) v[i] += __shfl_xor(v[i], o);
  }
}

// ---------------- fp32 -> bf16 convert (weights) ---------------------------
__global__ __launch_bounds__(256) void k_f2bf(const float* __restrict__ in,
                                              ushort* __restrict__ out, int n) {
  for (int i = blockIdx.x * 256 + threadIdx.x; i < n; i += gridDim.x * 256)
    out[i] = f2bf(in[i]);
}

// ---- one-wave bias/param sums kernel --------------------------------------
// bs: [0]=Sbq2 [1]=Sbk2 [2]=Sbv2 [3..6] unused [7]=Sg1_2 [8]=Sg1lb1 [9]=Slb1_2
__global__ void k_bsums(const float* __restrict__ bq, const float* __restrict__ bk,
                        const float* __restrict__ bv, const float* __restrict__ g1,
                        const float* __restrict__ lb1, float* __restrict__ bs) {
  int lane = threadIdx.x;
  float p[6];
#pragma unroll
  for (int i = 0; i < 6; ++i) p[i] = 0.f;
  for (int i = lane; i < E_DIM; i += 64) {
    float a = bq[i]; p[0] += a * a;
    a = bk[i]; p[1] += a * a;
    a = bv[i]; p[2] += a * a;
    float g = g1[i], l = lb1[i];
    p[3] += g * g; p[4] += g * l; p[5] += l * l;
  }
  waveRed<6>(p);
  if (lane == 0) {
    bs[0] = p[0]; bs[1] = p[1]; bs[2] = p[2];
    bs[7] = p[3]; bs[8] = p[4]; bs[9] = p[5];
  }
}

// ---- stage 1: h1 = expmap0(LN(logmap0(x))) -> bf16. 2 rows/wave. ----------
__global__ __launch_bounds__(256) void k_stage1(
    const float* __restrict__ x, const float* __restrict__ g,
    const float* __restrict__ bb, const float* __restrict__ bs,
    ushort* __restrict__ h, float* __restrict__ hn) {
  int wv = threadIdx.x >> 6, lane = threadIdx.x & 63;
  int row = blockIdx.x * 8 + wv * 2;
  size_t base = (size_t)row * E_DIM + lane * 8;
  float v[2][8], gv[8], bv[8];
  *(float4*)&v[0][0] = *(const float4*)(x + base);
  *(float4*)&v[0][4] = *(const float4*)(x + base + 4);
  *(float4*)&v[1][0] = *(const float4*)(x + base + E_DIM);
  *(float4*)&v[1][4] = *(const float4*)(x + base + E_DIM + 4);
  *(float4*)&gv[0] = *(const float4*)(g + lane * 8);
  *(float4*)&gv[4] = *(const float4*)(g + lane * 8 + 4);
  *(float4*)&bv[0] = *(const float4*)(bb + lane * 8);
  *(float4*)&bv[4] = *(const float4*)(bb + lane * 8 + 4);
  float s[10];
#pragma unroll
  for (int i = 0; i < 10; ++i) s[i] = 0.f;
#pragma unroll
  for (int i = 0; i < 8; ++i) {
    float gg = gv[i] * gv[i], gb = gv[i] * bv[i];
#pragma unroll
    for (int r2 = 0; r2 < 2; ++r2) {
      float vv = v[r2][i];
      s[r2 * 5 + 0] += vv * vv;
      s[r2 * 5 + 1] += vv;
      s[r2 * 5 + 2] += vv * vv * gg;
      s[r2 * 5 + 3] += vv * gg;
      s[r2 * 5 + 4] += vv * gb;
    }
  }
  waveRed<10>(s);
  float Sg2 = bs[7], Sgb = bs[8], Sb2 = bs[9];
#pragma unroll
  for (int r2 = 0; r2 < 2; ++r2) {
    float T0 = s[r2 * 5 + 0], T1 = s[r2 * 5 + 1], T2 = s[r2 * 5 + 2];
    float T3 = s[r2 * 5 + 3], T4 = s[r2 * 5 + 4];
    float se = T0 + 1e-30f;
    float rn = frsq(se);
    float n = se * rn;
    float a = fatanh(fminf(n, MAXN)) * rn;
    float mu = a * T1 * (1.f / 512.f);
    float var = fmaxf(a * a * T0 * (1.f / 512.f) - mu * mu, 0.f);
    float rstd = frsq(var + 1e-5f);
    float A = a * rstd, B = -mu * rstd;
    float se2 = fmaxf(A * A * T2 + 2.f * A * B * T3 + 2.f * A * T4 +
                          B * B * Sg2 + 2.f * B * Sgb + Sb2, 0.f) + 1e-30f;
    float rn2 = frsq(se2);
    float n2 = se2 * rn2;
    float th = ftanh(n2);
    float f = th * rn2;
    float e[8];
#pragma unroll
    for (int i = 0; i < 8; ++i) e[i] = (A * v[r2][i] + B) * gv[i] + bv[i];
    uint4 o = {pack2(e[0] * f, e[1] * f), pack2(e[2] * f, e[3] * f),
               pack2(e[4] * f, e[5] * f), pack2(e[6] * f, e[7] * f)};
    *reinterpret_cast<uint4*>(h + base + r2 * E_DIM) = o;
    if (lane == 0) hn[row + r2] = th;
  }
}

// ---- fused QKV projection: block = 32 rows x 512 cols, epilogue fused -----
// C[r][c] = sum_k A[r][k]*W[c][k]; then logmap0(projx(mobius_add(C,b))) bf16.
__global__ __launch_bounds__(256) void k_qkv_fused(
    const ushort* __restrict__ A, const ushort* __restrict__ B,
    const float* __restrict__ xn_arr, const float* __restrict__ bias,
    const float* __restrict__ bs_sb2, ushort* __restrict__ qout) {
  __shared__ __align__(16) ushort As[32 * 32];   // 2 KB
  __shared__ __align__(16) ushort Bs[512 * 32];  // 32 KB
  __shared__ float redu[2][32][4];
  __shared__ float coefA[32], coefB[32];
  const int K = E_DIM;
  int tid = threadIdx.x;
  int w = tid >> 6, lane = tid & 63;
  int r0 = blockIdx.x * 32;

  const ushort* gA =
      A + ((size_t)r0 + (w & 1) * 16 + (lane >> 2)) * K + (lane & 3) * 8;
  ushort* lA = As + ((w & 1) * 16) * 32;
  const ushort* gB = B + ((size_t)w * 128 + (lane >> 2)) * K + (lane & 3) * 8;
  ushort* lB = Bs + (w * 128) * 32;

  int fro = (lane & 15) * 32 + (lane >> 4) * 8;
  const ushort* raA = As + fro;
  const ushort* raB = Bs + w * 128 * 32 + fro;

  f32x4 zero = {0.f, 0.f, 0.f, 0.f};
  f32x4 acc[2][8];
#pragma unroll
  for (int i = 0; i < 2; ++i)
#pragma unroll
    for (int j = 0; j < 8; ++j) acc[i][j] = zero;

  for (int kt = 0; kt < K; kt += 32) {
    __syncthreads();
    if (w < 2) gld16(gA + kt, lA);
#pragma unroll
    for (int i = 0; i < 8; ++i)
      gld16(gB + kt + (size_t)i * 16 * K, lB + i * 16 * 32);
    __syncthreads();
    bf16x8 af[2], bfv[8];
    af[0] = *reinterpret_cast<const bf16x8*>(raA);
    af[1] = *reinterpret_cast<const bf16x8*>(raA + 512);
#pragma unroll
    for (int j = 0; j < 8; ++j)
      bfv[j] = *reinterpret_cast<const bf16x8*>(raB + j * 512);
#pragma unroll
    for (int i = 0; i < 2; ++i)
#pragma unroll
      for (int j = 0; j < 8; ++j)
        acc[i][j] = __builtin_amdgcn_mfma_f32_16x16x32_bf16(af[i], bfv[j],
                                                            acc[i][j], 0, 0, 0);
  }

  // ---- fused epilogue: block-local row sums, no atomics -------------------
  float bvv[8];
#pragma unroll
  for (int j = 0; j < 8; ++j) bvv[j] = bias[w * 128 + j * 16 + (lane & 15)];
#pragma unroll
  for (int ti = 0; ti < 2; ++ti) {
#pragma unroll
    for (int reg = 0; reg < 4; ++reg) {
      float p2 = 0.f, pb = 0.f;
#pragma unroll
      for (int j = 0; j < 8; ++j) {
        float c = acc[ti][j][reg];
        p2 += c * c;
        pb += c * bvv[j];
      }
#pragma unroll
      for (int o = 1; o < 16; o <<= 1) {
        p2 += __shfl_xor(p2, o);
        pb += __shfl_xor(pb, o);
      }
      if ((lane & 15) == 0) {
        int row = ti * 16 + (lane >> 4) * 4 + reg;
        redu[0][row][w] = p2;
        redu[1][row][w] = pb;
      }
    }
  }
  __syncthreads();
  if (tid < 32) {
    int row = tid;
    float S0 = (redu[0][row][0] + redu[0][row][1]) +
               (redu[0][row][2] + redu[0][row][3]);
    float S1 = (redu[1][row][0] + redu[1][row][1]) +
               (redu[1][row][2] + redu[1][row][3]);
    float S2 = *bs_sb2;
    float se = S0 + 1e-30f;
    float rmx = frsq(se);
    float mxn = se * rmx;
    float xn = xn_arr[r0 + row];
    float aa = fatanh(fminf(xn, MAXN));
    float tt = ftanh(mxn * frcp(xn) * aa);
    float c = tt * rmx;
    float xy = c * S1, y2 = S2, x2 = tt * tt;
    float c1 = 1.f + 2.f * xy + y2, c2 = 1.f - x2;
    float iden = frcp(fmaxf(1.f + 2.f * xy + x2 * y2, 1e-15f));
    float cc1 = c1 * c * iden, cc2 = c2 * iden;
    float un2 =
        fmaxf(cc1 * cc1 * S0 + 2.f * cc1 * cc2 * S1 + cc2 * cc2 * S2, 0.f);
    float ue = un2 + 1e-30f;
    float run = frsq(ue);
    float un = ue * run;
    float ne = fminf(un, MAXN);
    float f = fatanh(ne) * run;
    coefA[row] = cc1 * f;
    coefB[row] = cc2 * f;
  }
  __syncthreads();
#pragma unroll
  for (int ti = 0; ti < 2; ++ti) {
#pragma unroll
    for (int reg = 0; reg < 4; ++reg) {
      int row = ti * 16 + (lane >> 4) * 4 + reg;
      float cA = coefA[row], cB = coefB[row];
      ushort* orow = qout + (size_t)(r0 + row) * E_DIM + w * 128 + (lane & 15);
#pragma unroll
      for (int j = 0; j < 8; ++j)
        orow[j * 16] = f2bf(cA * acc[ti][j][reg] + cB * bvv[j]);
    }
  }
}

// -------- bf16 MFMA GEMM: C[n][m] = sum_k A[n][k]*B[m][k], C fp32 ----------
__global__ __launch_bounds__(256) void k_gemm_bf16(
    const ushort* __restrict__ A, const ushort* __restrict__ B,
    float* __restrict__ C, int K, int M, int kseg,
    unsigned long long partStride) {
  __shared__ __align__(16) ushort As[128 * 32];
  __shared__ __align__(16) ushort Bs[128 * 32];
  int tid = threadIdx.x;
  int w = tid >> 6, lane = tid & 63;
  int wm = w >> 1, wn = w & 1;
  size_t row0 = (size_t)blockIdx.y * 128;
  size_t col0 = (size_t)blockIdx.x * 128;
  int k0 = blockIdx.z * kseg;

  const ushort* gA =
      A + (row0 + w * 32 + (lane >> 2)) * (size_t)K + (lane & 3) * 8 + k0;
  const ushort* gB =
      B + (col0 + w * 32 + (lane >> 2)) * (size_t)K + (lane & 3) * 8 + k0;
  ushort* lA = As + (w * 32) * 32;
  ushort* lB = Bs + (w * 32) * 32;
  const int rowK16 = 16 * K;

  int fro = (lane & 15) * 32 + (lane >> 4) * 8;
  const ushort* raA = As + (wm * 64) * 32 + fro;
  const ushort* raB = Bs + (wn * 64) * 32 + fro;

  f32x4 zero = {0.f, 0.f, 0.f, 0.f};
  f32x4 acc[4][4];
#pragma unroll
  for (int i = 0; i < 4; ++i)
#pragma unroll
    for (int j = 0; j < 4; ++j) acc[i][j] = zero;

  for (int kt = 0; kt < kseg; kt += 32) {
    __syncthreads();
    gld16(gA + kt, lA);
    gld16(gA + kt + rowK16, lA + 16 * 32);
    gld16(gB + kt, lB);
    gld16(gB + kt + rowK16, lB + 16 * 32);
    __syncthreads();
    bf16x8 af[4], bfv[4];
#pragma unroll
    for (int t = 0; t < 4; ++t) {
      af[t] = *reinterpret_cast<const bf16x8*>(raA + t * 512);
      bfv[t] = *reinterpret_cast<const bf16x8*>(raB + t * 512);
    }
#pragma unroll
    for (int i = 0; i < 4; ++i)
#pragma unroll
      for (int j = 0; j < 4; ++j)
        acc[i][j] = __builtin_amdgcn_mfma_f32_16x16x32_bf16(af[i], bfv[j],
                                                            acc[i][j], 0, 0, 0);
  }
  float* Cz = C + (size_t)blockIdx.z * partStride;
  int crow = wm * 64 + (lane >> 4) * 4;
  int ccol = (int)col0 + wn * 64 + (lane & 15);
#pragma unroll
  for (int ti = 0; ti < 4; ++ti) {
    size_t r = row0 + crow + ti * 16;
#pragma unroll
    for (int tj = 0; tj < 4; ++tj) {
      int cc = ccol + tj * 16;
#pragma unroll
      for (int reg = 0; reg < 4; ++reg)
        Cz[(r + reg) * (size_t)M + cc] = acc[ti][tj][reg];
    }
  }
}

// ---- attention: per (b,h) MFMA tile (unchanged) ---------------------------
__global__ __launch_bounds__(256) void k_attn(const ushort* __restrict__ q,
                                              const ushort* __restrict__ k,
                                              const ushort* __restrict__ v,
                                              float* __restrict__ o) {
  __shared__ __align__(16) ushort smem[27136];
  ushort* Qs = smem;
  ushort* Ks = smem + 9216;
  ushort* VTs = smem + 18432;
  ushort* Ps = smem;
  int bh = blockIdx.x;
  int b = bh >> 3, h = bh & 7;
  int tid = threadIdx.x;
  int w = tid >> 6, lane = tid & 63;
  const size_t BE = (size_t)B_DIM * E_DIM;
  size_t gbase = (size_t)b * E_DIM + (size_t)h * 64;

  {
    int s = tid >> 1, half = (tid & 1) * 32;
    const ushort* qr = q + gbase + (size_t)s * BE + half;
    const ushort* kr = k + gbase + (size_t)s * BE + half;
    const ushort* vr = v + gbase + (size_t)s * BE + half;
#pragma unroll
    for (int j = 0; j < 4; ++j) {
      *reinterpret_cast<uint4*>(&Qs[s * 72 + half + j * 8]) =
          *reinterpret_cast<const uint4*>(qr + j * 8);
      *reinterpret_cast<uint4*>(&Ks[s * 72 + half + j * 8]) =
          *reinterpret_cast<const uint4*>(kr + j * 8);
    }
    ushort tv[32];
#pragma unroll
    for (int j = 0; j < 4; ++j)
      *reinterpret_cast<uint4*>(&tv[j * 8]) =
          *reinterpret_cast<const uint4*>(vr + j * 8);
#pragma unroll
    for (int d = 0; d < 32; ++d) VTs[(half + d) * 136 + s] = tv[d];
  }
  __syncthreads();

  f32x4 zero = {0.f, 0.f, 0.f, 0.f};
  f32x4 sacc[2][8];
#pragma unroll
  for (int i = 0; i < 2; ++i)
#pragma unroll
    for (int j = 0; j < 8; ++j) sacc[i][j] = zero;
  {
    const ushort* qb = Qs + (w * 32 + (lane & 15)) * 72 + (lane >> 4) * 8;
    const ushort* kb = Ks + (lane & 15) * 72 + (lane >> 4) * 8;
#pragma unroll
    for (int kk = 0; kk < 2; ++kk) {
      bf16x8 a0 = *reinterpret_cast<const bf16x8*>(qb + kk * 32);
      bf16x8 a1 = *reinterpret_cast<const bf16x8*>(qb + 16 * 72 + kk * 32);
#pragma unroll
      for (int tj = 0; tj < 8; ++tj) {
        bf16x8 bf = *reinterpret_cast<const bf16x8*>(kb + tj * 16 * 72 + kk * 32);
        sacc[0][tj] = __builtin_amdgcn_mfma_f32_16x16x32_bf16(a0, bf,
                                                              sacc[0][tj], 0, 0, 0);
        sacc[1][tj] = __builtin_amdgcn_mfma_f32_16x16x32_bf16(a1, bf,
                                                              sacc[1][tj], 0, 0, 0);
      }
    }
  }

#pragma unroll
  for (int ti = 0; ti < 2; ++ti) {
#pragma unroll
    for (int r = 0; r < 4; ++r) {
      float mx = -1e30f;
#pragma unroll
      for (int tj = 0; tj < 8; ++tj) mx = fmaxf(mx, sacc[ti][tj][r]);
      mx = fmaxf(mx, __shfl_xor(mx, 1));
      mx = fmaxf(mx, __shfl_xor(mx, 2));
      mx = fmaxf(mx, __shfl_xor(mx, 4));
      mx = fmaxf(mx, __shfl_xor(mx, 8));
      float l = 0.f;
#pragma unroll
      for (int tj = 0; tj < 8; ++tj) {
        float e = fexp2((sacc[ti][tj][r] - mx) * (0.125f * 1.44269504f));
        sacc[ti][tj][r] = e;
        l += e;
      }
      l += __shfl_xor(l, 1);
      l += __shfl_xor(l, 2);
      l += __shfl_xor(l, 4);
      l += __shfl_xor(l, 8);
      float inv = frcp(l);
#pragma unroll
      for (int tj = 0; tj < 8; ++tj) sacc[ti][tj][r] *= inv;
    }
  }

  __syncthreads();
  {
    int qr0 = w * 32 + (lane >> 4) * 4;
    int kc = lane & 15;
#pragma unroll
    for (int ti = 0; ti < 2; ++ti)
#pragma unroll
      for (int tj = 0; tj < 8; ++tj)
#pragma unroll
        for (int r = 0; r < 4; ++r)
          Ps[(qr0 + ti * 16 + r) * 136 + tj * 16 + kc] =
              f2bf(sacc[ti][tj][r]);
  }
  __syncthreads();

  f32x4 oacc[2][4];
#pragma unroll
  for (int i = 0; i < 2; ++i)
#pragma unroll
    for (int j = 0; j < 4; ++j) oacc[i][j] = zero;
  {
    const ushort* pb = Ps + (w * 32 + (lane & 15)) * 136 + (lane >> 4) * 8;
    const ushort* vb = VTs + (lane & 15) * 136 + (lane >> 4) * 8;
#pragma unroll
    for (int kk = 0; kk < 4; ++kk) {
      bf16x8 a0 = *reinterpret_cast<const bf16x8*>(pb + kk * 32);
      bf16x8 a1 = *reinterpret_cast<const bf16x8*>(pb + 16 * 136 + kk * 32);
#pragma unroll
      for (int tj = 0; tj < 4; ++tj) {
        bf16x8 bv = *reinterpret_cast<const bf16x8*>(vb + tj * 16 * 136 + kk * 32);
        oacc[0][tj] = __builtin_amdgcn_mfma_f32_16x16x32_bf16(a0, bv,
                                                              oacc[0][tj], 0, 0, 0);
        oacc[1][tj] = __builtin_amdgcn_mfma_f32_16x16x32_bf16(a1, bv,
                                                              oacc[1][tj], 0, 0, 0);
      }
    }
  }

  {
    int qr0 = w * 32 + (lane >> 4) * 4;
    int dc = lane & 15;
#pragma unroll
    for (int ti = 0; ti < 2; ++ti)
#pragma unroll
      for (int tj = 0; tj < 4; ++tj)
#pragma unroll
        for (int r = 0; r < 4; ++r)
          o[(size_t)(qr0 + ti * 16 + r) * BE + gbase + tj * 16 + dc] =
              oacc[ti][tj][r];
  }
}

// ---- expmap0 rowwise, 2 rows/wave ----------------------------------------
__global__ __launch_bounds__(256) void k_expmap_rows(const float* __restrict__ in,
                                                     ushort* __restrict__ out,
                                                     float* __restrict__ nrm) {
  int wv = threadIdx.x >> 6, lane = threadIdx.x & 63;
  int row = blockIdx.x * 8 + wv * 2;
  size_t base = (size_t)row * E_DIM + lane * 8;
  float v[2][8];
  *(float4*)&v[0][0] = *(const float4*)(in + base);
  *(float4*)&v[0][4] = *(const float4*)(in + base + 4);
  *(float4*)&v[1][0] = *(const float4*)(in + base + E_DIM);
  *(float4*)&v[1][4] = *(const float4*)(in + base + E_DIM + 4);
  float s[2] = {0.f, 0.f};
#pragma unroll
  for (int i = 0; i < 8; ++i) {
    s[0] += v[0][i] * v[0][i];
    s[1] += v[1][i] * v[1][i];
  }
  waveRed<2>(s);
#pragma unroll
  for (int r2 = 0; r2 < 2; ++r2) {
    float se = s[r2] + 1e-30f;
    float rn = frsq(se);
    float n = se * rn;
    float th = ftanh(n);
    float f = th * rn;
    uint4 o = {pack2(v[r2][0] * f, v[r2][1] * f), pack2(v[r2][2] * f, v[r2][3] * f),
               pack2(v[r2][4] * f, v[r2][5] * f), pack2(v[r2][6] * f, v[r2][7] * f)};
    *reinterpret_cast<uint4*>(out + base + r2 * E_DIM) = o;
    if (lane == 0) nrm[row + r2] = th;
  }
}

// ---- attn-out epilogue (round-6 form: 1 row/wave, 3 small chains) ---------
__global__ __launch_bounds__(256) void k_epi_attnout(
    float* __restrict__ mo, const float* __restrict__ xn_arr,
    const float* __restrict__ bo, const float* __restrict__ xin,
    const float* __restrict__ g2, const float* __restrict__ b2,
    ushort* __restrict__ h2, float* __restrict__ h2n) {
  int row = blockIdx.x * 4 + (threadIdx.x >> 6);
  int lane = threadIdx.x & 63;
  size_t base = (size_t)row * E_DIM + lane * 8;
  float m[8], bv[8];
  *(float4*)&m[0] = *(const float4*)(mo + base);
  *(float4*)&m[4] = *(const float4*)(mo + base + 4);
  *(float4*)&bv[0] = *(const float4*)(bo + lane * 8);
  *(float4*)&bv[4] = *(const float4*)(bo + lane * 8 + 4);
  float s[5] = {0.f, 0.f, 0.f, 0.f, 0.f};
#pragma unroll
  for (int i = 0; i < 8; ++i) {
    s[0] += m[i] * m[i]; s[1] += m[i] * bv[i]; s[2] += bv[i] * bv[i];
    s[3] += m[i]; s[4] += bv[i];
  }
  waveRed<5>(s);
  float se = s[0] + 1e-30f;
  float rmx = frsq(se);
  float mxn = se * rmx;
  float xn = xn_arr[row];
  float aa = fatanh(fminf(xn, MAXN));
  float tt = ftanh(mxn * frcp(xn) * aa);
  float c = tt * rmx;
  float xy = c * s[1], y2 = s[2], x2 = tt * tt;
  float c1 = 1.f + 2.f * xy + y2, c2 = 1.f - x2;
  float iden = frcp(fmaxf(1.f + 2.f * xy + x2 * y2, 1e-15f));
  float cc1 = c1 * c * iden, cc2 = c2 * iden;
  float un2 = fmaxf(cc1 * cc1 * s[0] + 2.f * cc1 * cc2 * s[1] + cc2 * cc2 * s[2], 0.f);
  float ue = un2 + 1e-30f;
  float run = frsq(ue);
  float un = ue * run;
  float ps = un > MAXN ? MAXN * run : 1.f;
  float zn = fminf(un, MAXN);
  float z[8];
#pragma unroll
  for (int i = 0; i < 8; ++i) z[i] = (cc1 * m[i] + cc2 * bv[i]) * ps;
  float sumz = ps * (cc1 * s[3] + cc2 * s[4]);
  float r[8];
  *(float4*)&r[0] = *(const float4*)(xin + base);
  *(float4*)&r[4] = *(const float4*)(xin + base + 4);
  float t2[3] = {0.f, 0.f, 0.f};
#pragma unroll
  for (int i = 0; i < 8; ++i) {
    t2[0] += z[i] * r[i]; t2[1] += r[i] * r[i]; t2[2] += r[i];
  }
  waveRed<3>(t2);
  float xy2 = t2[0], y22 = t2[1], x22 = zn * zn;
  float d1 = 1.f + 2.f * xy2 + y22, d2 = 1.f - x22;
  float iden2 = frcp(fmaxf(1.f + 2.f * xy2 + x22 * y22, 1e-15f));
  float wn2 = fmaxf(iden2 * iden2 *
                        (d1 * d1 * x22 + 2.f * d1 * d2 * xy2 + d2 * d2 * y22),
                    0.f);
  float we = wn2 + 1e-30f;
  float rwn = frsq(we);
  float wn = we * rwn;
  float ps2 = wn > MAXN ? MAXN * rwn : 1.f;
  float w[8];
#pragma unroll
  for (int i = 0; i < 8; ++i) w[i] = (d1 * z[i] + d2 * r[i]) * iden2 * ps2;
  *(float4*)(mo + base) = *(float4*)&w[0];
  *(float4*)(mo + base + 4) = *(float4*)&w[4];
  float ne = fminf(wn, MAXN);
  float ath = fatanh(ne);
  float lf = ath * frcp(ne);
  float sumw = ps2 * iden2 * (d1 * sumz + d2 * t2[2]);
  float mu = lf * sumw * (1.f / 512.f);
  float var = fmaxf(ath * ath * (1.f / 512.f) - mu * mu, 0.f);
  float rstd = frsq(var + 1e-5f);
  float gv[8], b2v[8];
  *(float4*)&gv[0] = *(const float4*)(g2 + lane * 8);
  *(float4*)&gv[4] = *(const float4*)(g2 + lane * 8 + 4);
  *(float4*)&b2v[0] = *(const float4*)(b2 + lane * 8);
  *(float4*)&b2v[4] = *(const float4*)(b2 + lane * 8 + 4);
  float e[8];
  float s3[1] = {0.f};
#pragma unroll
  for (int i = 0; i < 8; ++i) {
    e[i] = (lf * w[i] - mu) * rstd * gv[i] + b2v[i];
    s3[0] += e[i] * e[i];
  }
  waveRed<1>(s3);
  float s3e = s3[0] + 1e-30f;
  float rn3 = frsq(s3e);
  float n3 = s3e * rn3;
  float en = ftanh(n3);
  float f = en * rn3;
  if (en > MAXN) f *= MAXN * frcp(en);
  uint4 o = {pack2(e[0] * f, e[1] * f), pack2(e[2] * f, e[3] * f),
             pack2(e[4] * f, e[5] * f), pack2(e[6] * f, e[7] * f)};
  *reinterpret_cast<uint4*>(h2 + base) = o;
  if (lane == 0) h2n[row] = fminf(en, MAXN);
}

// ---- FFN1 epilogue (2 rows/wave of F=2048) -> bf16 ------------------------
__global__ __launch_bounds__(256) void k_epi_ffn1(const float* __restrict__ mr_,
                                                  const float* __restrict__ xn_arr,
                                                  const float* __restrict__ bias,
                                                  ushort* __restrict__ hid,
                                                  float* __restrict__ hn_out) {
  int wv = threadIdx.x >> 6, lane = threadIdx.x & 63;
  int row = blockIdx.x * 8 + wv * 2;
  const float* mr = mr_ + (size_t)row * F_DIM + lane * 32;
  const float* br = bias + lane * 32;
  float m[2][32], bv[32];
#pragma unroll
  for (int j = 0; j < 8; ++j) {
    *(float4*)&m[0][j * 4] = *(const float4*)(mr + j * 4);
    *(float4*)&m[1][j * 4] = *(const float4*)(mr + F_DIM + j * 4);
    *(float4*)&bv[j * 4] = *(const float4*)(br + j * 4);
  }
  float s[5];
#pragma unroll
  for (int i = 0; i < 5; ++i) s[i] = 0.f;
#pragma unroll
  for (int i = 0; i < 32; ++i) {
#pragma unroll
    for (int r2 = 0; r2 < 2; ++r2) {
      s[r2 * 2 + 0] += m[r2][i] * m[r2][i];
      s[r2 * 2 + 1] += m[r2][i] * bv[i];
    }
    s[4] += bv[i] * bv[i];
  }
  waveRed<5>(s);
  float s2[2] = {0.f, 0.f};
#pragma unroll
  for (int r2 = 0; r2 < 2; ++r2) {
    float S0 = s[r2 * 2 + 0], S1 = s[r2 * 2 + 1], S2 = s[4];
    float se = S0 + 1e-30f;
    float rmx = frsq(se);
    float mxn = se * rmx;
    float xn = xn_arr[row + r2];
    float aa = fatanh(fminf(xn, MAXN));
    float tt = ftanh(mxn * frcp(xn) * aa);
    float c = tt * rmx;
    float xy = c * S1, y2 = S2, x2 = tt * tt;
    float c1 = 1.f + 2.f * xy + y2, c2 = 1.f - x2;
    float iden = frcp(fmaxf(1.f + 2.f * xy + x2 * y2, 1e-15f));
    float cc1 = c1 * c * iden, cc2 = c2 * iden;
    float un2 = fmaxf(cc1 * cc1 * S0 + 2.f * cc1 * cc2 * S1 + cc2 * cc2 * S2, 0.f);
    float ue = un2 + 1e-30f;
    float run = frsq(ue);
    float un = ue * run;
    float zn = fminf(un, MAXN);
    float lf = fatanh(zn) * run;
#pragma unroll
    for (int i = 0; i < 32; ++i) {
      m[r2][i] = fmaxf((cc1 * m[r2][i] + cc2 * bv[i]) * lf, 0.f);
      s2[r2] += m[r2][i] * m[r2][i];
    }
  }
  waveRed<2>(s2);
#pragma unroll
  for (int r2 = 0; r2 < 2; ++r2) {
    float s2e = s2[r2] + 1e-30f;
    float rrn = frsq(s2e);
    float rn = s2e * rrn;
    float en = ftanh(rn);
    float f = en * rrn;
    if (en > MAXN) f *= MAXN * frcp(en);
    ushort* hr = hid + (size_t)(row + r2) * F_DIM + lane * 32;
#pragma unroll
    for (int j = 0; j < 4; ++j) {
      uint4 o = {pack2(m[r2][j * 8 + 0] * f, m[r2][j * 8 + 1] * f),
                 pack2(m[r2][j * 8 + 2] * f, m[r2][j * 8 + 3] * f),
                 pack2(m[r2][j * 8 + 4] * f, m[r2][j * 8 + 5] * f),
                 pack2(m[r2][j * 8 + 6] * f, m[r2][j * 8 + 7] * f)};
      *reinterpret_cast<uint4*>(hr + j * 8) = o;
    }
    if (lane == 0) hn_out[row + r2] = fminf(en, MAXN);
  }
}

// ---- final epilogue (2 rows/wave): 2-way split-K sum + man_linear(W2) +
// mob_relu + residual mobius_add + projx -> out fp32 ------------------------
__global__ __launch_bounds__(256) void k_epi_final(
    const float* __restrict__ m2, const float* __restrict__ xn_arr,
    const float* __restrict__ bias, const float* __restrict__ res,
    float* __restrict__ out) {
  int wv = threadIdx.x >> 6, lane = threadIdx.x & 63;
  int row = blockIdx.x * 8 + wv * 2;
  size_t base = (size_t)row * E_DIM + lane * 8;
  const size_t P2 = (size_t)CH * E_DIM;
  float m[2][8], bv[8], q[2][8];
#pragma unroll
  for (int r2 = 0; r2 < 2; ++r2) {
    float ta[8], tb[8];
    *(float4*)&ta[0] = *(const float4*)(m2 + base + r2 * E_DIM);
    *(float4*)&ta[4] = *(const float4*)(m2 + base + r2 * E_DIM + 4);
    *(float4*)&tb[0] = *(const float4*)(m2 + P2 + base + r2 * E_DIM);
    *(float4*)&tb[4] = *(const float4*)(m2 + P2 + base + r2 * E_DIM + 4);
#pragma unroll
    for (int i = 0; i < 8; ++i) m[r2][i] = ta[i] + tb[i];
    *(float4*)&q[r2][0] = *(const float4*)(res + base + r2 * E_DIM);
    *(float4*)&q[r2][4] = *(const float4*)(res + base + r2 * E_DIM + 4);
  }
  *(float4*)&bv[0] = *(const float4*)(bias + lane * 8);
  *(float4*)&bv[4] = *(const float4*)(bias + lane * 8 + 4);
  float s[7];
#pragma unroll
  for (int i = 0; i < 7; ++i) s[i] = 0.f;
#pragma unroll
  for (int i = 0; i < 8; ++i) {
#pragma unroll
    for (int r2 = 0; r2 < 2; ++r2) {
      s[r2 * 3 + 0] += m[r2][i] * m[r2][i];
      s[r2 * 3 + 1] += m[r2][i] * bv[i];
      s[r2 * 3 + 2] += q[r2][i] * q[r2][i];
    }
    s[6] += bv[i] * bv[i];
  }
  waveRed<7>(s);
  float r[2][8];
  float s2[4];
#pragma unroll
  for (int i = 0; i < 4; ++i) s2[i] = 0.f;
#pragma unroll
  for (int r2 = 0; r2 < 2; ++r2) {
    float S0 = s[r2 * 3 + 0], S1 = s[r2 * 3 + 1], S2 = s[6];
    float se = S0 + 1e-30f;
    float rmx = frsq(se);
    float mxn = se * rmx;
    float xn = xn_arr[row + r2];
    float aa = fatanh(fminf(xn, MAXN));
    float tt = ftanh(mxn * frcp(xn) * aa);
    float c = tt * rmx;
    float xy = c * S1, y2 = S2, x2 = tt * tt;
    float c1 = 1.f + 2.f * xy + y2, c2 = 1.f - x2;
    float iden = frcp(fmaxf(1.f + 2.f * xy + x2 * y2, 1e-15f));
    float cc1 = c1 * c * iden, cc2 = c2 * iden;
    float un2 = fmaxf(cc1 * cc1 * S0 + 2.f * cc1 * cc2 * S1 + cc2 * cc2 * S2, 0.f);
    float ue = un2 + 1e-30f;
    float run = frsq(ue);
    float un = ue * run;
    float zn = fminf(un, MAXN);
    float lf = fatanh(zn) * run;
#pragma unroll
    for (int i = 0; i < 8; ++i) {
      r[r2][i] = fmaxf((cc1 * m[r2][i] + cc2 * bv[i]) * lf, 0.f);
      s2[r2 * 2 + 0] += r[r2][i] * r[r2][i];
      s2[r2 * 2 + 1] += r[r2][i] * q[r2][i];
    }
  }
  waveRed<4>(s2);
#pragma unroll
  for (int r2 = 0; r2 < 2; ++r2) {
    float s2e = s2[r2 * 2 + 0] + 1e-30f;
    float rrn = frsq(s2e);
    float rn = s2e * rrn;
    float en = ftanh(rn);
    float f = en * rrn;
    if (en > MAXN) f *= MAXN * frcp(en);
    float hn = fminf(en, MAXN);
    float xy2 = f * s2[r2 * 2 + 1], y22 = s[r2 * 3 + 2], x22 = hn * hn;
    float d1 = 1.f + 2.f * xy2 + y22, d2 = 1.f - x22;
    float iden2 = frcp(fmaxf(1.f + 2.f * xy2 + x22 * y22, 1e-15f));
    float wn2 = fmaxf(iden2 * iden2 *
                          (d1 * d1 * x22 + 2.f * d1 * d2 * xy2 + d2 * d2 * y22),
                      0.f);
    float we = wn2 + 1e-30f;
    float rwn = frsq(we);
    float wn = we * rwn;
    float ps2 = wn > MAXN ? MAXN * rwn : 1.f;
    float w[8];
#pragma unroll
    for (int i = 0; i < 8; ++i)
      w[i] = (d1 * r[r2][i] * f + d2 * q[r2][i]) * iden2 * ps2;
    *(float4*)(out + base + r2 * E_DIM) = *(float4*)&w[0];
    *(float4*)(out + base + r2 * E_DIM + 4) = *(float4*)&w[4];
  }
}

extern "C" void kernel_launch(void* const* d_in, const int* in_sizes, int n_in,
                              void* d_out, int out_size, void* d_ws,
                              size_t ws_size, hipStream_t stream) {
  const float* x   = (const float*)d_in[0];
  const float* g1  = (const float*)d_in[1];
  const float* lb1 = (const float*)d_in[2];
  const float* g2  = (const float*)d_in[3];
  const float* lb2 = (const float*)d_in[4];
  const float* Wq  = (const float*)d_in[5];
  const float* bq  = (const float*)d_in[6];
  const float* Wk  = (const float*)d_in[7];
  const float* bk  = (const float*)d_in[8];
  const float* Wv  = (const float*)d_in[9];
  const float* bv  = (const float*)d_in[10];
  const float* Wo  = (const float*)d_in[11];
  const float* bo  = (const float*)d_in[12];
  const float* W1  = (const float*)d_in[13];
  const float* b1  = (const float*)d_in[14];
  const float* W2  = (const float*)d_in[15];
  const float* b2  = (const float*)d_in[16];
  float* out = (float*)d_out;
  float* ws = (float*)d_ws;

  const size_t NE = (size_t)N_ROWS * E_DIM;          // 16,777,216
  const size_t WF = (4 * (size_t)E_DIM * E_DIM +
                     2 * (size_t)F_DIM * E_DIM) / 2; // 1,572,864 floats
  float* R_b = ws;                   // NE: attn-out fp32 / mo / res2
  float* R_a = ws + NE;              // NE/2: h1_bf16 -> oe_bf16 -> h2_bf16
  float* R_q = ws + NE + NE / 2;     // NE/2: q_bf16 -> m1 lower -> m2 partials
  float* R_k = ws + 2 * NE;          // NE/2: k_bf16 -> m1 upper
  float* R_v = ws + 2 * NE + NE / 2; // NE/2: v_bf16 -> hid_bf16
  ushort* wqb = (ushort*)(ws + 3 * NE);
  ushort* wkb = wqb + (size_t)E_DIM * E_DIM;
  ushort* wvb = wkb + (size_t)E_DIM * E_DIM;
  ushort* wob = wvb + (size_t)E_DIM * E_DIM;
  ushort* w1b = wob + (size_t)E_DIM * E_DIM;
  ushort* w2b = w1b + (size_t)F_DIM * E_DIM;
  float* n_h1 = ws + 3 * NE + WF;
  float* n_oe = n_h1 + N_ROWS;
  float* n_h2 = n_oe + N_ROWS;
  float* n_h3 = n_h2 + N_ROWS;
  float* bs = n_h3 + N_ROWS;  // 16 scalar sums
  const size_t need = (3 * NE + WF + 4 * (size_t)N_ROWS + 16) * sizeof(float);
  if (ws_size < need) return;

  k_bsums<<<1, 64, 0, stream>>>(bq, bk, bv, g1, lb1, bs);
  k_f2bf<<<256, 256, 0, stream>>>(Wq, wqb, E_DIM * E_DIM);
  k_f2bf<<<256, 256, 0, stream>>>(Wk, wkb, E_DIM * E_DIM);
  k_f2bf<<<256, 256, 0, stream>>>(Wv, wvb, E_DIM * E_DIM);
  k_f2bf<<<256, 256, 0, stream>>>(Wo, wob, E_DIM * E_DIM);
  k_f2bf<<<512, 256, 0, stream>>>(W1, w1b, F_DIM * E_DIM);
  k_f2bf<<<512, 256, 0, stream>>>(W2, w2b, F_DIM * E_DIM);

  ushort* h1b = (ushort*)R_a;
  ushort* qb = (ushort*)R_q;
  ushort* kb = (ushort*)R_k;
  ushort* vb = (ushort*)R_v;

  // Phase A: stage1 + fused QKV projections (GEMM + epilogue in one kernel)
  k_stage1<<<N_ROWS / 8, 256, 0, stream>>>(x, g1, lb1, bs, h1b, n_h1);
  k_qkv_fused<<<N_ROWS / 32, 256, 0, stream>>>(h1b, wqb, n_h1, bq, bs + 0, qb);
  k_qkv_fused<<<N_ROWS / 32, 256, 0, stream>>>(h1b, wkb, n_h1, bk, bs + 1, kb);
  k_qkv_fused<<<N_ROWS / 32, 256, 0, stream>>>(h1b, wvb, n_h1, bv, bs + 2, vb);

  // Phase B: MFMA attention -> R_b fp32; expmap0 -> oe bf16 (R_a, h1 dead)
  k_attn<<<B_DIM * 8, 256, 0, stream>>>(qb, kb, vb, R_b);
  ushort* oeb = (ushort*)R_a;
  k_expmap_rows<<<N_ROWS / 8, 256, 0, stream>>>(R_b, oeb, n_oe);

  // Phase C: Wo projection -> R_b; attnout: res2 in-place, h2 bf16 -> R_a
  ushort* h2b = (ushort*)R_a;  // oe dead once GEMM Wo has read it
  dim3 gQ(E_DIM / 128, N_ROWS / 128, 1);
  k_gemm_bf16<<<gQ, 256, 0, stream>>>(oeb, wob, R_b, E_DIM, E_DIM, E_DIM, 0);
  k_epi_attnout<<<N_ROWS / 4, 256, 0, stream>>>(R_b, n_oe, bo, x, g2, lb2,
                                                h2b, n_h2);

  // Phase D: FFN chunked (CH=8192). m1 spans R_q+R_k (64MB contiguous),
  // hid in R_v, split-K2 partials reuse R_q (m1 dead). Stream-ordered.
  float* m1 = R_q;
  ushort* hidb = (ushort*)R_v;
  float* m2 = R_q;
  for (int c = 0; c < N_ROWS / CH; ++c) {
    size_t ro = (size_t)c * CH;
    k_gemm_bf16<<<dim3(F_DIM / 128, CH / 128, 1), 256, 0, stream>>>(
        h2b + ro * E_DIM, w1b, m1, E_DIM, F_DIM, E_DIM, 0);
    k_epi_ffn1<<<CH / 8, 256, 0, stream>>>(m1, n_h2 + ro, b1, hidb, n_h3 + ro);
    k_gemm_bf16<<<dim3(E_DIM / 128, CH / 128, 2), 256, 0, stream>>>(
        hidb, w2b, m2, F_DIM, E_DIM, F_DIM / 2,
        (unsigned long long)((size_t)CH * E_DIM));
    k_epi_final<<<CH / 8, 256, 0, stream>>>(m2, n_h3 + ro, b2,
                                            R_b + ro * E_DIM, out + ro * E_DIM);
  }
}

// Round 5
// 844.041 us; speedup vs baseline: 1.2309x; 1.0352x over previous
//
// Hyperbolic (Poincare ball) transformer block — MI355X round 10.
// Round-9 post-mortem: k_qkv_fused (32-row tile) was a skinny-GEMM
// regression (MfmaUtil 9.6%, 66us x3). Revert QKV to the proven split
// gemm+epi structure, and recover the C-traffic savings with BF16
// INTERMEDIATES instead:
//  * k_gemm_bf16 gains an obf flag: C written as bf16 (QKV, Wo, FFN1).
//  * k_attn writes bf16; expmap/epi kernels read bf16 (bit-shift unpack).
//  * attnout writes the residual res2 as bf16 (read by epi_final).
//  * FFN2 split-K partials stay fp32 (summed before rounding).
//  ~510 MB HBM traffic removed vs fp32 intermediates.
// Kept from round 9: CH=8192 FFN + split-K2, round-6 attnout structure,
// round-7 2-rows/wave epi_qkv/ffn1/final, stage1 single-chain.
#include <hip/hip_runtime.h>
#include <math.h>

#define S_DIM 128
#define B_DIM 256
#define E_DIM 512
#define F_DIM 2048
#define N_ROWS (S_DIM * B_DIM) /* 32768 */
#define CH 8192                /* FFN row chunk */
#define MAXN 0.99999f          /* 1 - 1e-5 */

typedef __bf16 bf16x8 __attribute__((ext_vector_type(8)));
typedef float f32x4 __attribute__((ext_vector_type(4)));

// ---- fast-math helpers (1-instr HW transcendentals) -----------------------
__device__ __forceinline__ float frcp(float x) { return __builtin_amdgcn_rcpf(x); }
__device__ __forceinline__ float frsq(float x) { return __builtin_amdgcn_rsqf(x); }
__device__ __forceinline__ float fexp2(float x) { return __builtin_amdgcn_exp2f(x); }
__device__ __forceinline__ float flog2(float x) { return __builtin_amdgcn_logf(x); }
__device__ __forceinline__ float fatanh(float x) {
  return 0.34657359f * flog2((1.f + x) * frcp(1.f - x));
}
__device__ __forceinline__ float ftanh(float x) {
  float t = fexp2(x * -2.88539008f);
  return (1.f - t) * frcp(1.f + t);
}

__device__ __forceinline__ ushort f2bf(float f) {
  __bf16 h = (__bf16)f;
  return __builtin_bit_cast(ushort, h);
}
__device__ __forceinline__ uint pack2(float a, float b) {
  return (uint)f2bf(a) | ((uint)f2bf(b) << 16);
}
// load 8 bf16 -> 8 fp32 (bit-shift unpack, no cvt chain)
__device__ __forceinline__ void ldbf8(const ushort* p, float (&f)[8]) {
  uint4 u = *reinterpret_cast<const uint4*>(p);
  f[0] = __uint_as_float(u.x << 16);
  f[1] = __uint_as_float(u.x & 0xFFFF0000u);
  f[2] = __uint_as_float(u.y << 16);
  f[3] = __uint_as_float(u.y & 0xFFFF0000u);
  f[4] = __uint_as_float(u.z << 16);
  f[5] = __uint_as_float(u.z & 0xFFFF0000u);
  f[6] = __uint_as_float(u.w << 16);
  f[7] = __uint_as_float(u.w & 0xFFFF0000u);
}

__device__ __forceinline__ void gld16(const ushort* g, ushort* l) {
  __builtin_amdgcn_global_load_lds(
      (const __attribute__((address_space(1))) void*)g,
      (__attribute__((address_space(3))) void*)l, 16, 0, 0);
}

// ---- wave-wide butterfly reduction of K values (all lanes get results) ----
template <int K>
__device__ __forceinline__ void waveRed(float (&v)[K]) {
#pragma unroll
  for (int o = 1; o < 64; o <<= 1) {
#pragma unroll
    for (int i = 0; i < K; ++i) v[i] += __shfl_xor(v[i], o);
  }
}

// ---------------- fp32 -> bf16 convert (weights) ---------------------------
__global__ __launch_bounds__(256) void k_f2bf(const float* __restrict__ in,
                                              ushort* __restrict__ out, int n) {
  for (int i = blockIdx.x * 256 + threadIdx.x; i < n; i += gridDim.x * 256)
    out[i] = f2bf(in[i]);
}

// ---- one-wave bias/param sums kernel --------------------------------------
// bs: [0]=Sbq2 [1]=Sbk2 [2]=Sbv2 [7]=Sg1_2 [8]=Sg1lb1 [9]=Slb1_2
__global__ void k_bsums(const float* __restrict__ bq, const float* __restrict__ bk,
                        const float* __restrict__ bv, const float* __restrict__ g1,
                        const float* __restrict__ lb1, float* __restrict__ bs) {
  int lane = threadIdx.x;
  float p[6];
#pragma unroll
  for (int i = 0; i < 6; ++i) p[i] = 0.f;
  for (int i = lane; i < E_DIM; i += 64) {
    float a = bq[i]; p[0] += a * a;
    a = bk[i]; p[1] += a * a;
    a = bv[i]; p[2] += a * a;
    float g = g1[i], l = lb1[i];
    p[3] += g * g; p[4] += g * l; p[5] += l * l;
  }
  waveRed<6>(p);
  if (lane == 0) {
    bs[0] = p[0]; bs[1] = p[1]; bs[2] = p[2];
    bs[7] = p[3]; bs[8] = p[4]; bs[9] = p[5];
  }
}

// ---- stage 1: h1 = expmap0(LN(logmap0(x))) -> bf16. 2 rows/wave. ----------
__global__ __launch_bounds__(256) void k_stage1(
    const float* __restrict__ x, const float* __restrict__ g,
    const float* __restrict__ bb, const float* __restrict__ bs,
    ushort* __restrict__ h, float* __restrict__ hn) {
  int wv = threadIdx.x >> 6, lane = threadIdx.x & 63;
  int row = blockIdx.x * 8 + wv * 2;
  size_t base = (size_t)row * E_DIM + lane * 8;
  float v[2][8], gv[8], bv[8];
  *(float4*)&v[0][0] = *(const float4*)(x + base);
  *(float4*)&v[0][4] = *(const float4*)(x + base + 4);
  *(float4*)&v[1][0] = *(const float4*)(x + base + E_DIM);
  *(float4*)&v[1][4] = *(const float4*)(x + base + E_DIM + 4);
  *(float4*)&gv[0] = *(const float4*)(g + lane * 8);
  *(float4*)&gv[4] = *(const float4*)(g + lane * 8 + 4);
  *(float4*)&bv[0] = *(const float4*)(bb + lane * 8);
  *(float4*)&bv[4] = *(const float4*)(bb + lane * 8 + 4);
  float s[10];
#pragma unroll
  for (int i = 0; i < 10; ++i) s[i] = 0.f;
#pragma unroll
  for (int i = 0; i < 8; ++i) {
    float gg = gv[i] * gv[i], gb = gv[i] * bv[i];
#pragma unroll
    for (int r2 = 0; r2 < 2; ++r2) {
      float vv = v[r2][i];
      s[r2 * 5 + 0] += vv * vv;
      s[r2 * 5 + 1] += vv;
      s[r2 * 5 + 2] += vv * vv * gg;
      s[r2 * 5 + 3] += vv * gg;
      s[r2 * 5 + 4] += vv * gb;
    }
  }
  waveRed<10>(s);
  float Sg2 = bs[7], Sgb = bs[8], Sb2 = bs[9];
#pragma unroll
  for (int r2 = 0; r2 < 2; ++r2) {
    float T0 = s[r2 * 5 + 0], T1 = s[r2 * 5 + 1], T2 = s[r2 * 5 + 2];
    float T3 = s[r2 * 5 + 3], T4 = s[r2 * 5 + 4];
    float se = T0 + 1e-30f;
    float rn = frsq(se);
    float n = se * rn;
    float a = fatanh(fminf(n, MAXN)) * rn;
    float mu = a * T1 * (1.f / 512.f);
    float var = fmaxf(a * a * T0 * (1.f / 512.f) - mu * mu, 0.f);
    float rstd = frsq(var + 1e-5f);
    float A = a * rstd, B = -mu * rstd;
    float se2 = fmaxf(A * A * T2 + 2.f * A * B * T3 + 2.f * A * T4 +
                          B * B * Sg2 + 2.f * B * Sgb + Sb2, 0.f) + 1e-30f;
    float rn2 = frsq(se2);
    float n2 = se2 * rn2;
    float th = ftanh(n2);
    float f = th * rn2;
    float e[8];
#pragma unroll
    for (int i = 0; i < 8; ++i) e[i] = (A * v[r2][i] + B) * gv[i] + bv[i];
    uint4 o = {pack2(e[0] * f, e[1] * f), pack2(e[2] * f, e[3] * f),
               pack2(e[4] * f, e[5] * f), pack2(e[6] * f, e[7] * f)};
    *reinterpret_cast<uint4*>(h + base + r2 * E_DIM) = o;
    if (lane == 0) hn[row + r2] = th;
  }
}

// -------- bf16 MFMA GEMM: C[n][m] = sum_k A[n][k]*B[m][k] ------------------
// obf=0: C fp32 (split-K partials). obf=1: C bf16 (norm-chain intermediates).
__global__ __launch_bounds__(256) void k_gemm_bf16(
    const ushort* __restrict__ A, const ushort* __restrict__ B,
    float* __restrict__ C, int K, int M, int kseg,
    unsigned long long partStride, int obf) {
  __shared__ __align__(16) ushort As[128 * 32];
  __shared__ __align__(16) ushort Bs[128 * 32];
  int tid = threadIdx.x;
  int w = tid >> 6, lane = tid & 63;
  int wm = w >> 1, wn = w & 1;
  size_t row0 = (size_t)blockIdx.y * 128;
  size_t col0 = (size_t)blockIdx.x * 128;
  int k0 = blockIdx.z * kseg;

  const ushort* gA =
      A + (row0 + w * 32 + (lane >> 2)) * (size_t)K + (lane & 3) * 8 + k0;
  const ushort* gB =
      B + (col0 + w * 32 + (lane >> 2)) * (size_t)K + (lane & 3) * 8 + k0;
  ushort* lA = As + (w * 32) * 32;
  ushort* lB = Bs + (w * 32) * 32;
  const int rowK16 = 16 * K;

  int fro = (lane & 15) * 32 + (lane >> 4) * 8;
  const ushort* raA = As + (wm * 64) * 32 + fro;
  const ushort* raB = Bs + (wn * 64) * 32 + fro;

  f32x4 zero = {0.f, 0.f, 0.f, 0.f};
  f32x4 acc[4][4];
#pragma unroll
  for (int i = 0; i < 4; ++i)
#pragma unroll
    for (int j = 0; j < 4; ++j) acc[i][j] = zero;

  for (int kt = 0; kt < kseg; kt += 32) {
    __syncthreads();
    gld16(gA + kt, lA);
    gld16(gA + kt + rowK16, lA + 16 * 32);
    gld16(gB + kt, lB);
    gld16(gB + kt + rowK16, lB + 16 * 32);
    __syncthreads();
    bf16x8 af[4], bfv[4];
#pragma unroll
    for (int t = 0; t < 4; ++t) {
      af[t] = *reinterpret_cast<const bf16x8*>(raA + t * 512);
      bfv[t] = *reinterpret_cast<const bf16x8*>(raB + t * 512);
    }
#pragma unroll
    for (int i = 0; i < 4; ++i)
#pragma unroll
      for (int j = 0; j < 4; ++j)
        acc[i][j] = __builtin_amdgcn_mfma_f32_16x16x32_bf16(af[i], bfv[j],
                                                            acc[i][j], 0, 0, 0);
  }
  int crow = wm * 64 + (lane >> 4) * 4;
  int ccol = (int)col0 + wn * 64 + (lane & 15);
  if (obf) {
    ushort* Cu = (ushort*)C;
#pragma unroll
    for (int ti = 0; ti < 4; ++ti) {
      size_t r = row0 + crow + ti * 16;
#pragma unroll
      for (int tj = 0; tj < 4; ++tj) {
        int cc = ccol + tj * 16;
#pragma unroll
        for (int reg = 0; reg < 4; ++reg)
          Cu[(r + reg) * (size_t)M + cc] = f2bf(acc[ti][tj][reg]);
      }
    }
  } else {
    float* Cz = C + (size_t)blockIdx.z * partStride;
#pragma unroll
    for (int ti = 0; ti < 4; ++ti) {
      size_t r = row0 + crow + ti * 16;
#pragma unroll
      for (int tj = 0; tj < 4; ++tj) {
        int cc = ccol + tj * 16;
#pragma unroll
        for (int reg = 0; reg < 4; ++reg)
          Cz[(r + reg) * (size_t)M + cc] = acc[ti][tj][reg];
      }
    }
  }
}

// ---- QKV epilogue (bf16 in): logmap0(projx(mobius_add(mv,b))). 2 rows. ----
__global__ __launch_bounds__(256) void k_epi_qkv(const ushort* __restrict__ mx,
                                                 const float* __restrict__ xn_arr,
                                                 const float* __restrict__ bias,
                                                 const float* __restrict__ bs_sb2,
                                                 ushort* __restrict__ qout) {
  int wv = threadIdx.x >> 6, lane = threadIdx.x & 63;
  int row = blockIdx.x * 8 + wv * 2;
  size_t base = (size_t)row * E_DIM + lane * 8;
  float m[2][8], bv[8];
  ldbf8(mx + base, m[0]);
  ldbf8(mx + base + E_DIM, m[1]);
  *(float4*)&bv[0] = *(const float4*)(bias + lane * 8);
  *(float4*)&bv[4] = *(const float4*)(bias + lane * 8 + 4);
  float s[4];
#pragma unroll
  for (int i = 0; i < 4; ++i) s[i] = 0.f;
#pragma unroll
  for (int i = 0; i < 8; ++i) {
#pragma unroll
    for (int r2 = 0; r2 < 2; ++r2) {
      s[r2 * 2 + 0] += m[r2][i] * m[r2][i];
      s[r2 * 2 + 1] += m[r2][i] * bv[i];
    }
  }
  waveRed<4>(s);
  float S2 = *bs_sb2;
#pragma unroll
  for (int r2 = 0; r2 < 2; ++r2) {
    float S0 = s[r2 * 2 + 0], S1 = s[r2 * 2 + 1];
    float se = S0 + 1e-30f;
    float rmx = frsq(se);
    float mxn = se * rmx;
    float xn = xn_arr[row + r2];
    float aa = fatanh(fminf(xn, MAXN));
    float tt = ftanh(mxn * frcp(xn) * aa);
    float c = tt * rmx;
    float xy = c * S1, y2 = S2, x2 = tt * tt;
    float c1 = 1.f + 2.f * xy + y2, c2 = 1.f - x2;
    float iden = frcp(fmaxf(1.f + 2.f * xy + x2 * y2, 1e-15f));
    float cc1 = c1 * c * iden, cc2 = c2 * iden;
    float un2 = fmaxf(cc1 * cc1 * S0 + 2.f * cc1 * cc2 * S1 + cc2 * cc2 * S2, 0.f);
    float ue = un2 + 1e-30f;
    float run = frsq(ue);
    float un = ue * run;
    float ne = fminf(un, MAXN);
    float f = fatanh(ne) * run;
    float u[8];
#pragma unroll
    for (int i = 0; i < 8; ++i) u[i] = (cc1 * m[r2][i] + cc2 * bv[i]) * f;
    uint4 o = {pack2(u[0], u[1]), pack2(u[2], u[3]), pack2(u[4], u[5]),
               pack2(u[6], u[7])};
    *reinterpret_cast<uint4*>(qout + base + r2 * E_DIM) = o;
  }
}

// ---- attention: per (b,h) MFMA tile; OUTPUT BF16 --------------------------
__global__ __launch_bounds__(256) void k_attn(const ushort* __restrict__ q,
                                              const ushort* __restrict__ k,
                                              const ushort* __restrict__ v,
                                              ushort* __restrict__ o) {
  __shared__ __align__(16) ushort smem[27136];
  ushort* Qs = smem;
  ushort* Ks = smem + 9216;
  ushort* VTs = smem + 18432;
  ushort* Ps = smem;
  int bh = blockIdx.x;
  int b = bh >> 3, h = bh & 7;
  int tid = threadIdx.x;
  int w = tid >> 6, lane = tid & 63;
  const size_t BE = (size_t)B_DIM * E_DIM;
  size_t gbase = (size_t)b * E_DIM + (size_t)h * 64;

  {
    int s = tid >> 1, half = (tid & 1) * 32;
    const ushort* qr = q + gbase + (size_t)s * BE + half;
    const ushort* kr = k + gbase + (size_t)s * BE + half;
    const ushort* vr = v + gbase + (size_t)s * BE + half;
#pragma unroll
    for (int j = 0; j < 4; ++j) {
      *reinterpret_cast<uint4*>(&Qs[s * 72 + half + j * 8]) =
          *reinterpret_cast<const uint4*>(qr + j * 8);
      *reinterpret_cast<uint4*>(&Ks[s * 72 + half + j * 8]) =
          *reinterpret_cast<const uint4*>(kr + j * 8);
    }
    ushort tv[32];
#pragma unroll
    for (int j = 0; j < 4; ++j)
      *reinterpret_cast<uint4*>(&tv[j * 8]) =
          *reinterpret_cast<const uint4*>(vr + j * 8);
#pragma unroll
    for (int d = 0; d < 32; ++d) VTs[(half + d) * 136 + s] = tv[d];
  }
  __syncthreads();

  f32x4 zero = {0.f, 0.f, 0.f, 0.f};
  f32x4 sacc[2][8];
#pragma unroll
  for (int i = 0; i < 2; ++i)
#pragma unroll
    for (int j = 0; j < 8; ++j) sacc[i][j] = zero;
  {
    const ushort* qb = Qs + (w * 32 + (lane & 15)) * 72 + (lane >> 4) * 8;
    const ushort* kb = Ks + (lane & 15) * 72 + (lane >> 4) * 8;
#pragma unroll
    for (int kk = 0; kk < 2; ++kk) {
      bf16x8 a0 = *reinterpret_cast<const bf16x8*>(qb + kk * 32);
      bf16x8 a1 = *reinterpret_cast<const bf16x8*>(qb + 16 * 72 + kk * 32);
#pragma unroll
      for (int tj = 0; tj < 8; ++tj) {
        bf16x8 bf = *reinterpret_cast<const bf16x8*>(kb + tj * 16 * 72 + kk * 32);
        sacc[0][tj] = __builtin_amdgcn_mfma_f32_16x16x32_bf16(a0, bf,
                                                              sacc[0][tj], 0, 0, 0);
        sacc[1][tj] = __builtin_amdgcn_mfma_f32_16x16x32_bf16(a1, bf,
                                                              sacc[1][tj], 0, 0, 0);
      }
    }
  }

#pragma unroll
  for (int ti = 0; ti < 2; ++ti) {
#pragma unroll
    for (int r = 0; r < 4; ++r) {
      float mx = -1e30f;
#pragma unroll
      for (int tj = 0; tj < 8; ++tj) mx = fmaxf(mx, sacc[ti][tj][r]);
      mx = fmaxf(mx, __shfl_xor(mx, 1));
      mx = fmaxf(mx, __shfl_xor(mx, 2));
      mx = fmaxf(mx, __shfl_xor(mx, 4));
      mx = fmaxf(mx, __shfl_xor(mx, 8));
      float l = 0.f;
#pragma unroll
      for (int tj = 0; tj < 8; ++tj) {
        float e = fexp2((sacc[ti][tj][r] - mx) * (0.125f * 1.44269504f));
        sacc[ti][tj][r] = e;
        l += e;
      }
      l += __shfl_xor(l, 1);
      l += __shfl_xor(l, 2);
      l += __shfl_xor(l, 4);
      l += __shfl_xor(l, 8);
      float inv = frcp(l);
#pragma unroll
      for (int tj = 0; tj < 8; ++tj) sacc[ti][tj][r] *= inv;
    }
  }

  __syncthreads();
  {
    int qr0 = w * 32 + (lane >> 4) * 4;
    int kc = lane & 15;
#pragma unroll
    for (int ti = 0; ti < 2; ++ti)
#pragma unroll
      for (int tj = 0; tj < 8; ++tj)
#pragma unroll
        for (int r = 0; r < 4; ++r)
          Ps[(qr0 + ti * 16 + r) * 136 + tj * 16 + kc] =
              f2bf(sacc[ti][tj][r]);
  }
  __syncthreads();

  f32x4 oacc[2][4];
#pragma unroll
  for (int i = 0; i < 2; ++i)
#pragma unroll
    for (int j = 0; j < 4; ++j) oacc[i][j] = zero;
  {
    const ushort* pb = Ps + (w * 32 + (lane & 15)) * 136 + (lane >> 4) * 8;
    const ushort* vb = VTs + (lane & 15) * 136 + (lane >> 4) * 8;
#pragma unroll
    for (int kk = 0; kk < 4; ++kk) {
      bf16x8 a0 = *reinterpret_cast<const bf16x8*>(pb + kk * 32);
      bf16x8 a1 = *reinterpret_cast<const bf16x8*>(pb + 16 * 136 + kk * 32);
#pragma unroll
      for (int tj = 0; tj < 4; ++tj) {
        bf16x8 bv = *reinterpret_cast<const bf16x8*>(vb + tj * 16 * 136 + kk * 32);
        oacc[0][tj] = __builtin_amdgcn_mfma_f32_16x16x32_bf16(a0, bv,
                                                              oacc[0][tj], 0, 0, 0);
        oacc[1][tj] = __builtin_amdgcn_mfma_f32_16x16x32_bf16(a1, bv,
                                                              oacc[1][tj], 0, 0, 0);
      }
    }
  }

  {
    int qr0 = w * 32 + (lane >> 4) * 4;
    int dc = lane & 15;
#pragma unroll
    for (int ti = 0; ti < 2; ++ti)
#pragma unroll
      for (int tj = 0; tj < 4; ++tj)
#pragma unroll
        for (int r = 0; r < 4; ++r)
          o[(size_t)(qr0 + ti * 16 + r) * BE + gbase + tj * 16 + dc] =
              f2bf(oacc[ti][tj][r]);
  }
}

// ---- expmap0 rowwise (bf16 in), 2 rows/wave -------------------------------
__global__ __launch_bounds__(256) void k_expmap_rows(const ushort* __restrict__ in,
                                                     ushort* __restrict__ out,
                                                     float* __restrict__ nrm) {
  int wv = threadIdx.x >> 6, lane = threadIdx.x & 63;
  int row = blockIdx.x * 8 + wv * 2;
  size_t base = (size_t)row * E_DIM + lane * 8;
  float v[2][8];
  ldbf8(in + base, v[0]);
  ldbf8(in + base + E_DIM, v[1]);
  float s[2] = {0.f, 0.f};
#pragma unroll
  for (int i = 0; i < 8; ++i) {
    s[0] += v[0][i] * v[0][i];
    s[1] += v[1][i] * v[1][i];
  }
  waveRed<2>(s);
#pragma unroll
  for (int r2 = 0; r2 < 2; ++r2) {
    float se = s[r2] + 1e-30f;
    float rn = frsq(se);
    float n = se * rn;
    float th = ftanh(n);
    float f = th * rn;
    uint4 o = {pack2(v[r2][0] * f, v[r2][1] * f), pack2(v[r2][2] * f, v[r2][3] * f),
               pack2(v[r2][4] * f, v[r2][5] * f), pack2(v[r2][6] * f, v[r2][7] * f)};
    *reinterpret_cast<uint4*>(out + base + r2 * E_DIM) = o;
    if (lane == 0) nrm[row + r2] = th;
  }
}

// ---- attn-out epilogue (1 row/wave, 3 small chains; bf16 mo in,
// bf16 res2 out) ------------------------------------------------------------
__global__ __launch_bounds__(256) void k_epi_attnout(
    const ushort* __restrict__ mo, const float* __restrict__ xn_arr,
    const float* __restrict__ bo, const float* __restrict__ xin,
    const float* __restrict__ g2, const float* __restrict__ b2,
    ushort* __restrict__ h2, float* __restrict__ h2n,
    ushort* __restrict__ r2o) {
  int row = blockIdx.x * 4 + (threadIdx.x >> 6);
  int lane = threadIdx.x & 63;
  size_t base = (size_t)row * E_DIM + lane * 8;
  float m[8], bv[8];
  ldbf8(mo + base, m);
  *(float4*)&bv[0] = *(const float4*)(bo + lane * 8);
  *(float4*)&bv[4] = *(const float4*)(bo + lane * 8 + 4);
  float s[5] = {0.f, 0.f, 0.f, 0.f, 0.f};
#pragma unroll
  for (int i = 0; i < 8; ++i) {
    s[0] += m[i] * m[i]; s[1] += m[i] * bv[i]; s[2] += bv[i] * bv[i];
    s[3] += m[i]; s[4] += bv[i];
  }
  waveRed<5>(s);
  float se = s[0] + 1e-30f;
  float rmx = frsq(se);
  float mxn = se * rmx;
  float xn = xn_arr[row];
  float aa = fatanh(fminf(xn, MAXN));
  float tt = ftanh(mxn * frcp(xn) * aa);
  float c = tt * rmx;
  float xy = c * s[1], y2 = s[2], x2 = tt * tt;
  float c1 = 1.f + 2.f * xy + y2, c2 = 1.f - x2;
  float iden = frcp(fmaxf(1.f + 2.f * xy + x2 * y2, 1e-15f));
  float cc1 = c1 * c * iden, cc2 = c2 * iden;
  float un2 = fmaxf(cc1 * cc1 * s[0] + 2.f * cc1 * cc2 * s[1] + cc2 * cc2 * s[2], 0.f);
  float ue = un2 + 1e-30f;
  float run = frsq(ue);
  float un = ue * run;
  float ps = un > MAXN ? MAXN * run : 1.f;
  float zn = fminf(un, MAXN);
  float z[8];
#pragma unroll
  for (int i = 0; i < 8; ++i) z[i] = (cc1 * m[i] + cc2 * bv[i]) * ps;
  float sumz = ps * (cc1 * s[3] + cc2 * s[4]);
  float r[8];
  *(float4*)&r[0] = *(const float4*)(xin + base);
  *(float4*)&r[4] = *(const float4*)(xin + base + 4);
  float t2[3] = {0.f, 0.f, 0.f};
#pragma unroll
  for (int i = 0; i < 8; ++i) {
    t2[0] += z[i] * r[i]; t2[1] += r[i] * r[i]; t2[2] += r[i];
  }
  waveRed<3>(t2);
  float xy2 = t2[0], y22 = t2[1], x22 = zn * zn;
  float d1 = 1.f + 2.f * xy2 + y22, d2 = 1.f - x22;
  float iden2 = frcp(fmaxf(1.f + 2.f * xy2 + x22 * y22, 1e-15f));
  float wn2 = fmaxf(iden2 * iden2 *
                        (d1 * d1 * x22 + 2.f * d1 * d2 * xy2 + d2 * d2 * y22),
                    0.f);
  float we = wn2 + 1e-30f;
  float rwn = frsq(we);
  float wn = we * rwn;
  float ps2 = wn > MAXN ? MAXN * rwn : 1.f;
  float w[8];
#pragma unroll
  for (int i = 0; i < 8; ++i) w[i] = (d1 * z[i] + d2 * r[i]) * iden2 * ps2;
  uint4 ro = {pack2(w[0], w[1]), pack2(w[2], w[3]), pack2(w[4], w[5]),
              pack2(w[6], w[7])};
  *reinterpret_cast<uint4*>(r2o + base) = ro;
  float ne = fminf(wn, MAXN);
  float ath = fatanh(ne);
  float lf = ath * frcp(ne);
  float sumw = ps2 * iden2 * (d1 * sumz + d2 * t2[2]);
  float mu = lf * sumw * (1.f / 512.f);
  float var = fmaxf(ath * ath * (1.f / 512.f) - mu * mu, 0.f);
  float rstd = frsq(var + 1e-5f);
  float gv[8], b2v[8];
  *(float4*)&gv[0] = *(const float4*)(g2 + lane * 8);
  *(float4*)&gv[4] = *(const float4*)(g2 + lane * 8 + 4);
  *(float4*)&b2v[0] = *(const float4*)(b2 + lane * 8);
  *(float4*)&b2v[4] = *(const float4*)(b2 + lane * 8 + 4);
  float e[8];
  float s3[1] = {0.f};
#pragma unroll
  for (int i = 0; i < 8; ++i) {
    e[i] = (lf * w[i] - mu) * rstd * gv[i] + b2v[i];
    s3[0] += e[i] * e[i];
  }
  waveRed<1>(s3);
  float s3e = s3[0] + 1e-30f;
  float rn3 = frsq(s3e);
  float n3 = s3e * rn3;
  float en = ftanh(n3);
  float f = en * rn3;
  if (en > MAXN) f *= MAXN * frcp(en);
  uint4 o = {pack2(e[0] * f, e[1] * f), pack2(e[2] * f, e[3] * f),
             pack2(e[4] * f, e[5] * f), pack2(e[6] * f, e[7] * f)};
  *reinterpret_cast<uint4*>(h2 + base) = o;
  if (lane == 0) h2n[row] = fminf(en, MAXN);
}

// ---- FFN1 epilogue (2 rows/wave of F=2048; bf16 m1 in) -> bf16 ------------
__global__ __launch_bounds__(256) void k_epi_ffn1(const ushort* __restrict__ mr_,
                                                  const float* __restrict__ xn_arr,
                                                  const float* __restrict__ bias,
                                                  ushort* __restrict__ hid,
                                                  float* __restrict__ hn_out) {
  int wv = threadIdx.x >> 6, lane = threadIdx.x & 63;
  int row = blockIdx.x * 8 + wv * 2;
  const ushort* mr = mr_ + (size_t)row * F_DIM + lane * 32;
  const float* br = bias + lane * 32;
  float m[2][32], bv[32];
#pragma unroll
  for (int j = 0; j < 4; ++j) {
    ldbf8(mr + j * 8, *(float(*)[8])&m[0][j * 8]);
    ldbf8(mr + F_DIM + j * 8, *(float(*)[8])&m[1][j * 8]);
  }
#pragma unroll
  for (int j = 0; j < 8; ++j)
    *(float4*)&bv[j * 4] = *(const float4*)(br + j * 4);
  float s[5];
#pragma unroll
  for (int i = 0; i < 5; ++i) s[i] = 0.f;
#pragma unroll
  for (int i = 0; i < 32; ++i) {
#pragma unroll
    for (int r2 = 0; r2 < 2; ++r2) {
      s[r2 * 2 + 0] += m[r2][i] * m[r2][i];
      s[r2 * 2 + 1] += m[r2][i] * bv[i];
    }
    s[4] += bv[i] * bv[i];
  }
  waveRed<5>(s);
  float s2[2] = {0.f, 0.f};
#pragma unroll
  for (int r2 = 0; r2 < 2; ++r2) {
    float S0 = s[r2 * 2 + 0], S1 = s[r2 * 2 + 1], S2 = s[4];
    float se = S0 + 1e-30f;
    float rmx = frsq(se);
    float mxn = se * rmx;
    float xn = xn_arr[row + r2];
    float aa = fatanh(fminf(xn, MAXN));
    float tt = ftanh(mxn * frcp(xn) * aa);
    float c = tt * rmx;
    float xy = c * S1, y2 = S2, x2 = tt * tt;
    float c1 = 1.f + 2.f * xy + y2, c2 = 1.f - x2;
    float iden = frcp(fmaxf(1.f + 2.f * xy + x2 * y2, 1e-15f));
    float cc1 = c1 * c * iden, cc2 = c2 * iden;
    float un2 = fmaxf(cc1 * cc1 * S0 + 2.f * cc1 * cc2 * S1 + cc2 * cc2 * S2, 0.f);
    float ue = un2 + 1e-30f;
    float run = frsq(ue);
    float un = ue * run;
    float zn = fminf(un, MAXN);
    float lf = fatanh(zn) * run;
#pragma unroll
    for (int i = 0; i < 32; ++i) {
      m[r2][i] = fmaxf((cc1 * m[r2][i] + cc2 * bv[i]) * lf, 0.f);
      s2[r2] += m[r2][i] * m[r2][i];
    }
  }
  waveRed<2>(s2);
#pragma unroll
  for (int r2 = 0; r2 < 2; ++r2) {
    float s2e = s2[r2] + 1e-30f;
    float rrn = frsq(s2e);
    float rn = s2e * rrn;
    float en = ftanh(rn);
    float f = en * rrn;
    if (en > MAXN) f *= MAXN * frcp(en);
    ushort* hr = hid + (size_t)(row + r2) * F_DIM + lane * 32;
#pragma unroll
    for (int j = 0; j < 4; ++j) {
      uint4 o = {pack2(m[r2][j * 8 + 0] * f, m[r2][j * 8 + 1] * f),
                 pack2(m[r2][j * 8 + 2] * f, m[r2][j * 8 + 3] * f),
                 pack2(m[r2][j * 8 + 4] * f, m[r2][j * 8 + 5] * f),
                 pack2(m[r2][j * 8 + 6] * f, m[r2][j * 8 + 7] * f)};
      *reinterpret_cast<uint4*>(hr + j * 8) = o;
    }
    if (lane == 0) hn_out[row + r2] = fminf(en, MAXN);
  }
}

// ---- final epilogue (2 rows/wave): fp32 split-K2 sum + man_linear(W2) +
// mob_relu + residual (bf16) mobius_add + projx -> out fp32 -----------------
__global__ __launch_bounds__(256) void k_epi_final(
    const float* __restrict__ m2, const float* __restrict__ xn_arr,
    const float* __restrict__ bias, const ushort* __restrict__ res,
    float* __restrict__ out) {
  int wv = threadIdx.x >> 6, lane = threadIdx.x & 63;
  int row = blockIdx.x * 8 + wv * 2;
  size_t base = (size_t)row * E_DIM + lane * 8;
  const size_t P2 = (size_t)CH * E_DIM;
  float m[2][8], bv[8], q[2][8];
#pragma unroll
  for (int r2 = 0; r2 < 2; ++r2) {
    float ta[8], tb[8];
    *(float4*)&ta[0] = *(const float4*)(m2 + base + r2 * E_DIM);
    *(float4*)&ta[4] = *(const float4*)(m2 + base + r2 * E_DIM + 4);
    *(float4*)&tb[0] = *(const float4*)(m2 + P2 + base + r2 * E_DIM);
    *(float4*)&tb[4] = *(const float4*)(m2 + P2 + base + r2 * E_DIM + 4);
#pragma unroll
    for (int i = 0; i < 8; ++i) m[r2][i] = ta[i] + tb[i];
    ldbf8(res + base + r2 * E_DIM, q[r2]);
  }
  *(float4*)&bv[0] = *(const float4*)(bias + lane * 8);
  *(float4*)&bv[4] = *(const float4*)(bias + lane * 8 + 4);
  float s[7];
#pragma unroll
  for (int i = 0; i < 7; ++i) s[i] = 0.f;
#pragma unroll
  for (int i = 0; i < 8; ++i) {
#pragma unroll
    for (int r2 = 0; r2 < 2; ++r2) {
      s[r2 * 3 + 0] += m[r2][i] * m[r2][i];
      s[r2 * 3 + 1] += m[r2][i] * bv[i];
      s[r2 * 3 + 2] += q[r2][i] * q[r2][i];
    }
    s[6] += bv[i] * bv[i];
  }
  waveRed<7>(s);
  float r[2][8];
  float s2[4];
#pragma unroll
  for (int i = 0; i < 4; ++i) s2[i] = 0.f;
#pragma unroll
  for (int r2 = 0; r2 < 2; ++r2) {
    float S0 = s[r2 * 3 + 0], S1 = s[r2 * 3 + 1], S2 = s[6];
    float se = S0 + 1e-30f;
    float rmx = frsq(se);
    float mxn = se * rmx;
    float xn = xn_arr[row + r2];
    float aa = fatanh(fminf(xn, MAXN));
    float tt = ftanh(mxn * frcp(xn) * aa);
    float c = tt * rmx;
    float xy = c * S1, y2 = S2, x2 = tt * tt;
    float c1 = 1.f + 2.f * xy + y2, c2 = 1.f - x2;
    float iden = frcp(fmaxf(1.f + 2.f * xy + x2 * y2, 1e-15f));
    float cc1 = c1 * c * iden, cc2 = c2 * iden;
    float un2 = fmaxf(cc1 * cc1 * S0 + 2.f * cc1 * cc2 * S1 + cc2 * cc2 * S2, 0.f);
    float ue = un2 + 1e-30f;
    float run = frsq(ue);
    float un = ue * run;
    float zn = fminf(un, MAXN);
    float lf = fatanh(zn) * run;
#pragma unroll
    for (int i = 0; i < 8; ++i) {
      r[r2][i] = fmaxf((cc1 * m[r2][i] + cc2 * bv[i]) * lf, 0.f);
      s2[r2 * 2 + 0] += r[r2][i] * r[r2][i];
      s2[r2 * 2 + 1] += r[r2][i] * q[r2][i];
    }
  }
  waveRed<4>(s2);
#pragma unroll
  for (int r2 = 0; r2 < 2; ++r2) {
    float s2e = s2[r2 * 2 + 0] + 1e-30f;
    float rrn = frsq(s2e);
    float rn = s2e * rrn;
    float en = ftanh(rn);
    float f = en * rrn;
    if (en > MAXN) f *= MAXN * frcp(en);
    float hn = fminf(en, MAXN);
    float xy2 = f * s2[r2 * 2 + 1], y22 = s[r2 * 3 + 2], x22 = hn * hn;
    float d1 = 1.f + 2.f * xy2 + y22, d2 = 1.f - x22;
    float iden2 = frcp(fmaxf(1.f + 2.f * xy2 + x22 * y22, 1e-15f));
    float wn2 = fmaxf(iden2 * iden2 *
                          (d1 * d1 * x22 + 2.f * d1 * d2 * xy2 + d2 * d2 * y22),
                      0.f);
    float we = wn2 + 1e-30f;
    float rwn = frsq(we);
    float wn = we * rwn;
    float ps2 = wn > MAXN ? MAXN * rwn : 1.f;
    float w[8];
#pragma unroll
    for (int i = 0; i < 8; ++i)
      w[i] = (d1 * r[r2][i] * f + d2 * q[r2][i]) * iden2 * ps2;
    *(float4*)(out + base + r2 * E_DIM) = *(float4*)&w[0];
    *(float4*)(out + base + r2 * E_DIM + 4) = *(float4*)&w[4];
  }
}

extern "C" void kernel_launch(void* const* d_in, const int* in_sizes, int n_in,
                              void* d_out, int out_size, void* d_ws,
                              size_t ws_size, hipStream_t stream) {
  const float* x   = (const float*)d_in[0];
  const float* g1  = (const float*)d_in[1];
  const float* lb1 = (const float*)d_in[2];
  const float* g2  = (const float*)d_in[3];
  const float* lb2 = (const float*)d_in[4];
  const float* Wq  = (const float*)d_in[5];
  const float* bq  = (const float*)d_in[6];
  const float* Wk  = (const float*)d_in[7];
  const float* bk  = (const float*)d_in[8];
  const float* Wv  = (const float*)d_in[9];
  const float* bv  = (const float*)d_in[10];
  const float* Wo  = (const float*)d_in[11];
  const float* bo  = (const float*)d_in[12];
  const float* W1  = (const float*)d_in[13];
  const float* b1  = (const float*)d_in[14];
  const float* W2  = (const float*)d_in[15];
  const float* b2  = (const float*)d_in[16];
  float* out = (float*)d_out;
  float* ws = (float*)d_ws;

  const size_t NE = (size_t)N_ROWS * E_DIM;          // 16,777,216
  const size_t WF = (4 * (size_t)E_DIM * E_DIM +
                     2 * (size_t)F_DIM * E_DIM) / 2; // 1,572,864 floats
  // R_b (NE floats = 64MB):
  //   lower 32MB as ushort: QKV C bf16 -> attn-out bf16 -> mo bf16 -> m1 bf16
  //   upper 32MB as ushort: res2 bf16 (attnout -> epi_final)
  float* R_b = ws;
  ushort* Cb   = (ushort*)ws;            // NE ushorts (32MB scratch)
  ushort* r2u  = (ushort*)(ws + NE / 2); // NE ushorts (res2 bf16)
  float* R_a = ws + NE;                  // NE/2: h1 -> oe -> h2 (bf16)
  float* R_q = ws + NE + NE / 2;         // NE/2: q_bf16 -> m2 fp32 partials
  float* R_k = ws + 2 * NE;              // NE/2: k_bf16
  float* R_v = ws + 2 * NE + NE / 2;     // NE/2: v_bf16 -> hid_bf16
  ushort* wqb = (ushort*)(ws + 3 * NE);
  ushort* wkb = wqb + (size_t)E_DIM * E_DIM;
  ushort* wvb = wkb + (size_t)E_DIM * E_DIM;
  ushort* wob = wvb + (size_t)E_DIM * E_DIM;
  ushort* w1b = wob + (size_t)E_DIM * E_DIM;
  ushort* w2b = w1b + (size_t)F_DIM * E_DIM;
  float* n_h1 = ws + 3 * NE + WF;
  float* n_oe = n_h1 + N_ROWS;
  float* n_h2 = n_oe + N_ROWS;
  float* n_h3 = n_h2 + N_ROWS;
  float* bs = n_h3 + N_ROWS;  // 16 scalar sums
  const size_t need = (3 * NE + WF + 4 * (size_t)N_ROWS + 16) * sizeof(float);
  if (ws_size < need) return;

  k_bsums<<<1, 64, 0, stream>>>(bq, bk, bv, g1, lb1, bs);
  k_f2bf<<<256, 256, 0, stream>>>(Wq, wqb, E_DIM * E_DIM);
  k_f2bf<<<256, 256, 0, stream>>>(Wk, wkb, E_DIM * E_DIM);
  k_f2bf<<<256, 256, 0, stream>>>(Wv, wvb, E_DIM * E_DIM);
  k_f2bf<<<256, 256, 0, stream>>>(Wo, wob, E_DIM * E_DIM);
  k_f2bf<<<512, 256, 0, stream>>>(W1, w1b, F_DIM * E_DIM);
  k_f2bf<<<512, 256, 0, stream>>>(W2, w2b, F_DIM * E_DIM);

  ushort* h1b = (ushort*)R_a;
  ushort* qb = (ushort*)R_q;
  ushort* kb = (ushort*)R_k;
  ushort* vb = (ushort*)R_v;

  // Phase A: stage1 + QKV projections (bf16 C scratch, no fp32 round-trip)
  k_stage1<<<N_ROWS / 8, 256, 0, stream>>>(x, g1, lb1, bs, h1b, n_h1);
  dim3 gQ(E_DIM / 128, N_ROWS / 128, 1);
  k_gemm_bf16<<<gQ, 256, 0, stream>>>(h1b, wqb, (float*)Cb, E_DIM, E_DIM,
                                      E_DIM, 0, 1);
  k_epi_qkv<<<N_ROWS / 8, 256, 0, stream>>>(Cb, n_h1, bq, bs + 0, qb);
  k_gemm_bf16<<<gQ, 256, 0, stream>>>(h1b, wkb, (float*)Cb, E_DIM, E_DIM,
                                      E_DIM, 0, 1);
  k_epi_qkv<<<N_ROWS / 8, 256, 0, stream>>>(Cb, n_h1, bk, bs + 1, kb);
  k_gemm_bf16<<<gQ, 256, 0, stream>>>(h1b, wvb, (float*)Cb, E_DIM, E_DIM,
                                      E_DIM, 0, 1);
  k_epi_qkv<<<N_ROWS / 8, 256, 0, stream>>>(Cb, n_h1, bv, bs + 2, vb);

  // Phase B: MFMA attention -> bf16 Cb; expmap0 -> oe bf16 (R_a, h1 dead)
  k_attn<<<B_DIM * 8, 256, 0, stream>>>(qb, kb, vb, Cb);
  ushort* oeb = (ushort*)R_a;
  k_expmap_rows<<<N_ROWS / 8, 256, 0, stream>>>(Cb, oeb, n_oe);

  // Phase C: Wo projection -> mo bf16 (Cb); attnout: res2 bf16 -> r2u,
  // h2 bf16 -> R_a (oe dead after Wo GEMM read)
  ushort* h2b = (ushort*)R_a;
  k_gemm_bf16<<<gQ, 256, 0, stream>>>(oeb, wob, (float*)Cb, E_DIM, E_DIM,
                                      E_DIM, 0, 1);
  k_epi_attnout<<<N_ROWS / 4, 256, 0, stream>>>(Cb, n_oe, bo, x, g2, lb2,
                                                h2b, n_h2, r2u);

  // Phase D: FFN chunked (CH=8192). m1 bf16 in Cb (mo dead), hid bf16 in
  // R_v (v dead), m2 fp32 split-K2 partials in R_q (q dead). Stream-ordered.
  ushort* m1 = Cb;
  ushort* hidb = (ushort*)R_v;
  float* m2 = R_q;
  for (int c = 0; c < N_ROWS / CH; ++c) {
    size_t ro = (size_t)c * CH;
    k_gemm_bf16<<<dim3(F_DIM / 128, CH / 128, 1), 256, 0, stream>>>(
        h2b + ro * E_DIM, w1b, (float*)m1, E_DIM, F_DIM, E_DIM, 0, 1);
    k_epi_ffn1<<<CH / 8, 256, 0, stream>>>(m1, n_h2 + ro, b1, hidb, n_h3 + ro);
    k_gemm_bf16<<<dim3(E_DIM / 128, CH / 128, 2), 256, 0, stream>>>(
        hidb, w2b, m2, F_DIM, E_DIM, F_DIM / 2,
        (unsigned long long)((size_t)CH * E_DIM), 0);
    k_epi_final<<<CH / 8, 256, 0, stream>>>(m2, n_h3 + ro, b2,
                                            r2u + ro * E_DIM, out + ro * E_DIM);
  }
}

// Round 6
// 820.811 us; speedup vs baseline: 1.2657x; 1.0283x over previous
//
// Hyperbolic (Poincare ball) transformer block — MI355X round 11.
// Round-10 post-mortem: GEMMs are now the top cost (8 x ~44us) and are
// MEMORY-bound on A-panel over-fetch: FETCH=68MB vs A=32MB, because the
// X col-blocks of each A row-panel round-robin onto different XCDs (each
// pulls the panel into its own non-coherent L2).
// Fix (T1): XCD-aware block swizzle. 1-D grid; decode
//   r=b&7, k=b>>3, x=k%X, g=r+8*(k/X), y=g%Y, z=g/Y
// so all X col-blocks of one (y,z) group land on the same XCD (bijective,
// G=Y*Z divisible by 8 for all our grids). Per-XCD A footprint = 4MB = L2.
// LDS bank conflict (8-way ds_read) left alone: T2 measured-null on
// 2-phase GEMM structures (learn_hip m230/m252).
// Everything else unchanged from round 10 (bf16 intermediates, CH=8192,
// split-K2 FFN2, round-6 attnout, fast-math epilogues).
#include <hip/hip_runtime.h>
#include <math.h>

#define S_DIM 128
#define B_DIM 256
#define E_DIM 512
#define F_DIM 2048
#define N_ROWS (S_DIM * B_DIM) /* 32768 */
#define CH 8192                /* FFN row chunk */
#define MAXN 0.99999f          /* 1 - 1e-5 */

typedef __bf16 bf16x8 __attribute__((ext_vector_type(8)));
typedef float f32x4 __attribute__((ext_vector_type(4)));

// ---- fast-math helpers (1-instr HW transcendentals) -----------------------
__device__ __forceinline__ float frcp(float x) { return __builtin_amdgcn_rcpf(x); }
__device__ __forceinline__ float frsq(float x) { return __builtin_amdgcn_rsqf(x); }
__device__ __forceinline__ float fexp2(float x) { return __builtin_amdgcn_exp2f(x); }
__device__ __forceinline__ float flog2(float x) { return __builtin_amdgcn_logf(x); }
__device__ __forceinline__ float fatanh(float x) {
  return 0.34657359f * flog2((1.f + x) * frcp(1.f - x));
}
__device__ __forceinline__ float ftanh(float x) {
  float t = fexp2(x * -2.88539008f);
  return (1.f - t) * frcp(1.f + t);
}

__device__ __forceinline__ ushort f2bf(float f) {
  __bf16 h = (__bf16)f;
  return __builtin_bit_cast(ushort, h);
}
__device__ __forceinline__ uint pack2(float a, float b) {
  return (uint)f2bf(a) | ((uint)f2bf(b) << 16);
}
// load 8 bf16 -> 8 fp32 (bit-shift unpack, no cvt chain)
__device__ __forceinline__ void ldbf8(const ushort* p, float (&f)[8]) {
  uint4 u = *reinterpret_cast<const uint4*>(p);
  f[0] = __uint_as_float(u.x << 16);
  f[1] = __uint_as_float(u.x & 0xFFFF0000u);
  f[2] = __uint_as_float(u.y << 16);
  f[3] = __uint_as_float(u.y & 0xFFFF0000u);
  f[4] = __uint_as_float(u.z << 16);
  f[5] = __uint_as_float(u.z & 0xFFFF0000u);
  f[6] = __uint_as_float(u.w << 16);
  f[7] = __uint_as_float(u.w & 0xFFFF0000u);
}

__device__ __forceinline__ void gld16(const ushort* g, ushort* l) {
  __builtin_amdgcn_global_load_lds(
      (const __attribute__((address_space(1))) void*)g,
      (__attribute__((address_space(3))) void*)l, 16, 0, 0);
}

// ---- wave-wide butterfly reduction of K values (all lanes get results) ----
template <int K>
__device__ __forceinline__ void waveRed(float (&v)[K]) {
#pragma unroll
  for (int o = 1; o < 64; o <<= 1) {
#pragma unroll
    for (int i = 0; i < K; ++i) v[i] += __shfl_xor(v[i], o);
  }
}

// ---------------- fp32 -> bf16 convert (weights) ---------------------------
__global__ __launch_bounds__(256) void k_f2bf(const float* __restrict__ in,
                                              ushort* __restrict__ out, int n) {
  for (int i = blockIdx.x * 256 + threadIdx.x; i < n; i += gridDim.x * 256)
    out[i] = f2bf(in[i]);
}

// ---- one-wave bias/param sums kernel --------------------------------------
// bs: [0]=Sbq2 [1]=Sbk2 [2]=Sbv2 [7]=Sg1_2 [8]=Sg1lb1 [9]=Slb1_2
__global__ void k_bsums(const float* __restrict__ bq, const float* __restrict__ bk,
                        const float* __restrict__ bv, const float* __restrict__ g1,
                        const float* __restrict__ lb1, float* __restrict__ bs) {
  int lane = threadIdx.x;
  float p[6];
#pragma unroll
  for (int i = 0; i < 6; ++i) p[i] = 0.f;
  for (int i = lane; i < E_DIM; i += 64) {
    float a = bq[i]; p[0] += a * a;
    a = bk[i]; p[1] += a * a;
    a = bv[i]; p[2] += a * a;
    float g = g1[i], l = lb1[i];
    p[3] += g * g; p[4] += g * l; p[5] += l * l;
  }
  waveRed<6>(p);
  if (lane == 0) {
    bs[0] = p[0]; bs[1] = p[1]; bs[2] = p[2];
    bs[7] = p[3]; bs[8] = p[4]; bs[9] = p[5];
  }
}

// ---- stage 1: h1 = expmap0(LN(logmap0(x))) -> bf16. 2 rows/wave. ----------
__global__ __launch_bounds__(256) void k_stage1(
    const float* __restrict__ x, const float* __restrict__ g,
    const float* __restrict__ bb, const float* __restrict__ bs,
    ushort* __restrict__ h, float* __restrict__ hn) {
  int wv = threadIdx.x >> 6, lane = threadIdx.x & 63;
  int row = blockIdx.x * 8 + wv * 2;
  size_t base = (size_t)row * E_DIM + lane * 8;
  float v[2][8], gv[8], bv[8];
  *(float4*)&v[0][0] = *(const float4*)(x + base);
  *(float4*)&v[0][4] = *(const float4*)(x + base + 4);
  *(float4*)&v[1][0] = *(const float4*)(x + base + E_DIM);
  *(float4*)&v[1][4] = *(const float4*)(x + base + E_DIM + 4);
  *(float4*)&gv[0] = *(const float4*)(g + lane * 8);
  *(float4*)&gv[4] = *(const float4*)(g + lane * 8 + 4);
  *(float4*)&bv[0] = *(const float4*)(bb + lane * 8);
  *(float4*)&bv[4] = *(const float4*)(bb + lane * 8 + 4);
  float s[10];
#pragma unroll
  for (int i = 0; i < 10; ++i) s[i] = 0.f;
#pragma unroll
  for (int i = 0; i < 8; ++i) {
    float gg = gv[i] * gv[i], gb = gv[i] * bv[i];
#pragma unroll
    for (int r2 = 0; r2 < 2; ++r2) {
      float vv = v[r2][i];
      s[r2 * 5 + 0] += vv * vv;
      s[r2 * 5 + 1] += vv;
      s[r2 * 5 + 2] += vv * vv * gg;
      s[r2 * 5 + 3] += vv * gg;
      s[r2 * 5 + 4] += vv * gb;
    }
  }
  waveRed<10>(s);
  float Sg2 = bs[7], Sgb = bs[8], Sb2 = bs[9];
#pragma unroll
  for (int r2 = 0; r2 < 2; ++r2) {
    float T0 = s[r2 * 5 + 0], T1 = s[r2 * 5 + 1], T2 = s[r2 * 5 + 2];
    float T3 = s[r2 * 5 + 3], T4 = s[r2 * 5 + 4];
    float se = T0 + 1e-30f;
    float rn = frsq(se);
    float n = se * rn;
    float a = fatanh(fminf(n, MAXN)) * rn;
    float mu = a * T1 * (1.f / 512.f);
    float var = fmaxf(a * a * T0 * (1.f / 512.f) - mu * mu, 0.f);
    float rstd = frsq(var + 1e-5f);
    float A = a * rstd, B = -mu * rstd;
    float se2 = fmaxf(A * A * T2 + 2.f * A * B * T3 + 2.f * A * T4 +
                          B * B * Sg2 + 2.f * B * Sgb + Sb2, 0.f) + 1e-30f;
    float rn2 = frsq(se2);
    float n2 = se2 * rn2;
    float th = ftanh(n2);
    float f = th * rn2;
    float e[8];
#pragma unroll
    for (int i = 0; i < 8; ++i) e[i] = (A * v[r2][i] + B) * gv[i] + bv[i];
    uint4 o = {pack2(e[0] * f, e[1] * f), pack2(e[2] * f, e[3] * f),
               pack2(e[4] * f, e[5] * f), pack2(e[6] * f, e[7] * f)};
    *reinterpret_cast<uint4*>(h + base + r2 * E_DIM) = o;
    if (lane == 0) hn[row + r2] = th;
  }
}

// -------- bf16 MFMA GEMM: C[n][m] = sum_k A[n][k]*B[m][k] ------------------
// 1-D grid, XCD-swizzled decode: all X col-blocks of one (y,z) group land
// on the same XCD (dispatch id % 8 == XCD). G=Y*Z must be divisible by 8.
// obf=0: C fp32 (split-K partials). obf=1: C bf16.
__global__ __launch_bounds__(256) void k_gemm_bf16(
    const ushort* __restrict__ A, const ushort* __restrict__ B,
    float* __restrict__ C, int K, int M, int kseg,
    unsigned long long partStride, int obf, int GX, int GY) {
  __shared__ __align__(16) ushort As[128 * 32];
  __shared__ __align__(16) ushort Bs[128 * 32];
  int b = blockIdx.x;
  int rx = b & 7, kk2 = b >> 3;
  int bx = kk2 % GX;
  int gg = rx + 8 * (kk2 / GX);
  int by = gg % GY, bz = gg / GY;
  int tid = threadIdx.x;
  int w = tid >> 6, lane = tid & 63;
  int wm = w >> 1, wn = w & 1;
  size_t row0 = (size_t)by * 128;
  size_t col0 = (size_t)bx * 128;
  int k0 = bz * kseg;

  const ushort* gA =
      A + (row0 + w * 32 + (lane >> 2)) * (size_t)K + (lane & 3) * 8 + k0;
  const ushort* gB =
      B + (col0 + w * 32 + (lane >> 2)) * (size_t)K + (lane & 3) * 8 + k0;
  ushort* lA = As + (w * 32) * 32;
  ushort* lB = Bs + (w * 32) * 32;
  const int rowK16 = 16 * K;

  int fro = (lane & 15) * 32 + (lane >> 4) * 8;
  const ushort* raA = As + (wm * 64) * 32 + fro;
  const ushort* raB = Bs + (wn * 64) * 32 + fro;

  f32x4 zero = {0.f, 0.f, 0.f, 0.f};
  f32x4 acc[4][4];
#pragma unroll
  for (int i = 0; i < 4; ++i)
#pragma unroll
    for (int j = 0; j < 4; ++j) acc[i][j] = zero;

  for (int kt = 0; kt < kseg; kt += 32) {
    __syncthreads();
    gld16(gA + kt, lA);
    gld16(gA + kt + rowK16, lA + 16 * 32);
    gld16(gB + kt, lB);
    gld16(gB + kt + rowK16, lB + 16 * 32);
    __syncthreads();
    bf16x8 af[4], bfv[4];
#pragma unroll
    for (int t = 0; t < 4; ++t) {
      af[t] = *reinterpret_cast<const bf16x8*>(raA + t * 512);
      bfv[t] = *reinterpret_cast<const bf16x8*>(raB + t * 512);
    }
#pragma unroll
    for (int i = 0; i < 4; ++i)
#pragma unroll
      for (int j = 0; j < 4; ++j)
        acc[i][j] = __builtin_amdgcn_mfma_f32_16x16x32_bf16(af[i], bfv[j],
                                                            acc[i][j], 0, 0, 0);
  }
  int crow = wm * 64 + (lane >> 4) * 4;
  int ccol = (int)col0 + wn * 64 + (lane & 15);
  if (obf) {
    ushort* Cu = (ushort*)C;
#pragma unroll
    for (int ti = 0; ti < 4; ++ti) {
      size_t r = row0 + crow + ti * 16;
#pragma unroll
      for (int tj = 0; tj < 4; ++tj) {
        int cc = ccol + tj * 16;
#pragma unroll
        for (int reg = 0; reg < 4; ++reg)
          Cu[(r + reg) * (size_t)M + cc] = f2bf(acc[ti][tj][reg]);
      }
    }
  } else {
    float* Cz = C + (size_t)bz * partStride;
#pragma unroll
    for (int ti = 0; ti < 4; ++ti) {
      size_t r = row0 + crow + ti * 16;
#pragma unroll
      for (int tj = 0; tj < 4; ++tj) {
        int cc = ccol + tj * 16;
#pragma unroll
        for (int reg = 0; reg < 4; ++reg)
          Cz[(r + reg) * (size_t)M + cc] = acc[ti][tj][reg];
      }
    }
  }
}

// ---- QKV epilogue (bf16 in): logmap0(projx(mobius_add(mv,b))). 2 rows. ----
__global__ __launch_bounds__(256) void k_epi_qkv(const ushort* __restrict__ mx,
                                                 const float* __restrict__ xn_arr,
                                                 const float* __restrict__ bias,
                                                 const float* __restrict__ bs_sb2,
                                                 ushort* __restrict__ qout) {
  int wv = threadIdx.x >> 6, lane = threadIdx.x & 63;
  int row = blockIdx.x * 8 + wv * 2;
  size_t base = (size_t)row * E_DIM + lane * 8;
  float m[2][8], bv[8];
  ldbf8(mx + base, m[0]);
  ldbf8(mx + base + E_DIM, m[1]);
  *(float4*)&bv[0] = *(const float4*)(bias + lane * 8);
  *(float4*)&bv[4] = *(const float4*)(bias + lane * 8 + 4);
  float s[4];
#pragma unroll
  for (int i = 0; i < 4; ++i) s[i] = 0.f;
#pragma unroll
  for (int i = 0; i < 8; ++i) {
#pragma unroll
    for (int r2 = 0; r2 < 2; ++r2) {
      s[r2 * 2 + 0] += m[r2][i] * m[r2][i];
      s[r2 * 2 + 1] += m[r2][i] * bv[i];
    }
  }
  waveRed<4>(s);
  float S2 = *bs_sb2;
#pragma unroll
  for (int r2 = 0; r2 < 2; ++r2) {
    float S0 = s[r2 * 2 + 0], S1 = s[r2 * 2 + 1];
    float se = S0 + 1e-30f;
    float rmx = frsq(se);
    float mxn = se * rmx;
    float xn = xn_arr[row + r2];
    float aa = fatanh(fminf(xn, MAXN));
    float tt = ftanh(mxn * frcp(xn) * aa);
    float c = tt * rmx;
    float xy = c * S1, y2 = S2, x2 = tt * tt;
    float c1 = 1.f + 2.f * xy + y2, c2 = 1.f - x2;
    float iden = frcp(fmaxf(1.f + 2.f * xy + x2 * y2, 1e-15f));
    float cc1 = c1 * c * iden, cc2 = c2 * iden;
    float un2 = fmaxf(cc1 * cc1 * S0 + 2.f * cc1 * cc2 * S1 + cc2 * cc2 * S2, 0.f);
    float ue = un2 + 1e-30f;
    float run = frsq(ue);
    float un = ue * run;
    float ne = fminf(un, MAXN);
    float f = fatanh(ne) * run;
    float u[8];
#pragma unroll
    for (int i = 0; i < 8; ++i) u[i] = (cc1 * m[r2][i] + cc2 * bv[i]) * f;
    uint4 o = {pack2(u[0], u[1]), pack2(u[2], u[3]), pack2(u[4], u[5]),
               pack2(u[6], u[7])};
    *reinterpret_cast<uint4*>(qout + base + r2 * E_DIM) = o;
  }
}

// ---- attention: per (b,h) MFMA tile; OUTPUT BF16 --------------------------
__global__ __launch_bounds__(256) void k_attn(const ushort* __restrict__ q,
                                              const ushort* __restrict__ k,
                                              const ushort* __restrict__ v,
                                              ushort* __restrict__ o) {
  __shared__ __align__(16) ushort smem[27136];
  ushort* Qs = smem;
  ushort* Ks = smem + 9216;
  ushort* VTs = smem + 18432;
  ushort* Ps = smem;
  int bh = blockIdx.x;
  int b = bh >> 3, h = bh & 7;
  int tid = threadIdx.x;
  int w = tid >> 6, lane = tid & 63;
  const size_t BE = (size_t)B_DIM * E_DIM;
  size_t gbase = (size_t)b * E_DIM + (size_t)h * 64;

  {
    int s = tid >> 1, half = (tid & 1) * 32;
    const ushort* qr = q + gbase + (size_t)s * BE + half;
    const ushort* kr = k + gbase + (size_t)s * BE + half;
    const ushort* vr = v + gbase + (size_t)s * BE + half;
#pragma unroll
    for (int j = 0; j < 4; ++j) {
      *reinterpret_cast<uint4*>(&Qs[s * 72 + half + j * 8]) =
          *reinterpret_cast<const uint4*>(qr + j * 8);
      *reinterpret_cast<uint4*>(&Ks[s * 72 + half + j * 8]) =
          *reinterpret_cast<const uint4*>(kr + j * 8);
    }
    ushort tv[32];
#pragma unroll
    for (int j = 0; j < 4; ++j)
      *reinterpret_cast<uint4*>(&tv[j * 8]) =
          *reinterpret_cast<const uint4*>(vr + j * 8);
#pragma unroll
    for (int d = 0; d < 32; ++d) VTs[(half + d) * 136 + s] = tv[d];
  }
  __syncthreads();

  f32x4 zero = {0.f, 0.f, 0.f, 0.f};
  f32x4 sacc[2][8];
#pragma unroll
  for (int i = 0; i < 2; ++i)
#pragma unroll
    for (int j = 0; j < 8; ++j) sacc[i][j] = zero;
  {
    const ushort* qb = Qs + (w * 32 + (lane & 15)) * 72 + (lane >> 4) * 8;
    const ushort* kb = Ks + (lane & 15) * 72 + (lane >> 4) * 8;
#pragma unroll
    for (int kk = 0; kk < 2; ++kk) {
      bf16x8 a0 = *reinterpret_cast<const bf16x8*>(qb + kk * 32);
      bf16x8 a1 = *reinterpret_cast<const bf16x8*>(qb + 16 * 72 + kk * 32);
#pragma unroll
      for (int tj = 0; tj < 8; ++tj) {
        bf16x8 bf = *reinterpret_cast<const bf16x8*>(kb + tj * 16 * 72 + kk * 32);
        sacc[0][tj] = __builtin_amdgcn_mfma_f32_16x16x32_bf16(a0, bf,
                                                              sacc[0][tj], 0, 0, 0);
        sacc[1][tj] = __builtin_amdgcn_mfma_f32_16x16x32_bf16(a1, bf,
                                                              sacc[1][tj], 0, 0, 0);
      }
    }
  }

#pragma unroll
  for (int ti = 0; ti < 2; ++ti) {
#pragma unroll
    for (int r = 0; r < 4; ++r) {
      float mx = -1e30f;
#pragma unroll
      for (int tj = 0; tj < 8; ++tj) mx = fmaxf(mx, sacc[ti][tj][r]);
      mx = fmaxf(mx, __shfl_xor(mx, 1));
      mx = fmaxf(mx, __shfl_xor(mx, 2));
      mx = fmaxf(mx, __shfl_xor(mx, 4));
      mx = fmaxf(mx, __shfl_xor(mx, 8));
      float l = 0.f;
#pragma unroll
      for (int tj = 0; tj < 8; ++tj) {
        float e = fexp2((sacc[ti][tj][r] - mx) * (0.125f * 1.44269504f));
        sacc[ti][tj][r] = e;
        l += e;
      }
      l += __shfl_xor(l, 1);
      l += __shfl_xor(l, 2);
      l += __shfl_xor(l, 4);
      l += __shfl_xor(l, 8);
      float inv = frcp(l);
#pragma unroll
      for (int tj = 0; tj < 8; ++tj) sacc[ti][tj][r] *= inv;
    }
  }

  __syncthreads();
  {
    int qr0 = w * 32 + (lane >> 4) * 4;
    int kc = lane & 15;
#pragma unroll
    for (int ti = 0; ti < 2; ++ti)
#pragma unroll
      for (int tj = 0; tj < 8; ++tj)
#pragma unroll
        for (int r = 0; r < 4; ++r)
          Ps[(qr0 + ti * 16 + r) * 136 + tj * 16 + kc] =
              f2bf(sacc[ti][tj][r]);
  }
  __syncthreads();

  f32x4 oacc[2][4];
#pragma unroll
  for (int i = 0; i < 2; ++i)
#pragma unroll
    for (int j = 0; j < 4; ++j) oacc[i][j] = zero;
  {
    const ushort* pb = Ps + (w * 32 + (lane & 15)) * 136 + (lane >> 4) * 8;
    const ushort* vb = VTs + (lane & 15) * 136 + (lane >> 4) * 8;
#pragma unroll
    for (int kk = 0; kk < 4; ++kk) {
      bf16x8 a0 = *reinterpret_cast<const bf16x8*>(pb + kk * 32);
      bf16x8 a1 = *reinterpret_cast<const bf16x8*>(pb + 16 * 136 + kk * 32);
#pragma unroll
      for (int tj = 0; tj < 4; ++tj) {
        bf16x8 bv = *reinterpret_cast<const bf16x8*>(vb + tj * 16 * 136 + kk * 32);
        oacc[0][tj] = __builtin_amdgcn_mfma_f32_16x16x32_bf16(a0, bv,
                                                              oacc[0][tj], 0, 0, 0);
        oacc[1][tj] = __builtin_amdgcn_mfma_f32_16x16x32_bf16(a1, bv,
                                                              oacc[1][tj], 0, 0, 0);
      }
    }
  }

  {
    int qr0 = w * 32 + (lane >> 4) * 4;
    int dc = lane & 15;
#pragma unroll
    for (int ti = 0; ti < 2; ++ti)
#pragma unroll
      for (int tj = 0; tj < 4; ++tj)
#pragma unroll
        for (int r = 0; r < 4; ++r)
          o[(size_t)(qr0 + ti * 16 + r) * BE + gbase + tj * 16 + dc] =
              f2bf(oacc[ti][tj][r]);
  }
}

// ---- expmap0 rowwise (bf16 in), 2 rows/wave -------------------------------
__global__ __launch_bounds__(256) void k_expmap_rows(const ushort* __restrict__ in,
                                                     ushort* __restrict__ out,
                                                     float* __restrict__ nrm) {
  int wv = threadIdx.x >> 6, lane = threadIdx.x & 63;
  int row = blockIdx.x * 8 + wv * 2;
  size_t base = (size_t)row * E_DIM + lane * 8;
  float v[2][8];
  ldbf8(in + base, v[0]);
  ldbf8(in + base + E_DIM, v[1]);
  float s[2] = {0.f, 0.f};
#pragma unroll
  for (int i = 0; i < 8; ++i) {
    s[0] += v[0][i] * v[0][i];
    s[1] += v[1][i] * v[1][i];
  }
  waveRed<2>(s);
#pragma unroll
  for (int r2 = 0; r2 < 2; ++r2) {
    float se = s[r2] + 1e-30f;
    float rn = frsq(se);
    float n = se * rn;
    float th = ftanh(n);
    float f = th * rn;
    uint4 o = {pack2(v[r2][0] * f, v[r2][1] * f), pack2(v[r2][2] * f, v[r2][3] * f),
               pack2(v[r2][4] * f, v[r2][5] * f), pack2(v[r2][6] * f, v[r2][7] * f)};
    *reinterpret_cast<uint4*>(out + base + r2 * E_DIM) = o;
    if (lane == 0) nrm[row + r2] = th;
  }
}

// ---- attn-out epilogue (1 row/wave, 3 small chains; bf16 mo in,
// bf16 res2 out) ------------------------------------------------------------
__global__ __launch_bounds__(256) void k_epi_attnout(
    const ushort* __restrict__ mo, const float* __restrict__ xn_arr,
    const float* __restrict__ bo, const float* __restrict__ xin,
    const float* __restrict__ g2, const float* __restrict__ b2,
    ushort* __restrict__ h2, float* __restrict__ h2n,
    ushort* __restrict__ r2o) {
  int row = blockIdx.x * 4 + (threadIdx.x >> 6);
  int lane = threadIdx.x & 63;
  size_t base = (size_t)row * E_DIM + lane * 8;
  float m[8], bv[8];
  ldbf8(mo + base, m);
  *(float4*)&bv[0] = *(const float4*)(bo + lane * 8);
  *(float4*)&bv[4] = *(const float4*)(bo + lane * 8 + 4);
  float s[5] = {0.f, 0.f, 0.f, 0.f, 0.f};
#pragma unroll
  for (int i = 0; i < 8; ++i) {
    s[0] += m[i] * m[i]; s[1] += m[i] * bv[i]; s[2] += bv[i] * bv[i];
    s[3] += m[i]; s[4] += bv[i];
  }
  waveRed<5>(s);
  float se = s[0] + 1e-30f;
  float rmx = frsq(se);
  float mxn = se * rmx;
  float xn = xn_arr[row];
  float aa = fatanh(fminf(xn, MAXN));
  float tt = ftanh(mxn * frcp(xn) * aa);
  float c = tt * rmx;
  float xy = c * s[1], y2 = s[2], x2 = tt * tt;
  float c1 = 1.f + 2.f * xy + y2, c2 = 1.f - x2;
  float iden = frcp(fmaxf(1.f + 2.f * xy + x2 * y2, 1e-15f));
  float cc1 = c1 * c * iden, cc2 = c2 * iden;
  float un2 = fmaxf(cc1 * cc1 * s[0] + 2.f * cc1 * cc2 * s[1] + cc2 * cc2 * s[2], 0.f);
  float ue = un2 + 1e-30f;
  float run = frsq(ue);
  float un = ue * run;
  float ps = un > MAXN ? MAXN * run : 1.f;
  float zn = fminf(un, MAXN);
  float z[8];
#pragma unroll
  for (int i = 0; i < 8; ++i) z[i] = (cc1 * m[i] + cc2 * bv[i]) * ps;
  float sumz = ps * (cc1 * s[3] + cc2 * s[4]);
  float r[8];
  *(float4*)&r[0] = *(const float4*)(xin + base);
  *(float4*)&r[4] = *(const float4*)(xin + base + 4);
  float t2[3] = {0.f, 0.f, 0.f};
#pragma unroll
  for (int i = 0; i < 8; ++i) {
    t2[0] += z[i] * r[i]; t2[1] += r[i] * r[i]; t2[2] += r[i];
  }
  waveRed<3>(t2);
  float xy2 = t2[0], y22 = t2[1], x22 = zn * zn;
  float d1 = 1.f + 2.f * xy2 + y22, d2 = 1.f - x22;
  float iden2 = frcp(fmaxf(1.f + 2.f * xy2 + x22 * y22, 1e-15f));
  float wn2 = fmaxf(iden2 * iden2 *
                        (d1 * d1 * x22 + 2.f * d1 * d2 * xy2 + d2 * d2 * y22),
                    0.f);
  float we = wn2 + 1e-30f;
  float rwn = frsq(we);
  float wn = we * rwn;
  float ps2 = wn > MAXN ? MAXN * rwn : 1.f;
  float w[8];
#pragma unroll
  for (int i = 0; i < 8; ++i) w[i] = (d1 * z[i] + d2 * r[i]) * iden2 * ps2;
  uint4 ro = {pack2(w[0], w[1]), pack2(w[2], w[3]), pack2(w[4], w[5]),
              pack2(w[6], w[7])};
  *reinterpret_cast<uint4*>(r2o + base) = ro;
  float ne = fminf(wn, MAXN);
  float ath = fatanh(ne);
  float lf = ath * frcp(ne);
  float sumw = ps2 * iden2 * (d1 * sumz + d2 * t2[2]);
  float mu = lf * sumw * (1.f / 512.f);
  float var = fmaxf(ath * ath * (1.f / 512.f) - mu * mu, 0.f);
  float rstd = frsq(var + 1e-5f);
  float gv[8], b2v[8];
  *(float4*)&gv[0] = *(const float4*)(g2 + lane * 8);
  *(float4*)&gv[4] = *(const float4*)(g2 + lane * 8 + 4);
  *(float4*)&b2v[0] = *(const float4*)(b2 + lane * 8);
  *(float4*)&b2v[4] = *(const float4*)(b2 + lane * 8 + 4);
  float e[8];
  float s3[1] = {0.f};
#pragma unroll
  for (int i = 0; i < 8; ++i) {
    e[i] = (lf * w[i] - mu) * rstd * gv[i] + b2v[i];
    s3[0] += e[i] * e[i];
  }
  waveRed<1>(s3);
  float s3e = s3[0] + 1e-30f;
  float rn3 = frsq(s3e);
  float n3 = s3e * rn3;
  float en = ftanh(n3);
  float f = en * rn3;
  if (en > MAXN) f *= MAXN * frcp(en);
  uint4 o = {pack2(e[0] * f, e[1] * f), pack2(e[2] * f, e[3] * f),
             pack2(e[4] * f, e[5] * f), pack2(e[6] * f, e[7] * f)};
  *reinterpret_cast<uint4*>(h2 + base) = o;
  if (lane == 0) h2n[row] = fminf(en, MAXN);
}

// ---- FFN1 epilogue (2 rows/wave of F=2048; bf16 m1 in) -> bf16 ------------
__global__ __launch_bounds__(256) void k_epi_ffn1(const ushort* __restrict__ mr_,
                                                  const float* __restrict__ xn_arr,
                                                  const float* __restrict__ bias,
                                                  ushort* __restrict__ hid,
                                                  float* __restrict__ hn_out) {
  int wv = threadIdx.x >> 6, lane = threadIdx.x & 63;
  int row = blockIdx.x * 8 + wv * 2;
  const ushort* mr = mr_ + (size_t)row * F_DIM + lane * 32;
  const float* br = bias + lane * 32;
  float m[2][32], bv[32];
#pragma unroll
  for (int j = 0; j < 4; ++j) {
    ldbf8(mr + j * 8, *(float(*)[8])&m[0][j * 8]);
    ldbf8(mr + F_DIM + j * 8, *(float(*)[8])&m[1][j * 8]);
  }
#pragma unroll
  for (int j = 0; j < 8; ++j)
    *(float4*)&bv[j * 4] = *(const float4*)(br + j * 4);
  float s[5];
#pragma unroll
  for (int i = 0; i < 5; ++i) s[i] = 0.f;
#pragma unroll
  for (int i = 0; i < 32; ++i) {
#pragma unroll
    for (int r2 = 0; r2 < 2; ++r2) {
      s[r2 * 2 + 0] += m[r2][i] * m[r2][i];
      s[r2 * 2 + 1] += m[r2][i] * bv[i];
    }
    s[4] += bv[i] * bv[i];
  }
  waveRed<5>(s);
  float s2[2] = {0.f, 0.f};
#pragma unroll
  for (int r2 = 0; r2 < 2; ++r2) {
    float S0 = s[r2 * 2 + 0], S1 = s[r2 * 2 + 1], S2 = s[4];
    float se = S0 + 1e-30f;
    float rmx = frsq(se);
    float mxn = se * rmx;
    float xn = xn_arr[row + r2];
    float aa = fatanh(fminf(xn, MAXN));
    float tt = ftanh(mxn * frcp(xn) * aa);
    float c = tt * rmx;
    float xy = c * S1, y2 = S2, x2 = tt * tt;
    float c1 = 1.f + 2.f * xy + y2, c2 = 1.f - x2;
    float iden = frcp(fmaxf(1.f + 2.f * xy + x2 * y2, 1e-15f));
    float cc1 = c1 * c * iden, cc2 = c2 * iden;
    float un2 = fmaxf(cc1 * cc1 * S0 + 2.f * cc1 * cc2 * S1 + cc2 * cc2 * S2, 0.f);
    float ue = un2 + 1e-30f;
    float run = frsq(ue);
    float un = ue * run;
    float zn = fminf(un, MAXN);
    float lf = fatanh(zn) * run;
#pragma unroll
    for (int i = 0; i < 32; ++i) {
      m[r2][i] = fmaxf((cc1 * m[r2][i] + cc2 * bv[i]) * lf, 0.f);
      s2[r2] += m[r2][i] * m[r2][i];
    }
  }
  waveRed<2>(s2);
#pragma unroll
  for (int r2 = 0; r2 < 2; ++r2) {
    float s2e = s2[r2] + 1e-30f;
    float rrn = frsq(s2e);
    float rn = s2e * rrn;
    float en = ftanh(rn);
    float f = en * rrn;
    if (en > MAXN) f *= MAXN * frcp(en);
    ushort* hr = hid + (size_t)(row + r2) * F_DIM + lane * 32;
#pragma unroll
    for (int j = 0; j < 4; ++j) {
      uint4 o = {pack2(m[r2][j * 8 + 0] * f, m[r2][j * 8 + 1] * f),
                 pack2(m[r2][j * 8 + 2] * f, m[r2][j * 8 + 3] * f),
                 pack2(m[r2][j * 8 + 4] * f, m[r2][j * 8 + 5] * f),
                 pack2(m[r2][j * 8 + 6] * f, m[r2][j * 8 + 7] * f)};
      *reinterpret_cast<uint4*>(hr + j * 8) = o;
    }
    if (lane == 0) hn_out[row + r2] = fminf(en, MAXN);
  }
}

// ---- final epilogue (2 rows/wave): fp32 split-K2 sum + man_linear(W2) +
// mob_relu + residual (bf16) mobius_add + projx -> out fp32 -----------------
__global__ __launch_bounds__(256) void k_epi_final(
    const float* __restrict__ m2, const float* __restrict__ xn_arr,
    const float* __restrict__ bias, const ushort* __restrict__ res,
    float* __restrict__ out) {
  int wv = threadIdx.x >> 6, lane = threadIdx.x & 63;
  int row = blockIdx.x * 8 + wv * 2;
  size_t base = (size_t)row * E_DIM + lane * 8;
  const size_t P2 = (size_t)CH * E_DIM;
  float m[2][8], bv[8], q[2][8];
#pragma unroll
  for (int r2 = 0; r2 < 2; ++r2) {
    float ta[8], tb[8];
    *(float4*)&ta[0] = *(const float4*)(m2 + base + r2 * E_DIM);
    *(float4*)&ta[4] = *(const float4*)(m2 + base + r2 * E_DIM + 4);
    *(float4*)&tb[0] = *(const float4*)(m2 + P2 + base + r2 * E_DIM);
    *(float4*)&tb[4] = *(const float4*)(m2 + P2 + base + r2 * E_DIM + 4);
#pragma unroll
    for (int i = 0; i < 8; ++i) m[r2][i] = ta[i] + tb[i];
    ldbf8(res + base + r2 * E_DIM, q[r2]);
  }
  *(float4*)&bv[0] = *(const float4*)(bias + lane * 8);
  *(float4*)&bv[4] = *(const float4*)(bias + lane * 8 + 4);
  float s[7];
#pragma unroll
  for (int i = 0; i < 7; ++i) s[i] = 0.f;
#pragma unroll
  for (int i = 0; i < 8; ++i) {
#pragma unroll
    for (int r2 = 0; r2 < 2; ++r2) {
      s[r2 * 3 + 0] += m[r2][i] * m[r2][i];
      s[r2 * 3 + 1] += m[r2][i] * bv[i];
      s[r2 * 3 + 2] += q[r2][i] * q[r2][i];
    }
    s[6] += bv[i] * bv[i];
  }
  waveRed<7>(s);
  float r[2][8];
  float s2[4];
#pragma unroll
  for (int i = 0; i < 4; ++i) s2[i] = 0.f;
#pragma unroll
  for (int r2 = 0; r2 < 2; ++r2) {
    float S0 = s[r2 * 3 + 0], S1 = s[r2 * 3 + 1], S2 = s[6];
    float se = S0 + 1e-30f;
    float rmx = frsq(se);
    float mxn = se * rmx;
    float xn = xn_arr[row + r2];
    float aa = fatanh(fminf(xn, MAXN));
    float tt = ftanh(mxn * frcp(xn) * aa);
    float c = tt * rmx;
    float xy = c * S1, y2 = S2, x2 = tt * tt;
    float c1 = 1.f + 2.f * xy + y2, c2 = 1.f - x2;
    float iden = frcp(fmaxf(1.f + 2.f * xy + x2 * y2, 1e-15f));
    float cc1 = c1 * c * iden, cc2 = c2 * iden;
    float un2 = fmaxf(cc1 * cc1 * S0 + 2.f * cc1 * cc2 * S1 + cc2 * cc2 * S2, 0.f);
    float ue = un2 + 1e-30f;
    float run = frsq(ue);
    float un = ue * run;
    float zn = fminf(un, MAXN);
    float lf = fatanh(zn) * run;
#pragma unroll
    for (int i = 0; i < 8; ++i) {
      r[r2][i] = fmaxf((cc1 * m[r2][i] + cc2 * bv[i]) * lf, 0.f);
      s2[r2 * 2 + 0] += r[r2][i] * r[r2][i];
      s2[r2 * 2 + 1] += r[r2][i] * q[r2][i];
    }
  }
  waveRed<4>(s2);
#pragma unroll
  for (int r2 = 0; r2 < 2; ++r2) {
    float s2e = s2[r2 * 2 + 0] + 1e-30f;
    float rrn = frsq(s2e);
    float rn = s2e * rrn;
    float en = ftanh(rn);
    float f = en * rrn;
    if (en > MAXN) f *= MAXN * frcp(en);
    float hn = fminf(en, MAXN);
    float xy2 = f * s2[r2 * 2 + 1], y22 = s[r2 * 3 + 2], x22 = hn * hn;
    float d1 = 1.f + 2.f * xy2 + y22, d2 = 1.f - x22;
    float iden2 = frcp(fmaxf(1.f + 2.f * xy2 + x22 * y22, 1e-15f));
    float wn2 = fmaxf(iden2 * iden2 *
                          (d1 * d1 * x22 + 2.f * d1 * d2 * xy2 + d2 * d2 * y22),
                      0.f);
    float we = wn2 + 1e-30f;
    float rwn = frsq(we);
    float wn = we * rwn;
    float ps2 = wn > MAXN ? MAXN * rwn : 1.f;
    float w[8];
#pragma unroll
    for (int i = 0; i < 8; ++i)
      w[i] = (d1 * r[r2][i] * f + d2 * q[r2][i]) * iden2 * ps2;
    *(float4*)(out + base + r2 * E_DIM) = *(float4*)&w[0];
    *(float4*)(out + base + r2 * E_DIM + 4) = *(float4*)&w[4];
  }
}

extern "C" void kernel_launch(void* const* d_in, const int* in_sizes, int n_in,
                              void* d_out, int out_size, void* d_ws,
                              size_t ws_size, hipStream_t stream) {
  const float* x   = (const float*)d_in[0];
  const float* g1  = (const float*)d_in[1];
  const float* lb1 = (const float*)d_in[2];
  const float* g2  = (const float*)d_in[3];
  const float* lb2 = (const float*)d_in[4];
  const float* Wq  = (const float*)d_in[5];
  const float* bq  = (const float*)d_in[6];
  const float* Wk  = (const float*)d_in[7];
  const float* bk  = (const float*)d_in[8];
  const float* Wv  = (const float*)d_in[9];
  const float* bv  = (const float*)d_in[10];
  const float* Wo  = (const float*)d_in[11];
  const float* bo  = (const float*)d_in[12];
  const float* W1  = (const float*)d_in[13];
  const float* b1  = (const float*)d_in[14];
  const float* W2  = (const float*)d_in[15];
  const float* b2  = (const float*)d_in[16];
  float* out = (float*)d_out;
  float* ws = (float*)d_ws;

  const size_t NE = (size_t)N_ROWS * E_DIM;          // 16,777,216
  const size_t WF = (4 * (size_t)E_DIM * E_DIM +
                     2 * (size_t)F_DIM * E_DIM) / 2; // 1,572,864 floats
  // R_b (NE floats = 64MB):
  //   lower 32MB as ushort: QKV C bf16 -> attn-out bf16 -> mo bf16 -> m1 bf16
  //   upper 32MB as ushort: res2 bf16 (attnout -> epi_final)
  ushort* Cb   = (ushort*)ws;            // NE ushorts (32MB scratch)
  ushort* r2u  = (ushort*)(ws + NE / 2); // NE ushorts (res2 bf16)
  float* R_a = ws + NE;                  // NE/2: h1 -> oe -> h2 (bf16)
  float* R_q = ws + NE + NE / 2;         // NE/2: q_bf16 -> m2 fp32 partials
  float* R_k = ws + 2 * NE;              // NE/2: k_bf16
  float* R_v = ws + 2 * NE + NE / 2;     // NE/2: v_bf16 -> hid_bf16
  ushort* wqb = (ushort*)(ws + 3 * NE);
  ushort* wkb = wqb + (size_t)E_DIM * E_DIM;
  ushort* wvb = wkb + (size_t)E_DIM * E_DIM;
  ushort* wob = wvb + (size_t)E_DIM * E_DIM;
  ushort* w1b = wob + (size_t)E_DIM * E_DIM;
  ushort* w2b = w1b + (size_t)F_DIM * E_DIM;
  float* n_h1 = ws + 3 * NE + WF;
  float* n_oe = n_h1 + N_ROWS;
  float* n_h2 = n_oe + N_ROWS;
  float* n_h3 = n_h2 + N_ROWS;
  float* bs = n_h3 + N_ROWS;  // 16 scalar sums
  const size_t need = (3 * NE + WF + 4 * (size_t)N_ROWS + 16) * sizeof(float);
  if (ws_size < need) return;

  k_bsums<<<1, 64, 0, stream>>>(bq, bk, bv, g1, lb1, bs);
  k_f2bf<<<256, 256, 0, stream>>>(Wq, wqb, E_DIM * E_DIM);
  k_f2bf<<<256, 256, 0, stream>>>(Wk, wkb, E_DIM * E_DIM);
  k_f2bf<<<256, 256, 0, stream>>>(Wv, wvb, E_DIM * E_DIM);
  k_f2bf<<<256, 256, 0, stream>>>(Wo, wob, E_DIM * E_DIM);
  k_f2bf<<<512, 256, 0, stream>>>(W1, w1b, F_DIM * E_DIM);
  k_f2bf<<<512, 256, 0, stream>>>(W2, w2b, F_DIM * E_DIM);

  ushort* h1b = (ushort*)R_a;
  ushort* qb = (ushort*)R_q;
  ushort* kb = (ushort*)R_k;
  ushort* vb = (ushort*)R_v;

  // Phase A: stage1 + QKV projections (bf16 C scratch, XCD-swizzled GEMM)
  k_stage1<<<N_ROWS / 8, 256, 0, stream>>>(x, g1, lb1, bs, h1b, n_h1);
  const int gE = 4 * 256;  // X=4 col-blocks, Y=256 row-panels
  k_gemm_bf16<<<gE, 256, 0, stream>>>(h1b, wqb, (float*)Cb, E_DIM, E_DIM,
                                      E_DIM, 0, 1, 4, 256);
  k_epi_qkv<<<N_ROWS / 8, 256, 0, stream>>>(Cb, n_h1, bq, bs + 0, qb);
  k_gemm_bf16<<<gE, 256, 0, stream>>>(h1b, wkb, (float*)Cb, E_DIM, E_DIM,
                                      E_DIM, 0, 1, 4, 256);
  k_epi_qkv<<<N_ROWS / 8, 256, 0, stream>>>(Cb, n_h1, bk, bs + 1, kb);
  k_gemm_bf16<<<gE, 256, 0, stream>>>(h1b, wvb, (float*)Cb, E_DIM, E_DIM,
                                      E_DIM, 0, 1, 4, 256);
  k_epi_qkv<<<N_ROWS / 8, 256, 0, stream>>>(Cb, n_h1, bv, bs + 2, vb);

  // Phase B: MFMA attention -> bf16 Cb; expmap0 -> oe bf16 (R_a, h1 dead)
  k_attn<<<B_DIM * 8, 256, 0, stream>>>(qb, kb, vb, Cb);
  ushort* oeb = (ushort*)R_a;
  k_expmap_rows<<<N_ROWS / 8, 256, 0, stream>>>(Cb, oeb, n_oe);

  // Phase C: Wo projection -> mo bf16 (Cb); attnout: res2 bf16 -> r2u,
  // h2 bf16 -> R_a (oe dead after Wo GEMM read)
  ushort* h2b = (ushort*)R_a;
  k_gemm_bf16<<<gE, 256, 0, stream>>>(oeb, wob, (float*)Cb, E_DIM, E_DIM,
                                      E_DIM, 0, 1, 4, 256);
  k_epi_attnout<<<N_ROWS / 4, 256, 0, stream>>>(Cb, n_oe, bo, x, g2, lb2,
                                                h2b, n_h2, r2u);

  // Phase D: FFN chunked (CH=8192). m1 bf16 in Cb (mo dead), hid bf16 in
  // R_v (v dead), m2 fp32 split-K2 partials in R_q (q dead). Stream-ordered.
  ushort* m1 = Cb;
  ushort* hidb = (ushort*)R_v;
  float* m2 = R_q;
  for (int c = 0; c < N_ROWS / CH; ++c) {
    size_t ro = (size_t)c * CH;
    // FFN1: X=16 (F/128), Y=64 (CH/128)
    k_gemm_bf16<<<16 * 64, 256, 0, stream>>>(
        h2b + ro * E_DIM, w1b, (float*)m1, E_DIM, F_DIM, E_DIM, 0, 1, 16, 64);
    k_epi_ffn1<<<CH / 8, 256, 0, stream>>>(m1, n_h2 + ro, b1, hidb, n_h3 + ro);
    // FFN2: X=4 (E/128), Y=64 (CH/128), Z=2 (split-K)
    k_gemm_bf16<<<4 * 64 * 2, 256, 0, stream>>>(
        hidb, w2b, m2, F_DIM, E_DIM, F_DIM / 2,
        (unsigned long long)((size_t)CH * E_DIM), 0, 4, 64);
    k_epi_final<<<CH / 8, 256, 0, stream>>>(m2, n_h3 + ro, b2,
                                            r2u + ro * E_DIM, out + ro * E_DIM);
  }
}

// Round 7
// 762.859 us; speedup vs baseline: 1.3618x; 1.0760x over previous
//
// Hyperbolic (Poincare ball) transformer block — MI355X round 12.
// Round-11 post-mortem: swizzle fixed FETCH (68->25MB) but GEMM time was
// unchanged (43us, MfmaUtil 13.7, VALUBusy 27, HBM 17%) -> GEMMs are
// LATENCY-bound: the 2-barrier K-step serializes global_load_lds latency
// (~600-900cyc) with compute (~400cyc), 16x per block, little cross-block
// overlap. Fix: minimum 2-phase prefetch (learn_hip T3-lite, m230-V0):
//  * double-buffered LDS (32KB/block), stage tile t+1 at TOP of iter t,
//    compute tile t, then ONE vmcnt(0) + raw s_barrier per K-step.
//  * raw __builtin_amdgcn_s_barrier (NOT __syncthreads, which re-inserts
//    the vmcnt drain before the loads issue) + sched_barrier(0) to pin
//    ds_reads from hoisting above the barrier (rule #18).
// Everything else unchanged from round 11 (XCD swizzle, bf16
// intermediates, CH=8192 split-K2 FFN, fast-math epilogues).
#include <hip/hip_runtime.h>
#include <math.h>

#define S_DIM 128
#define B_DIM 256
#define E_DIM 512
#define F_DIM 2048
#define N_ROWS (S_DIM * B_DIM) /* 32768 */
#define CH 8192                /* FFN row chunk */
#define MAXN 0.99999f          /* 1 - 1e-5 */

typedef __bf16 bf16x8 __attribute__((ext_vector_type(8)));
typedef float f32x4 __attribute__((ext_vector_type(4)));

// ---- fast-math helpers (1-instr HW transcendentals) -----------------------
__device__ __forceinline__ float frcp(float x) { return __builtin_amdgcn_rcpf(x); }
__device__ __forceinline__ float frsq(float x) { return __builtin_amdgcn_rsqf(x); }
__device__ __forceinline__ float fexp2(float x) { return __builtin_amdgcn_exp2f(x); }
__device__ __forceinline__ float flog2(float x) { return __builtin_amdgcn_logf(x); }
__device__ __forceinline__ float fatanh(float x) {
  return 0.34657359f * flog2((1.f + x) * frcp(1.f - x));
}
__device__ __forceinline__ float ftanh(float x) {
  float t = fexp2(x * -2.88539008f);
  return (1.f - t) * frcp(1.f + t);
}

__device__ __forceinline__ ushort f2bf(float f) {
  __bf16 h = (__bf16)f;
  return __builtin_bit_cast(ushort, h);
}
__device__ __forceinline__ uint pack2(float a, float b) {
  return (uint)f2bf(a) | ((uint)f2bf(b) << 16);
}
// load 8 bf16 -> 8 fp32 (bit-shift unpack, no cvt chain)
__device__ __forceinline__ void ldbf8(const ushort* p, float (&f)[8]) {
  uint4 u = *reinterpret_cast<const uint4*>(p);
  f[0] = __uint_as_float(u.x << 16);
  f[1] = __uint_as_float(u.x & 0xFFFF0000u);
  f[2] = __uint_as_float(u.y << 16);
  f[3] = __uint_as_float(u.y & 0xFFFF0000u);
  f[4] = __uint_as_float(u.z << 16);
  f[5] = __uint_as_float(u.z & 0xFFFF0000u);
  f[6] = __uint_as_float(u.w << 16);
  f[7] = __uint_as_float(u.w & 0xFFFF0000u);
}

__device__ __forceinline__ void gld16(const ushort* g, ushort* l) {
  __builtin_amdgcn_global_load_lds(
      (const __attribute__((address_space(1))) void*)g,
      (__attribute__((address_space(3))) void*)l, 16, 0, 0);
}

// ---- wave-wide butterfly reduction of K values (all lanes get results) ----
template <int K>
__device__ __forceinline__ void waveRed(float (&v)[K]) {
#pragma unroll
  for (int o = 1; o < 64; o <<= 1) {
#pragma unroll
    for (int i = 0; i < K; ++i) v[i] += __shfl_xor(v[i], o);
  }
}

// ---------------- fp32 -> bf16 convert (weights) ---------------------------
__global__ __launch_bounds__(256) void k_f2bf(const float* __restrict__ in,
                                              ushort* __restrict__ out, int n) {
  for (int i = blockIdx.x * 256 + threadIdx.x; i < n; i += gridDim.x * 256)
    out[i] = f2bf(in[i]);
}

// ---- one-wave bias/param sums kernel --------------------------------------
// bs: [0]=Sbq2 [1]=Sbk2 [2]=Sbv2 [7]=Sg1_2 [8]=Sg1lb1 [9]=Slb1_2
__global__ void k_bsums(const float* __restrict__ bq, const float* __restrict__ bk,
                        const float* __restrict__ bv, const float* __restrict__ g1,
                        const float* __restrict__ lb1, float* __restrict__ bs) {
  int lane = threadIdx.x;
  float p[6];
#pragma unroll
  for (int i = 0; i < 6; ++i) p[i] = 0.f;
  for (int i = lane; i < E_DIM; i += 64) {
    float a = bq[i]; p[0] += a * a;
    a = bk[i]; p[1] += a * a;
    a = bv[i]; p[2] += a * a;
    float g = g1[i], l = lb1[i];
    p[3] += g * g; p[4] += g * l; p[5] += l * l;
  }
  waveRed<6>(p);
  if (lane == 0) {
    bs[0] = p[0]; bs[1] = p[1]; bs[2] = p[2];
    bs[7] = p[3]; bs[8] = p[4]; bs[9] = p[5];
  }
}

// ---- stage 1: h1 = expmap0(LN(logmap0(x))) -> bf16. 2 rows/wave. ----------
__global__ __launch_bounds__(256) void k_stage1(
    const float* __restrict__ x, const float* __restrict__ g,
    const float* __restrict__ bb, const float* __restrict__ bs,
    ushort* __restrict__ h, float* __restrict__ hn) {
  int wv = threadIdx.x >> 6, lane = threadIdx.x & 63;
  int row = blockIdx.x * 8 + wv * 2;
  size_t base = (size_t)row * E_DIM + lane * 8;
  float v[2][8], gv[8], bv[8];
  *(float4*)&v[0][0] = *(const float4*)(x + base);
  *(float4*)&v[0][4] = *(const float4*)(x + base + 4);
  *(float4*)&v[1][0] = *(const float4*)(x + base + E_DIM);
  *(float4*)&v[1][4] = *(const float4*)(x + base + E_DIM + 4);
  *(float4*)&gv[0] = *(const float4*)(g + lane * 8);
  *(float4*)&gv[4] = *(const float4*)(g + lane * 8 + 4);
  *(float4*)&bv[0] = *(const float4*)(bb + lane * 8);
  *(float4*)&bv[4] = *(const float4*)(bb + lane * 8 + 4);
  float s[10];
#pragma unroll
  for (int i = 0; i < 10; ++i) s[i] = 0.f;
#pragma unroll
  for (int i = 0; i < 8; ++i) {
    float gg = gv[i] * gv[i], gb = gv[i] * bv[i];
#pragma unroll
    for (int r2 = 0; r2 < 2; ++r2) {
      float vv = v[r2][i];
      s[r2 * 5 + 0] += vv * vv;
      s[r2 * 5 + 1] += vv;
      s[r2 * 5 + 2] += vv * vv * gg;
      s[r2 * 5 + 3] += vv * gg;
      s[r2 * 5 + 4] += vv * gb;
    }
  }
  waveRed<10>(s);
  float Sg2 = bs[7], Sgb = bs[8], Sb2 = bs[9];
#pragma unroll
  for (int r2 = 0; r2 < 2; ++r2) {
    float T0 = s[r2 * 5 + 0], T1 = s[r2 * 5 + 1], T2 = s[r2 * 5 + 2];
    float T3 = s[r2 * 5 + 3], T4 = s[r2 * 5 + 4];
    float se = T0 + 1e-30f;
    float rn = frsq(se);
    float n = se * rn;
    float a = fatanh(fminf(n, MAXN)) * rn;
    float mu = a * T1 * (1.f / 512.f);
    float var = fmaxf(a * a * T0 * (1.f / 512.f) - mu * mu, 0.f);
    float rstd = frsq(var + 1e-5f);
    float A = a * rstd, B = -mu * rstd;
    float se2 = fmaxf(A * A * T2 + 2.f * A * B * T3 + 2.f * A * T4 +
                          B * B * Sg2 + 2.f * B * Sgb + Sb2, 0.f) + 1e-30f;
    float rn2 = frsq(se2);
    float n2 = se2 * rn2;
    float th = ftanh(n2);
    float f = th * rn2;
    float e[8];
#pragma unroll
    for (int i = 0; i < 8; ++i) e[i] = (A * v[r2][i] + B) * gv[i] + bv[i];
    uint4 o = {pack2(e[0] * f, e[1] * f), pack2(e[2] * f, e[3] * f),
               pack2(e[4] * f, e[5] * f), pack2(e[6] * f, e[7] * f)};
    *reinterpret_cast<uint4*>(h + base + r2 * E_DIM) = o;
    if (lane == 0) hn[row + r2] = th;
  }
}

// -------- bf16 MFMA GEMM: C[n][m] = sum_k A[n][k]*B[m][k] ------------------
// 1-D grid, XCD-swizzled decode (all GX col-blocks of one (y,z) group on
// one XCD). Minimum 2-phase pipeline: double-buffered LDS, stage t+1 at
// top of iter t, one vmcnt(0)+raw-barrier per K-step.
// obf=0: C fp32 (split-K partials). obf=1: C bf16.
__global__ __launch_bounds__(256) void k_gemm_bf16(
    const ushort* __restrict__ A, const ushort* __restrict__ B,
    float* __restrict__ C, int K, int M, int kseg,
    unsigned long long partStride, int obf, int GX, int GY) {
  __shared__ __align__(16) ushort As[2][128 * 32];
  __shared__ __align__(16) ushort Bs[2][128 * 32];
  int b = blockIdx.x;
  int rx = b & 7, kk2 = b >> 3;
  int bx = kk2 % GX;
  int gg = rx + 8 * (kk2 / GX);
  int by = gg % GY, bz = gg / GY;
  int tid = threadIdx.x;
  int w = tid >> 6, lane = tid & 63;
  int wm = w >> 1, wn = w & 1;
  size_t row0 = (size_t)by * 128;
  size_t col0 = (size_t)bx * 128;
  int k0 = bz * kseg;

  const ushort* gA =
      A + (row0 + w * 32 + (lane >> 2)) * (size_t)K + (lane & 3) * 8 + k0;
  const ushort* gB =
      B + (col0 + w * 32 + (lane >> 2)) * (size_t)K + (lane & 3) * 8 + k0;
  const int lofs = (w * 32) * 32;
  const int rowK16 = 16 * K;
  int fro = (lane & 15) * 32 + (lane >> 4) * 8;

  f32x4 zero = {0.f, 0.f, 0.f, 0.f};
  f32x4 acc[4][4];
#pragma unroll
  for (int i = 0; i < 4; ++i)
#pragma unroll
    for (int j = 0; j < 4; ++j) acc[i][j] = zero;

  // prologue: stage tile 0 into buffer 0
  gld16(gA, As[0] + lofs);
  gld16(gA + rowK16, As[0] + lofs + 16 * 32);
  gld16(gB, Bs[0] + lofs);
  gld16(gB + rowK16, Bs[0] + lofs + 16 * 32);
  asm volatile("s_waitcnt vmcnt(0)" ::: "memory");
  __builtin_amdgcn_s_barrier();
  __builtin_amdgcn_sched_barrier(0);

  int cur = 0;
  for (int kt = 0; kt < kseg; kt += 32) {
    // issue next tile's loads into the other buffer (overlaps with compute)
    if (kt + 32 < kseg) {
      int nxt = cur ^ 1;
      gld16(gA + kt + 32, As[nxt] + lofs);
      gld16(gA + kt + 32 + rowK16, As[nxt] + lofs + 16 * 32);
      gld16(gB + kt + 32, Bs[nxt] + lofs);
      gld16(gB + kt + 32 + rowK16, Bs[nxt] + lofs + 16 * 32);
    }
    const ushort* raA = As[cur] + (wm * 64) * 32 + fro;
    const ushort* raB = Bs[cur] + (wn * 64) * 32 + fro;
    bf16x8 af[4], bfv[4];
#pragma unroll
    for (int t = 0; t < 4; ++t) {
      af[t] = *reinterpret_cast<const bf16x8*>(raA + t * 512);
      bfv[t] = *reinterpret_cast<const bf16x8*>(raB + t * 512);
    }
#pragma unroll
    for (int i = 0; i < 4; ++i)
#pragma unroll
      for (int j = 0; j < 4; ++j)
        acc[i][j] = __builtin_amdgcn_mfma_f32_16x16x32_bf16(af[i], bfv[j],
                                                            acc[i][j], 0, 0, 0);
    // next-tile stage complete + all waves done reading buf[cur]
    asm volatile("s_waitcnt vmcnt(0)" ::: "memory");
    __builtin_amdgcn_s_barrier();
    __builtin_amdgcn_sched_barrier(0);
    cur ^= 1;
  }

  int crow = wm * 64 + (lane >> 4) * 4;
  int ccol = (int)col0 + wn * 64 + (lane & 15);
  if (obf) {
    ushort* Cu = (ushort*)C;
#pragma unroll
    for (int ti = 0; ti < 4; ++ti) {
      size_t r = row0 + crow + ti * 16;
#pragma unroll
      for (int tj = 0; tj < 4; ++tj) {
        int cc = ccol + tj * 16;
#pragma unroll
        for (int reg = 0; reg < 4; ++reg)
          Cu[(r + reg) * (size_t)M + cc] = f2bf(acc[ti][tj][reg]);
      }
    }
  } else {
    float* Cz = C + (size_t)bz * partStride;
#pragma unroll
    for (int ti = 0; ti < 4; ++ti) {
      size_t r = row0 + crow + ti * 16;
#pragma unroll
      for (int tj = 0; tj < 4; ++tj) {
        int cc = ccol + tj * 16;
#pragma unroll
        for (int reg = 0; reg < 4; ++reg)
          Cz[(r + reg) * (size_t)M + cc] = acc[ti][tj][reg];
      }
    }
  }
}

// ---- QKV epilogue (bf16 in): logmap0(projx(mobius_add(mv,b))). 2 rows. ----
__global__ __launch_bounds__(256) void k_epi_qkv(const ushort* __restrict__ mx,
                                                 const float* __restrict__ xn_arr,
                                                 const float* __restrict__ bias,
                                                 const float* __restrict__ bs_sb2,
                                                 ushort* __restrict__ qout) {
  int wv = threadIdx.x >> 6, lane = threadIdx.x & 63;
  int row = blockIdx.x * 8 + wv * 2;
  size_t base = (size_t)row * E_DIM + lane * 8;
  float m[2][8], bv[8];
  ldbf8(mx + base, m[0]);
  ldbf8(mx + base + E_DIM, m[1]);
  *(float4*)&bv[0] = *(const float4*)(bias + lane * 8);
  *(float4*)&bv[4] = *(const float4*)(bias + lane * 8 + 4);
  float s[4];
#pragma unroll
  for (int i = 0; i < 4; ++i) s[i] = 0.f;
#pragma unroll
  for (int i = 0; i < 8; ++i) {
#pragma unroll
    for (int r2 = 0; r2 < 2; ++r2) {
      s[r2 * 2 + 0] += m[r2][i] * m[r2][i];
      s[r2 * 2 + 1] += m[r2][i] * bv[i];
    }
  }
  waveRed<4>(s);
  float S2 = *bs_sb2;
#pragma unroll
  for (int r2 = 0; r2 < 2; ++r2) {
    float S0 = s[r2 * 2 + 0], S1 = s[r2 * 2 + 1];
    float se = S0 + 1e-30f;
    float rmx = frsq(se);
    float mxn = se * rmx;
    float xn = xn_arr[row + r2];
    float aa = fatanh(fminf(xn, MAXN));
    float tt = ftanh(mxn * frcp(xn) * aa);
    float c = tt * rmx;
    float xy = c * S1, y2 = S2, x2 = tt * tt;
    float c1 = 1.f + 2.f * xy + y2, c2 = 1.f - x2;
    float iden = frcp(fmaxf(1.f + 2.f * xy + x2 * y2, 1e-15f));
    float cc1 = c1 * c * iden, cc2 = c2 * iden;
    float un2 = fmaxf(cc1 * cc1 * S0 + 2.f * cc1 * cc2 * S1 + cc2 * cc2 * S2, 0.f);
    float ue = un2 + 1e-30f;
    float run = frsq(ue);
    float un = ue * run;
    float ne = fminf(un, MAXN);
    float f = fatanh(ne) * run;
    float u[8];
#pragma unroll
    for (int i = 0; i < 8; ++i) u[i] = (cc1 * m[r2][i] + cc2 * bv[i]) * f;
    uint4 o = {pack2(u[0], u[1]), pack2(u[2], u[3]), pack2(u[4], u[5]),
               pack2(u[6], u[7])};
    *reinterpret_cast<uint4*>(qout + base + r2 * E_DIM) = o;
  }
}

// ---- attention: per (b,h) MFMA tile; OUTPUT BF16 --------------------------
__global__ __launch_bounds__(256) void k_attn(const ushort* __restrict__ q,
                                              const ushort* __restrict__ k,
                                              const ushort* __restrict__ v,
                                              ushort* __restrict__ o) {
  __shared__ __align__(16) ushort smem[27136];
  ushort* Qs = smem;
  ushort* Ks = smem + 9216;
  ushort* VTs = smem + 18432;
  ushort* Ps = smem;
  int bh = blockIdx.x;
  int b = bh >> 3, h = bh & 7;
  int tid = threadIdx.x;
  int w = tid >> 6, lane = tid & 63;
  const size_t BE = (size_t)B_DIM * E_DIM;
  size_t gbase = (size_t)b * E_DIM + (size_t)h * 64;

  {
    int s = tid >> 1, half = (tid & 1) * 32;
    const ushort* qr = q + gbase + (size_t)s * BE + half;
    const ushort* kr = k + gbase + (size_t)s * BE + half;
    const ushort* vr = v + gbase + (size_t)s * BE + half;
#pragma unroll
    for (int j = 0; j < 4; ++j) {
      *reinterpret_cast<uint4*>(&Qs[s * 72 + half + j * 8]) =
          *reinterpret_cast<const uint4*>(qr + j * 8);
      *reinterpret_cast<uint4*>(&Ks[s * 72 + half + j * 8]) =
          *reinterpret_cast<const uint4*>(kr + j * 8);
    }
    ushort tv[32];
#pragma unroll
    for (int j = 0; j < 4; ++j)
      *reinterpret_cast<uint4*>(&tv[j * 8]) =
          *reinterpret_cast<const uint4*>(vr + j * 8);
#pragma unroll
    for (int d = 0; d < 32; ++d) VTs[(half + d) * 136 + s] = tv[d];
  }
  __syncthreads();

  f32x4 zero = {0.f, 0.f, 0.f, 0.f};
  f32x4 sacc[2][8];
#pragma unroll
  for (int i = 0; i < 2; ++i)
#pragma unroll
    for (int j = 0; j < 8; ++j) sacc[i][j] = zero;
  {
    const ushort* qb = Qs + (w * 32 + (lane & 15)) * 72 + (lane >> 4) * 8;
    const ushort* kb = Ks + (lane & 15) * 72 + (lane >> 4) * 8;
#pragma unroll
    for (int kk = 0; kk < 2; ++kk) {
      bf16x8 a0 = *reinterpret_cast<const bf16x8*>(qb + kk * 32);
      bf16x8 a1 = *reinterpret_cast<const bf16x8*>(qb + 16 * 72 + kk * 32);
#pragma unroll
      for (int tj = 0; tj < 8; ++tj) {
        bf16x8 bf = *reinterpret_cast<const bf16x8*>(kb + tj * 16 * 72 + kk * 32);
        sacc[0][tj] = __builtin_amdgcn_mfma_f32_16x16x32_bf16(a0, bf,
                                                              sacc[0][tj], 0, 0, 0);
        sacc[1][tj] = __builtin_amdgcn_mfma_f32_16x16x32_bf16(a1, bf,
                                                              sacc[1][tj], 0, 0, 0);
      }
    }
  }

#pragma unroll
  for (int ti = 0; ti < 2; ++ti) {
#pragma unroll
    for (int r = 0; r < 4; ++r) {
      float mx = -1e30f;
#pragma unroll
      for (int tj = 0; tj < 8; ++tj) mx = fmaxf(mx, sacc[ti][tj][r]);
      mx = fmaxf(mx, __shfl_xor(mx, 1));
      mx = fmaxf(mx, __shfl_xor(mx, 2));
      mx = fmaxf(mx, __shfl_xor(mx, 4));
      mx = fmaxf(mx, __shfl_xor(mx, 8));
      float l = 0.f;
#pragma unroll
      for (int tj = 0; tj < 8; ++tj) {
        float e = fexp2((sacc[ti][tj][r] - mx) * (0.125f * 1.44269504f));
        sacc[ti][tj][r] = e;
        l += e;
      }
      l += __shfl_xor(l, 1);
      l += __shfl_xor(l, 2);
      l += __shfl_xor(l, 4);
      l += __shfl_xor(l, 8);
      float inv = frcp(l);
#pragma unroll
      for (int tj = 0; tj < 8; ++tj) sacc[ti][tj][r] *= inv;
    }
  }

  __syncthreads();
  {
    int qr0 = w * 32 + (lane >> 4) * 4;
    int kc = lane & 15;
#pragma unroll
    for (int ti = 0; ti < 2; ++ti)
#pragma unroll
      for (int tj = 0; tj < 8; ++tj)
#pragma unroll
        for (int r = 0; r < 4; ++r)
          Ps[(qr0 + ti * 16 + r) * 136 + tj * 16 + kc] =
              f2bf(sacc[ti][tj][r]);
  }
  __syncthreads();

  f32x4 oacc[2][4];
#pragma unroll
  for (int i = 0; i < 2; ++i)
#pragma unroll
    for (int j = 0; j < 4; ++j) oacc[i][j] = zero;
  {
    const ushort* pb = Ps + (w * 32 + (lane & 15)) * 136 + (lane >> 4) * 8;
    const ushort* vb = VTs + (lane & 15) * 136 + (lane >> 4) * 8;
#pragma unroll
    for (int kk = 0; kk < 4; ++kk) {
      bf16x8 a0 = *reinterpret_cast<const bf16x8*>(pb + kk * 32);
      bf16x8 a1 = *reinterpret_cast<const bf16x8*>(pb + 16 * 136 + kk * 32);
#pragma unroll
      for (int tj = 0; tj < 4; ++tj) {
        bf16x8 bv = *reinterpret_cast<const bf16x8*>(vb + tj * 16 * 136 + kk * 32);
        oacc[0][tj] = __builtin_amdgcn_mfma_f32_16x16x32_bf16(a0, bv,
                                                              oacc[0][tj], 0, 0, 0);
        oacc[1][tj] = __builtin_amdgcn_mfma_f32_16x16x32_bf16(a1, bv,
                                                              oacc[1][tj], 0, 0, 0);
      }
    }
  }

  {
    int qr0 = w * 32 + (lane >> 4) * 4;
    int dc = lane & 15;
#pragma unroll
    for (int ti = 0; ti < 2; ++ti)
#pragma unroll
      for (int tj = 0; tj < 4; ++tj)
#pragma unroll
        for (int r = 0; r < 4; ++r)
          o[(size_t)(qr0 + ti * 16 + r) * BE + gbase + tj * 16 + dc] =
              f2bf(oacc[ti][tj][r]);
  }
}

// ---- expmap0 rowwise (bf16 in), 2 rows/wave -------------------------------
__global__ __launch_bounds__(256) void k_expmap_rows(const ushort* __restrict__ in,
                                                     ushort* __restrict__ out,
                                                     float* __restrict__ nrm) {
  int wv = threadIdx.x >> 6, lane = threadIdx.x & 63;
  int row = blockIdx.x * 8 + wv * 2;
  size_t base = (size_t)row * E_DIM + lane * 8;
  float v[2][8];
  ldbf8(in + base, v[0]);
  ldbf8(in + base + E_DIM, v[1]);
  float s[2] = {0.f, 0.f};
#pragma unroll
  for (int i = 0; i < 8; ++i) {
    s[0] += v[0][i] * v[0][i];
    s[1] += v[1][i] * v[1][i];
  }
  waveRed<2>(s);
#pragma unroll
  for (int r2 = 0; r2 < 2; ++r2) {
    float se = s[r2] + 1e-30f;
    float rn = frsq(se);
    float n = se * rn;
    float th = ftanh(n);
    float f = th * rn;
    uint4 o = {pack2(v[r2][0] * f, v[r2][1] * f), pack2(v[r2][2] * f, v[r2][3] * f),
               pack2(v[r2][4] * f, v[r2][5] * f), pack2(v[r2][6] * f, v[r2][7] * f)};
    *reinterpret_cast<uint4*>(out + base + r2 * E_DIM) = o;
    if (lane == 0) nrm[row + r2] = th;
  }
}

// ---- attn-out epilogue (1 row/wave, 3 small chains; bf16 mo in,
// bf16 res2 out) ------------------------------------------------------------
__global__ __launch_bounds__(256) void k_epi_attnout(
    const ushort* __restrict__ mo, const float* __restrict__ xn_arr,
    const float* __restrict__ bo, const float* __restrict__ xin,
    const float* __restrict__ g2, const float* __restrict__ b2,
    ushort* __restrict__ h2, float* __restrict__ h2n,
    ushort* __restrict__ r2o) {
  int row = blockIdx.x * 4 + (threadIdx.x >> 6);
  int lane = threadIdx.x & 63;
  size_t base = (size_t)row * E_DIM + lane * 8;
  float m[8], bv[8];
  ldbf8(mo + base, m);
  *(float4*)&bv[0] = *(const float4*)(bo + lane * 8);
  *(float4*)&bv[4] = *(const float4*)(bo + lane * 8 + 4);
  float s[5] = {0.f, 0.f, 0.f, 0.f, 0.f};
#pragma unroll
  for (int i = 0; i < 8; ++i) {
    s[0] += m[i] * m[i]; s[1] += m[i] * bv[i]; s[2] += bv[i] * bv[i];
    s[3] += m[i]; s[4] += bv[i];
  }
  waveRed<5>(s);
  float se = s[0] + 1e-30f;
  float rmx = frsq(se);
  float mxn = se * rmx;
  float xn = xn_arr[row];
  float aa = fatanh(fminf(xn, MAXN));
  float tt = ftanh(mxn * frcp(xn) * aa);
  float c = tt * rmx;
  float xy = c * s[1], y2 = s[2], x2 = tt * tt;
  float c1 = 1.f + 2.f * xy + y2, c2 = 1.f - x2;
  float iden = frcp(fmaxf(1.f + 2.f * xy + x2 * y2, 1e-15f));
  float cc1 = c1 * c * iden, cc2 = c2 * iden;
  float un2 = fmaxf(cc1 * cc1 * s[0] + 2.f * cc1 * cc2 * s[1] + cc2 * cc2 * s[2], 0.f);
  float ue = un2 + 1e-30f;
  float run = frsq(ue);
  float un = ue * run;
  float ps = un > MAXN ? MAXN * run : 1.f;
  float zn = fminf(un, MAXN);
  float z[8];
#pragma unroll
  for (int i = 0; i < 8; ++i) z[i] = (cc1 * m[i] + cc2 * bv[i]) * ps;
  float sumz = ps * (cc1 * s[3] + cc2 * s[4]);
  float r[8];
  *(float4*)&r[0] = *(const float4*)(xin + base);
  *(float4*)&r[4] = *(const float4*)(xin + base + 4);
  float t2[3] = {0.f, 0.f, 0.f};
#pragma unroll
  for (int i = 0; i < 8; ++i) {
    t2[0] += z[i] * r[i]; t2[1] += r[i] * r[i]; t2[2] += r[i];
  }
  waveRed<3>(t2);
  float xy2 = t2[0], y22 = t2[1], x22 = zn * zn;
  float d1 = 1.f + 2.f * xy2 + y22, d2 = 1.f - x22;
  float iden2 = frcp(fmaxf(1.f + 2.f * xy2 + x22 * y22, 1e-15f));
  float wn2 = fmaxf(iden2 * iden2 *
                        (d1 * d1 * x22 + 2.f * d1 * d2 * xy2 + d2 * d2 * y22),
                    0.f);
  float we = wn2 + 1e-30f;
  float rwn = frsq(we);
  float wn = we * rwn;
  float ps2 = wn > MAXN ? MAXN * rwn : 1.f;
  float w[8];
#pragma unroll
  for (int i = 0; i < 8; ++i) w[i] = (d1 * z[i] + d2 * r[i]) * iden2 * ps2;
  uint4 ro = {pack2(w[0], w[1]), pack2(w[2], w[3]), pack2(w[4], w[5]),
              pack2(w[6], w[7])};
  *reinterpret_cast<uint4*>(r2o + base) = ro;
  float ne = fminf(wn, MAXN);
  float ath = fatanh(ne);
  float lf = ath * frcp(ne);
  float sumw = ps2 * iden2 * (d1 * sumz + d2 * t2[2]);
  float mu = lf * sumw * (1.f / 512.f);
  float var = fmaxf(ath * ath * (1.f / 512.f) - mu * mu, 0.f);
  float rstd = frsq(var + 1e-5f);
  float gv[8], b2v[8];
  *(float4*)&gv[0] = *(const float4*)(g2 + lane * 8);
  *(float4*)&gv[4] = *(const float4*)(g2 + lane * 8 + 4);
  *(float4*)&b2v[0] = *(const float4*)(b2 + lane * 8);
  *(float4*)&b2v[4] = *(const float4*)(b2 + lane * 8 + 4);
  float e[8];
  float s3[1] = {0.f};
#pragma unroll
  for (int i = 0; i < 8; ++i) {
    e[i] = (lf * w[i] - mu) * rstd * gv[i] + b2v[i];
    s3[0] += e[i] * e[i];
  }
  waveRed<1>(s3);
  float s3e = s3[0] + 1e-30f;
  float rn3 = frsq(s3e);
  float n3 = s3e * rn3;
  float en = ftanh(n3);
  float f = en * rn3;
  if (en > MAXN) f *= MAXN * frcp(en);
  uint4 o = {pack2(e[0] * f, e[1] * f), pack2(e[2] * f, e[3] * f),
             pack2(e[4] * f, e[5] * f), pack2(e[6] * f, e[7] * f)};
  *reinterpret_cast<uint4*>(h2 + base) = o;
  if (lane == 0) h2n[row] = fminf(en, MAXN);
}

// ---- FFN1 epilogue (2 rows/wave of F=2048; bf16 m1 in) -> bf16 ------------
__global__ __launch_bounds__(256) void k_epi_ffn1(const ushort* __restrict__ mr_,
                                                  const float* __restrict__ xn_arr,
                                                  const float* __restrict__ bias,
                                                  ushort* __restrict__ hid,
                                                  float* __restrict__ hn_out) {
  int wv = threadIdx.x >> 6, lane = threadIdx.x & 63;
  int row = blockIdx.x * 8 + wv * 2;
  const ushort* mr = mr_ + (size_t)row * F_DIM + lane * 32;
  const float* br = bias + lane * 32;
  float m[2][32], bv[32];
#pragma unroll
  for (int j = 0; j < 4; ++j) {
    ldbf8(mr + j * 8, *(float(*)[8])&m[0][j * 8]);
    ldbf8(mr + F_DIM + j * 8, *(float(*)[8])&m[1][j * 8]);
  }
#pragma unroll
  for (int j = 0; j < 8; ++j)
    *(float4*)&bv[j * 4] = *(const float4*)(br + j * 4);
  float s[5];
#pragma unroll
  for (int i = 0; i < 5; ++i) s[i] = 0.f;
#pragma unroll
  for (int i = 0; i < 32; ++i) {
#pragma unroll
    for (int r2 = 0; r2 < 2; ++r2) {
      s[r2 * 2 + 0] += m[r2][i] * m[r2][i];
      s[r2 * 2 + 1] += m[r2][i] * bv[i];
    }
    s[4] += bv[i] * bv[i];
  }
  waveRed<5>(s);
  float s2[2] = {0.f, 0.f};
#pragma unroll
  for (int r2 = 0; r2 < 2; ++r2) {
    float S0 = s[r2 * 2 + 0], S1 = s[r2 * 2 + 1], S2 = s[4];
    float se = S0 + 1e-30f;
    float rmx = frsq(se);
    float mxn = se * rmx;
    float xn = xn_arr[row + r2];
    float aa = fatanh(fminf(xn, MAXN));
    float tt = ftanh(mxn * frcp(xn) * aa);
    float c = tt * rmx;
    float xy = c * S1, y2 = S2, x2 = tt * tt;
    float c1 = 1.f + 2.f * xy + y2, c2 = 1.f - x2;
    float iden = frcp(fmaxf(1.f + 2.f * xy + x2 * y2, 1e-15f));
    float cc1 = c1 * c * iden, cc2 = c2 * iden;
    float un2 = fmaxf(cc1 * cc1 * S0 + 2.f * cc1 * cc2 * S1 + cc2 * cc2 * S2, 0.f);
    float ue = un2 + 1e-30f;
    float run = frsq(ue);
    float un = ue * run;
    float zn = fminf(un, MAXN);
    float lf = fatanh(zn) * run;
#pragma unroll
    for (int i = 0; i < 32; ++i) {
      m[r2][i] = fmaxf((cc1 * m[r2][i] + cc2 * bv[i]) * lf, 0.f);
      s2[r2] += m[r2][i] * m[r2][i];
    }
  }
  waveRed<2>(s2);
#pragma unroll
  for (int r2 = 0; r2 < 2; ++r2) {
    float s2e = s2[r2] + 1e-30f;
    float rrn = frsq(s2e);
    float rn = s2e * rrn;
    float en = ftanh(rn);
    float f = en * rrn;
    if (en > MAXN) f *= MAXN * frcp(en);
    ushort* hr = hid + (size_t)(row + r2) * F_DIM + lane * 32;
#pragma unroll
    for (int j = 0; j < 4; ++j) {
      uint4 o = {pack2(m[r2][j * 8 + 0] * f, m[r2][j * 8 + 1] * f),
                 pack2(m[r2][j * 8 + 2] * f, m[r2][j * 8 + 3] * f),
                 pack2(m[r2][j * 8 + 4] * f, m[r2][j * 8 + 5] * f),
                 pack2(m[r2][j * 8 + 6] * f, m[r2][j * 8 + 7] * f)};
      *reinterpret_cast<uint4*>(hr + j * 8) = o;
    }
    if (lane == 0) hn_out[row + r2] = fminf(en, MAXN);
  }
}

// ---- final epilogue (2 rows/wave): fp32 split-K2 sum + man_linear(W2) +
// mob_relu + residual (bf16) mobius_add + projx -> out fp32 -----------------
__global__ __launch_bounds__(256) void k_epi_final(
    const float* __restrict__ m2, const float* __restrict__ xn_arr,
    const float* __restrict__ bias, const ushort* __restrict__ res,
    float* __restrict__ out) {
  int wv = threadIdx.x >> 6, lane = threadIdx.x & 63;
  int row = blockIdx.x * 8 + wv * 2;
  size_t base = (size_t)row * E_DIM + lane * 8;
  const size_t P2 = (size_t)CH * E_DIM;
  float m[2][8], bv[8], q[2][8];
#pragma unroll
  for (int r2 = 0; r2 < 2; ++r2) {
    float ta[8], tb[8];
    *(float4*)&ta[0] = *(const float4*)(m2 + base + r2 * E_DIM);
    *(float4*)&ta[4] = *(const float4*)(m2 + base + r2 * E_DIM + 4);
    *(float4*)&tb[0] = *(const float4*)(m2 + P2 + base + r2 * E_DIM);
    *(float4*)&tb[4] = *(const float4*)(m2 + P2 + base + r2 * E_DIM + 4);
#pragma unroll
    for (int i = 0; i < 8; ++i) m[r2][i] = ta[i] + tb[i];
    ldbf8(res + base + r2 * E_DIM, q[r2]);
  }
  *(float4*)&bv[0] = *(const float4*)(bias + lane * 8);
  *(float4*)&bv[4] = *(const float4*)(bias + lane * 8 + 4);
  float s[7];
#pragma unroll
  for (int i = 0; i < 7; ++i) s[i] = 0.f;
#pragma unroll
  for (int i = 0; i < 8; ++i) {
#pragma unroll
    for (int r2 = 0; r2 < 2; ++r2) {
      s[r2 * 3 + 0] += m[r2][i] * m[r2][i];
      s[r2 * 3 + 1] += m[r2][i] * bv[i];
      s[r2 * 3 + 2] += q[r2][i] * q[r2][i];
    }
    s[6] += bv[i] * bv[i];
  }
  waveRed<7>(s);
  float r[2][8];
  float s2[4];
#pragma unroll
  for (int i = 0; i < 4; ++i) s2[i] = 0.f;
#pragma unroll
  for (int r2 = 0; r2 < 2; ++r2) {
    float S0 = s[r2 * 3 + 0], S1 = s[r2 * 3 + 1], S2 = s[6];
    float se = S0 + 1e-30f;
    float rmx = frsq(se);
    float mxn = se * rmx;
    float xn = xn_arr[row + r2];
    float aa = fatanh(fminf(xn, MAXN));
    float tt = ftanh(mxn * frcp(xn) * aa);
    float c = tt * rmx;
    float xy = c * S1, y2 = S2, x2 = tt * tt;
    float c1 = 1.f + 2.f * xy + y2, c2 = 1.f - x2;
    float iden = frcp(fmaxf(1.f + 2.f * xy + x2 * y2, 1e-15f));
    float cc1 = c1 * c * iden, cc2 = c2 * iden;
    float un2 = fmaxf(cc1 * cc1 * S0 + 2.f * cc1 * cc2 * S1 + cc2 * cc2 * S2, 0.f);
    float ue = un2 + 1e-30f;
    float run = frsq(ue);
    float un = ue * run;
    float zn = fminf(un, MAXN);
    float lf = fatanh(zn) * run;
#pragma unroll
    for (int i = 0; i < 8; ++i) {
      r[r2][i] = fmaxf((cc1 * m[r2][i] + cc2 * bv[i]) * lf, 0.f);
      s2[r2 * 2 + 0] += r[r2][i] * r[r2][i];
      s2[r2 * 2 + 1] += r[r2][i] * q[r2][i];
    }
  }
  waveRed<4>(s2);
#pragma unroll
  for (int r2 = 0; r2 < 2; ++r2) {
    float s2e = s2[r2 * 2 + 0] + 1e-30f;
    float rrn = frsq(s2e);
    float rn = s2e * rrn;
    float en = ftanh(rn);
    float f = en * rrn;
    if (en > MAXN) f *= MAXN * frcp(en);
    float hn = fminf(en, MAXN);
    float xy2 = f * s2[r2 * 2 + 1], y22 = s[r2 * 3 + 2], x22 = hn * hn;
    float d1 = 1.f + 2.f * xy2 + y22, d2 = 1.f - x22;
    float iden2 = frcp(fmaxf(1.f + 2.f * xy2 + x22 * y22, 1e-15f));
    float wn2 = fmaxf(iden2 * iden2 *
                          (d1 * d1 * x22 + 2.f * d1 * d2 * xy2 + d2 * d2 * y22),
                      0.f);
    float we = wn2 + 1e-30f;
    float rwn = frsq(we);
    float wn = we * rwn;
    float ps2 = wn > MAXN ? MAXN * rwn : 1.f;
    float w[8];
#pragma unroll
    for (int i = 0; i < 8; ++i)
      w[i] = (d1 * r[r2][i] * f + d2 * q[r2][i]) * iden2 * ps2;
    *(float4*)(out + base + r2 * E_DIM) = *(float4*)&w[0];
    *(float4*)(out + base + r2 * E_DIM + 4) = *(float4*)&w[4];
  }
}

extern "C" void kernel_launch(void* const* d_in, const int* in_sizes, int n_in,
                              void* d_out, int out_size, void* d_ws,
                              size_t ws_size, hipStream_t stream) {
  const float* x   = (const float*)d_in[0];
  const float* g1  = (const float*)d_in[1];
  const float* lb1 = (const float*)d_in[2];
  const float* g2  = (const float*)d_in[3];
  const float* lb2 = (const float*)d_in[4];
  const float* Wq  = (const float*)d_in[5];
  const float* bq  = (const float*)d_in[6];
  const float* Wk  = (const float*)d_in[7];
  const float* bk  = (const float*)d_in[8];
  const float* Wv  = (const float*)d_in[9];
  const float* bv  = (const float*)d_in[10];
  const float* Wo  = (const float*)d_in[11];
  const float* bo  = (const float*)d_in[12];
  const float* W1  = (const float*)d_in[13];
  const float* b1  = (const float*)d_in[14];
  const float* W2  = (const float*)d_in[15];
  const float* b2  = (const float*)d_in[16];
  float* out = (float*)d_out;
  float* ws = (float*)d_ws;

  const size_t NE = (size_t)N_ROWS * E_DIM;          // 16,777,216
  const size_t WF = (4 * (size_t)E_DIM * E_DIM +
                     2 * (size_t)F_DIM * E_DIM) / 2; // 1,572,864 floats
  // R_b (NE floats = 64MB):
  //   lower 32MB as ushort: QKV C bf16 -> attn-out bf16 -> mo bf16 -> m1 bf16
  //   upper 32MB as ushort: res2 bf16 (attnout -> epi_final)
  ushort* Cb   = (ushort*)ws;            // NE ushorts (32MB scratch)
  ushort* r2u  = (ushort*)(ws + NE / 2); // NE ushorts (res2 bf16)
  float* R_a = ws + NE;                  // NE/2: h1 -> oe -> h2 (bf16)
  float* R_q = ws + NE + NE / 2;         // NE/2: q_bf16 -> m2 fp32 partials
  float* R_k = ws + 2 * NE;              // NE/2: k_bf16
  float* R_v = ws + 2 * NE + NE / 2;     // NE/2: v_bf16 -> hid_bf16
  ushort* wqb = (ushort*)(ws + 3 * NE);
  ushort* wkb = wqb + (size_t)E_DIM * E_DIM;
  ushort* wvb = wkb + (size_t)E_DIM * E_DIM;
  ushort* wob = wvb + (size_t)E_DIM * E_DIM;
  ushort* w1b = wob + (size_t)E_DIM * E_DIM;
  ushort* w2b = w1b + (size_t)F_DIM * E_DIM;
  float* n_h1 = ws + 3 * NE + WF;
  float* n_oe = n_h1 + N_ROWS;
  float* n_h2 = n_oe + N_ROWS;
  float* n_h3 = n_h2 + N_ROWS;
  float* bs = n_h3 + N_ROWS;  // 16 scalar sums
  const size_t need = (3 * NE + WF + 4 * (size_t)N_ROWS + 16) * sizeof(float);
  if (ws_size < need) return;

  k_bsums<<<1, 64, 0, stream>>>(bq, bk, bv, g1, lb1, bs);
  k_f2bf<<<256, 256, 0, stream>>>(Wq, wqb, E_DIM * E_DIM);
  k_f2bf<<<256, 256, 0, stream>>>(Wk, wkb, E_DIM * E_DIM);
  k_f2bf<<<256, 256, 0, stream>>>(Wv, wvb, E_DIM * E_DIM);
  k_f2bf<<<256, 256, 0, stream>>>(Wo, wob, E_DIM * E_DIM);
  k_f2bf<<<512, 256, 0, stream>>>(W1, w1b, F_DIM * E_DIM);
  k_f2bf<<<512, 256, 0, stream>>>(W2, w2b, F_DIM * E_DIM);

  ushort* h1b = (ushort*)R_a;
  ushort* qb = (ushort*)R_q;
  ushort* kb = (ushort*)R_k;
  ushort* vb = (ushort*)R_v;

  // Phase A: stage1 + QKV projections (bf16 C scratch, XCD-swizzled GEMM)
  k_stage1<<<N_ROWS / 8, 256, 0, stream>>>(x, g1, lb1, bs, h1b, n_h1);
  const int gE = 4 * 256;  // X=4 col-blocks, Y=256 row-panels
  k_gemm_bf16<<<gE, 256, 0, stream>>>(h1b, wqb, (float*)Cb, E_DIM, E_DIM,
                                      E_DIM, 0, 1, 4, 256);
  k_epi_qkv<<<N_ROWS / 8, 256, 0, stream>>>(Cb, n_h1, bq, bs + 0, qb);
  k_gemm_bf16<<<gE, 256, 0, stream>>>(h1b, wkb, (float*)Cb, E_DIM, E_DIM,
                                      E_DIM, 0, 1, 4, 256);
  k_epi_qkv<<<N_ROWS / 8, 256, 0, stream>>>(Cb, n_h1, bk, bs + 1, kb);
  k_gemm_bf16<<<gE, 256, 0, stream>>>(h1b, wvb, (float*)Cb, E_DIM, E_DIM,
                                      E_DIM, 0, 1, 4, 256);
  k_epi_qkv<<<N_ROWS / 8, 256, 0, stream>>>(Cb, n_h1, bv, bs + 2, vb);

  // Phase B: MFMA attention -> bf16 Cb; expmap0 -> oe bf16 (R_a, h1 dead)
  k_attn<<<B_DIM * 8, 256, 0, stream>>>(qb, kb, vb, Cb);
  ushort* oeb = (ushort*)R_a;
  k_expmap_rows<<<N_ROWS / 8, 256, 0, stream>>>(Cb, oeb, n_oe);

  // Phase C: Wo projection -> mo bf16 (Cb); attnout: res2 bf16 -> r2u,
  // h2 bf16 -> R_a (oe dead after Wo GEMM read)
  ushort* h2b = (ushort*)R_a;
  k_gemm_bf16<<<gE, 256, 0, stream>>>(oeb, wob, (float*)Cb, E_DIM, E_DIM,
                                      E_DIM, 0, 1, 4, 256);
  k_epi_attnout<<<N_ROWS / 4, 256, 0, stream>>>(Cb, n_oe, bo, x, g2, lb2,
                                                h2b, n_h2, r2u);

  // Phase D: FFN chunked (CH=8192). m1 bf16 in Cb (mo dead), hid bf16 in
  // R_v (v dead), m2 fp32 split-K2 partials in R_q (q dead). Stream-ordered.
  ushort* m1 = Cb;
  ushort* hidb = (ushort*)R_v;
  float* m2 = R_q;
  for (int c = 0; c < N_ROWS / CH; ++c) {
    size_t ro = (size_t)c * CH;
    // FFN1: X=16 (F/128), Y=64 (CH/128)
    k_gemm_bf16<<<16 * 64, 256, 0, stream>>>(
        h2b + ro * E_DIM, w1b, (float*)m1, E_DIM, F_DIM, E_DIM, 0, 1, 16, 64);
    k_epi_ffn1<<<CH / 8, 256, 0, stream>>>(m1, n_h2 + ro, b1, hidb, n_h3 + ro);
    // FFN2: X=4 (E/128), Y=64 (CH/128), Z=2 (split-K)
    k_gemm_bf16<<<4 * 64 * 2, 256, 0, stream>>>(
        hidb, w2b, m2, F_DIM, E_DIM, F_DIM / 2,
        (unsigned long long)((size_t)CH * E_DIM), 0, 4, 64);
    k_epi_final<<<CH / 8, 256, 0, stream>>>(m2, n_h3 + ro, b2,
                                            r2u + ro * E_DIM, out + ro * E_DIM);
  }
}